// Round 2
// baseline (1563.596 us; speedup 1.0000x reference)
//
#include <hip/hip_runtime.h>
#include <math.h>

// ---------------------------------------------------------------------------
// Problem dims: B_IN=15, B1=10, B2=6, F1=20, F2=40, F_OUT=10
// M1=19, C1=9, M2=11, C2=5, batch=128
// ---------------------------------------------------------------------------

// workspace layout (offsets in floats; all even -> float2 aligned)
constexpr int OFF_WS2   = 0;                     // W_S2_FWD  [30][10][19]
constexpr int OFF_WINV1 = OFF_WS2   + 5700;      // W_INV1    [20][10][19][19]
constexpr int OFF_WSO3  = OFF_WINV1 + 72200;     // W_SO3_FWD [20][6][11][11]
constexpr int OFF_WINV2 = OFF_WSO3  + 14520;     // W_INV2    [12][6][11][11]
constexpr int OFF_WINT  = OFF_WINV2 + 8712;      // W_INT     [12] (+pad)
constexpr int OFF_FE1   = OFF_WINT  + 16;        // FE1  cplx [19][30]
constexpr int OFF_EA1   = OFF_FE1   + 1140;      // E_A1 cplx [19][20]
constexpr int OFF_FF2   = OFF_EA1   + 760;       // FF2  cplx [11][20]
constexpr int OFF_EA2   = OFF_FF2   + 440;       // E_A2 cplx [11][12]
constexpr int OFF_BS2   = OFF_EA2   + 264;       // B_S2 cplx [24][10][19]
constexpr int OFF_BSO3  = OFF_BS2   + 9120;      // B_SO3 cplx[144][6][11][11]
constexpr int OFF_PSI   = OFF_BSO3  + 209088;    // psi  cplx [20][10][19]
constexpr int OFF_X     = OFF_PSI   + 7600;      // X    cplx [128][10][19]
constexpr int OFF_X2    = OFF_X     + 48640;     // X2   cplx [128][20][6][11][11]
constexpr int OFF_PSI2  = OFF_X2    + 3717120;   // psi2 cplx [20][40][6][11][11]
constexpr int OFF_FEAT  = OFF_PSI2  + 1161600;   // feat      [128][40]
// total = OFF_FEAT + 5120 = 5,262,040 floats  (~21.0 MB)

#define DPI 3.14159265358979323846

// ---------------------------------------------------------------------------
// table-building helpers (double precision, matches numpy reference)
// ---------------------------------------------------------------------------
__device__ __forceinline__ double dfact(int n) {
    double f = 1.0;
    for (int i = 2; i <= n; ++i) f *= (double)i;
    return f;
}
__device__ __forceinline__ double dpowi(double x, int n) {
    double r = 1.0;
    for (int i = 0; i < n; ++i) r *= x;
    return r;
}
__device__ double wig_d(int l, int mi, int ni, double beta) {
    // mi, ni in 0..2l ; m = mi-l, n = ni-l
    int m = mi - l, n = ni - l;
    double cb = cos(0.5 * beta), sb = sin(0.5 * beta);
    double pref = sqrt(dfact(l + m) * dfact(l - m) * dfact(l + n) * dfact(l - n));
    int s0 = (n - m) > 0 ? (n - m) : 0;
    int s1 = (l + n) < (l - m) ? (l + n) : (l - m);
    double v = 0.0;
    for (int s = s0; s <= s1; ++s) {
        double term = dpowi(cb, 2 * l + n - m - 2 * s) * dpowi(sb, m - n + 2 * s) /
                      (dfact(l + n - s) * dfact(s) * dfact(m - n + s) * dfact(l - m - s));
        v += ((m - n + s) & 1) ? -term : term;
    }
    return pref * v;
}
__device__ double wig_pad(int l, int m, int n, int c, double beta) {
    if (m < c - l || m > c + l || n < c - l || n > c + l) return 0.0;
    return wig_d(l, m - (c - l), n - (c - l), beta);
}
__device__ double quad_w(int b, int k) {
    double beta = DPI * (2 * k + 1) / (4.0 * b);
    double s = 0.0;
    for (int j = 0; j < b; ++j) s += sin((2 * j + 1) * beta) / (double)(2 * j + 1);
    return 2.0 / b * sin(beta) * s;
}

// total element ids: 5700+72200+14520+8712+12+570+380+220+132+4560+104544 = 211550
__global__ __launch_bounds__(256) void build_tables_kernel(float* ws) {
    int idx = blockIdx.x * 256 + threadIdx.x;
    // R0: W_S2_FWD [k=30][l=10][m=19]
    if (idx < 5700) {
        int k = idx / 190, r = idx % 190, l = r / 19, m = r % 19;
        double beta = DPI * (2 * k + 1) / 60.0;
        ws[OFF_WS2 + idx] = (float)(quad_w(15, k) * wig_pad(l, m, 9, 9, beta));
        return;
    }
    idx -= 5700;
    // R1: W_INV1 [k=20][l=10][m=19][n=19]
    if (idx < 72200) {
        int k = idx / 3610, r = idx % 3610, l = r / 361, r2 = r % 361, m = r2 / 19, n = r2 % 19;
        double beta = DPI * (2 * k + 1) / 40.0;
        ws[OFF_WINV1 + idx] = (float)((2 * l + 1) * wig_pad(l, m, n, 9, beta));
        return;
    }
    idx -= 72200;
    // R2: W_SO3_FWD [k=20][l=6][m=11][n=11]
    if (idx < 14520) {
        int k = idx / 726, r = idx % 726, l = r / 121, m = (r % 121) / 11, n = r % 11;
        double beta = DPI * (2 * k + 1) / 40.0;
        ws[OFF_WSO3 + idx] = (float)(quad_w(10, k) * wig_pad(l, m, n, 5, beta));
        return;
    }
    idx -= 14520;
    // R3: W_INV2 [k=12][l=6][11][11]
    if (idx < 8712) {
        int k = idx / 726, r = idx % 726, l = r / 121, m = (r % 121) / 11, n = r % 11;
        double beta = DPI * (2 * k + 1) / 24.0;
        ws[OFF_WINV2 + idx] = (float)((2 * l + 1) * wig_pad(l, m, n, 5, beta));
        return;
    }
    idx -= 8712;
    // R4: W_INT [12]
    if (idx < 12) { ws[OFF_WINT + idx] = (float)quad_w(6, idx); return; }
    idx -= 12;
    // R5: FE1 [m=19][t=30]  exp(-2*pi*i*(m-9)*t/30)
    if (idx < 570) {
        int m = idx / 30, t = idx % 30;
        double ang = -2.0 * DPI * (double)((m - 9) * t) / 30.0;
        ws[OFF_FE1 + 2 * idx] = (float)cos(ang);
        ws[OFF_FE1 + 2 * idx + 1] = (float)sin(ang);
        return;
    }
    idx -= 570;
    // R6: E_A1 [m=19][a=20]  exp(+2*pi*i*(m-9)*a/20)
    if (idx < 380) {
        int m = idx / 20, a = idx % 20;
        double ang = 2.0 * DPI * (double)((m - 9) * a) / 20.0;
        ws[OFF_EA1 + 2 * idx] = (float)cos(ang);
        ws[OFF_EA1 + 2 * idx + 1] = (float)sin(ang);
        return;
    }
    idx -= 380;
    // R7: FF2 [mi=11][a=20]  exp(-2*pi*i*(mi-5)*a/20)
    if (idx < 220) {
        int m = idx / 20, a = idx % 20;
        double ang = -2.0 * DPI * (double)((m - 5) * a) / 20.0;
        ws[OFF_FF2 + 2 * idx] = (float)cos(ang);
        ws[OFF_FF2 + 2 * idx + 1] = (float)sin(ang);
        return;
    }
    idx -= 220;
    // R8: E_A2 [m=11][a=12]  exp(+2*pi*i*(m-5)*a/12)
    if (idx < 132) {
        int m = idx / 12, a = idx % 12;
        double ang = 2.0 * DPI * (double)((m - 5) * a) / 12.0;
        ws[OFF_EA2 + 2 * idx] = (float)cos(ang);
        ws[OFF_EA2 + 2 * idx + 1] = (float)sin(ang);
        return;
    }
    idx -= 132;
    // R9: B_S2 [p=24][l=10][m=19]
    if (idx < 4560) {
        int p = idx / 190, r = idx % 190, l = r / 19, m = r % 19;
        int bi = p / 8, ai = p % 8;
        double beta = (bi + 1) * (DPI / 24.0);
        double alpha = 2.0 * DPI * ai / 8.0;
        double re = 0.0, im = 0.0;
        if (m - 9 >= -l && m - 9 <= l) {
            double d = wig_d(l, m - 9 + l, l, beta);
            double ang = -(double)(m - 9) * alpha;
            re = d * cos(ang); im = d * sin(ang);
        }
        ws[OFF_BS2 + 2 * idx] = (float)re;
        ws[OFF_BS2 + 2 * idx + 1] = (float)im;
        return;
    }
    idx -= 4560;
    // R10: B_SO3 [p=144][l=6][m=11][n=11]
    if (idx < 104544) {
        int p = idx / 726, r = idx % 726, l = r / 121, m = (r % 121) / 11, n = r % 11;
        int bi = p / 48, ai = (p % 48) / 6, gi = p % 6;
        double beta = (bi + 1) * (DPI / 24.0);
        double alpha = 2.0 * DPI * ai / 8.0;
        double gamma = 2.0 * DPI * gi / 6.0;
        double re = 0.0, im = 0.0;
        if (m - 5 >= -l && m - 5 <= l && n - 5 >= -l && n - 5 <= l) {
            double d = wig_d(l, m - 5 + l, n - 5 + l, beta);
            double ang = -((double)(m - 5) * alpha + (double)(n - 5) * gamma);
            re = d * cos(ang); im = d * sin(ang);
        }
        ws[OFF_BSO3 + 2 * idx] = (float)re;
        ws[OFF_BSO3 + 2 * idx + 1] = (float)im;
        return;
    }
}

// ---------------------------------------------------------------------------
// psi = kernel1 . B_S2  -> [o=20][l=10][m=19] complex
// ---------------------------------------------------------------------------
__global__ __launch_bounds__(256) void psi1_kernel(float* ws, const float* __restrict__ k1) {
    int idx = blockIdx.x * 256 + threadIdx.x;
    if (idx >= 3800) return;
    int o = idx / 190, r = idx % 190;
    const float2* BS2 = (const float2*)(ws + OFF_BS2);
    float2 s = {0.f, 0.f};
    for (int p = 0; p < 24; ++p) {
        float w = k1[o * 24 + p];
        float2 bv = BS2[p * 190 + r];
        s.x += w * bv.x; s.y += w * bv.y;
    }
    ((float2*)(ws + OFF_PSI))[idx] = s;
}

// ---------------------------------------------------------------------------
// psi2 = kernel2 . B_SO3 -> [i=20][o=40][l=6][m=11][n=11] complex
// ---------------------------------------------------------------------------
__global__ __launch_bounds__(256) void psi2_kernel(float* ws, const float* __restrict__ k2) {
    int idx = blockIdx.x * 256 + threadIdx.x;
    if (idx >= 580800) return;
    int i = idx / 29040, r = idx % 29040, o = r / 726, lmn = r % 726;
    const float2* BS = (const float2*)(ws + OFF_BSO3);
    float2 s = {0.f, 0.f};
    for (int p = 0; p < 144; ++p) {
        float w = k2[(i * 40 + o) * 144 + p];
        float2 bv = BS[p * 726 + lmn];
        s.x += w * bv.x; s.y += w * bv.y;
    }
    ((float2*)(ws + OFF_PSI2))[idx] = s;
}

// ---------------------------------------------------------------------------
// X[b,l,m] = sum_k W_S2_FWD[k,l,m] * (sum_t x[b,k,t] FE1[m,t])
// ---------------------------------------------------------------------------
__global__ __launch_bounds__(256) void xform1_kernel(float* ws, const float* __restrict__ x) {
    const int tid = threadIdx.x, b = blockIdx.x;
    const float2* FE1 = (const float2*)(ws + OFF_FE1);
    const float* WS2 = ws + OFF_WS2;
    float2* Xg = (float2*)(ws + OFF_X) + b * 190;
    __shared__ float xs[900];
    __shared__ float2 xm[570];
    for (int i = tid; i < 900; i += 256) xs[i] = x[b * 900 + i];
    __syncthreads();
    for (int i = tid; i < 570; i += 256) {
        int k = i / 19, m = i % 19;
        float2 s = {0.f, 0.f};
        #pragma unroll
        for (int t = 0; t < 30; ++t) {
            float v = xs[k * 30 + t];
            float2 e = FE1[m * 30 + t];
            s.x += v * e.x; s.y += v * e.y;
        }
        xm[k * 19 + m] = s;
    }
    __syncthreads();
    for (int i = tid; i < 190; i += 256) {
        int l = i / 19, m = i % 19;
        float2 s = {0.f, 0.f};
        for (int k = 0; k < 30; ++k) {
            float w = WS2[k * 190 + l * 19 + m];
            float2 v = xm[k * 19 + m];
            s.x += w * v.x; s.y += w * v.y;
        }
        Xg[i] = s;
    }
}

// ---------------------------------------------------------------------------
// stage1 v2: per (b,o). 2 k-values per pipeline pass, Z recomputed on the fly
// (no Zs buffer), X2 accumulator in registers. LDS = 23.5 KB -> 6 blocks/CU.
// ---------------------------------------------------------------------------
__global__ __launch_bounds__(256, 6) void stage1_kernel(float* ws) {
    const int tid = threadIdx.x;
    const int b = blockIdx.x / 20;
    const int o = blockIdx.x % 20;
    const float2* Xg  = (const float2*)(ws + OFF_X) + b * 190;
    const float2* Pg  = (const float2*)(ws + OFF_PSI) + o * 190;
    const float*  WI1 = ws + OFF_WINV1;
    const float*  WS3 = ws + OFF_WSO3;
    const float2* EA1 = (const float2*)(ws + OFF_EA1);
    const float2* FF2 = (const float2*)(ws + OFF_FF2);
    float2* X2g = (float2*)(ws + OFF_X2) + (b * 20 + o) * 726;

    __shared__ float2 Xs[190];
    __shared__ float2 Ps[190];
    __shared__ float2 fh[2][361];
    __shared__ float2 tt[2][380];
    __shared__ float  yy[2][400];
    __shared__ float2 uu[2][220];
    __shared__ float2 ymn[2][121];

    // register accumulator for X2 (each thread owns up to 3 of 726 items)
    const int j0 = tid, j1 = tid + 256, j2 = tid + 512;
    const int jm0 = j0 % 121, jm1 = j1 % 121;
    const bool has2 = (j2 < 726);
    const int jm2 = has2 ? (j2 % 121) : 0;
    float2 acc0 = {0.f, 0.f}, acc1 = {0.f, 0.f}, acc2 = {0.f, 0.f};

    for (int i = tid; i < 190; i += 256) { Xs[i] = Xg[i]; Ps[i] = Pg[i]; }
    __syncthreads();

    for (int kk = 0; kk < 20; kk += 2) {
        // fh[kl][m,n] = sum_l W_INV1[kk+kl,l,m,n] * X[l,m]*conj(psi[l,n])
        for (int i = tid; i < 722; i += 256) {
            int kl = i / 361, idx = i - kl * 361;
            int m = idx / 19, n = idx - m * 19;
            const float* w = WI1 + (kk + kl) * 3610 + idx;
            float2 s = {0.f, 0.f};
            #pragma unroll
            for (int l = 0; l < 10; ++l) {
                float2 a = Xs[l * 19 + m], c = Ps[l * 19 + n];
                float zr = a.x * c.x + a.y * c.y;
                float zi = a.y * c.x - a.x * c.y;
                float wv = w[l * 361];
                s.x += wv * zr; s.y += wv * zi;
            }
            fh[kl][idx] = s;
        }
        __syncthreads();
        // tt[kl][m,g] = sum_n fh[kl][m,n]*E_G1[n,g]
        for (int i = tid; i < 760; i += 256) {
            int kl = i / 380, r = i - kl * 380;
            int m = r / 20, g = r - m * 20;
            float2 s = {0.f, 0.f};
            #pragma unroll
            for (int n = 0; n < 19; ++n) {
                float2 f = fh[kl][m * 19 + n], e = EA1[n * 20 + g];
                s.x += f.x * e.x - f.y * e.y;
                s.y += f.x * e.y + f.y * e.x;
            }
            tt[kl][r] = s;
        }
        __syncthreads();
        // yy[kl][a,g] = relu(Re sum_m E_A1[m,a]*tt[kl][m,g])
        for (int i = tid; i < 800; i += 256) {
            int kl = i / 400, r = i - kl * 400;
            int a = r / 20, g = r - a * 20;
            float s = 0.f;
            #pragma unroll
            for (int m = 0; m < 19; ++m) {
                float2 e = EA1[m * 20 + a], t = tt[kl][m * 20 + g];
                s += e.x * t.x - e.y * t.y;
            }
            yy[kl][r] = s > 0.f ? s : 0.f;
        }
        __syncthreads();
        // uu[kl][mi,g] = sum_a yy[kl][a,g]*FF2[mi,a]
        for (int i = tid; i < 440; i += 256) {
            int kl = i / 220, r = i - kl * 220;
            int mi = r / 20, g = r - mi * 20;
            float2 s = {0.f, 0.f};
            #pragma unroll
            for (int a = 0; a < 20; ++a) {
                float v = yy[kl][a * 20 + g];
                float2 e = FF2[mi * 20 + a];
                s.x += v * e.x; s.y += v * e.y;
            }
            uu[kl][r] = s;
        }
        __syncthreads();
        // ymn[kl][mi,ni] = sum_g uu[kl][mi,g]*FF2[ni,g]
        if (tid < 242) {
            int kl = tid / 121, r = tid - kl * 121;
            int mi = r / 11, ni = r - mi * 11;
            float2 s = {0.f, 0.f};
            #pragma unroll
            for (int g = 0; g < 20; ++g) {
                float2 u = uu[kl][mi * 20 + g], e = FF2[ni * 20 + g];
                s.x += u.x * e.x - u.y * e.y;
                s.y += u.x * e.y + u.y * e.x;
            }
            ymn[kl][r] = s;
        }
        __syncthreads();
        // acc += W_SO3_FWD[kk+kl] * ymn[kl]   (registers; no trailing barrier:
        // next ymn write is 4 barriers away, fh/tt/... buffers are guarded)
        {
            float w0 = WS3[kk * 726 + j0], w1 = WS3[(kk + 1) * 726 + j0];
            float2 v0 = ymn[0][jm0], v1 = ymn[1][jm0];
            acc0.x += w0 * v0.x + w1 * v1.x; acc0.y += w0 * v0.y + w1 * v1.y;
            w0 = WS3[kk * 726 + j1]; w1 = WS3[(kk + 1) * 726 + j1];
            v0 = ymn[0][jm1]; v1 = ymn[1][jm1];
            acc1.x += w0 * v0.x + w1 * v1.x; acc1.y += w0 * v0.y + w1 * v1.y;
            if (has2) {
                w0 = WS3[kk * 726 + j2]; w1 = WS3[(kk + 1) * 726 + j2];
                v0 = ymn[0][jm2]; v1 = ymn[1][jm2];
                acc2.x += w0 * v0.x + w1 * v1.x; acc2.y += w0 * v0.y + w1 * v1.y;
            }
        }
    }
    X2g[j0] = acc0;
    X2g[j1] = acc1;
    if (has2) X2g[j2] = acc2;
}

// ---------------------------------------------------------------------------
// stage2 v2: per (b,o). k2 processed in two halves of 6 -> LDS 29.6 KB.
// ---------------------------------------------------------------------------
__global__ __launch_bounds__(256, 5) void stage2_kernel(float* ws) {
    const int tid = threadIdx.x;
    const int b = blockIdx.x / 40;
    const int o = blockIdx.x % 40;
    const float2* X2g = (const float2*)(ws + OFF_X2) + b * 20 * 726;
    const float2* P2g = (const float2*)(ws + OFF_PSI2);
    const float*  WI2 = ws + OFF_WINV2;
    const float2* EA2 = (const float2*)(ws + OFF_EA2);
    const float*  WIT = ws + OFF_WINT;
    float* featg = ws + OFF_FEAT;

    __shared__ float2 xi[726];
    __shared__ float2 pp[726];
    __shared__ float2 z2[726];
    __shared__ float2 fh2[726];   // [6][121] per half
    __shared__ float2 t2[792];    // [6][132] per half
    __shared__ float red[4];

    // each thread owns z2 indices tid, tid+256, tid+512(<726)
    const int i0 = tid, i1 = tid + 256, i2 = tid + 512;
    float2 a0 = {0.f, 0.f}, a1 = {0.f, 0.f}, a2 = {0.f, 0.f};
    int l, r;
    l = i0 / 121; r = i0 % 121;
    const int xo0 = l * 121 + (r / 11) * 11, po0 = l * 121 + (r % 11) * 11;
    l = i1 / 121; r = i1 % 121;
    const int xo1 = l * 121 + (r / 11) * 11, po1 = l * 121 + (r % 11) * 11;
    int xo2 = 0, po2 = 0;
    const bool has2 = (i2 < 726);
    if (has2) { l = i2 / 121; r = i2 % 121; xo2 = l * 121 + (r / 11) * 11; po2 = l * 121 + (r % 11) * 11; }

    for (int i = 0; i < 20; ++i) {
        for (int j = tid; j < 726; j += 256) {
            xi[j] = X2g[i * 726 + j];
            pp[j] = P2g[(i * 40 + o) * 726 + j];
        }
        __syncthreads();
        #pragma unroll
        for (int k = 0; k < 11; ++k) {
            float2 u = xi[xo0 + k], v = pp[po0 + k];
            a0.x += u.x * v.x + u.y * v.y; a0.y += u.y * v.x - u.x * v.y;
        }
        #pragma unroll
        for (int k = 0; k < 11; ++k) {
            float2 u = xi[xo1 + k], v = pp[po1 + k];
            a1.x += u.x * v.x + u.y * v.y; a1.y += u.y * v.x - u.x * v.y;
        }
        if (has2) {
            #pragma unroll
            for (int k = 0; k < 11; ++k) {
                float2 u = xi[xo2 + k], v = pp[po2 + k];
                a2.x += u.x * v.x + u.y * v.y; a2.y += u.y * v.x - u.x * v.y;
            }
        }
        __syncthreads();
    }
    z2[i0] = a0;
    z2[i1] = a1;
    if (has2) z2[i2] = a2;
    __syncthreads();

    float partial = 0.f;
    for (int h = 0; h < 2; ++h) {
        // fh2[k2h,m,n] = sum_l W_INV2[h*6+k2h,l,m,n]*z2[l,m,n]
        for (int i = tid; i < 726; i += 256) {
            int k2h = i / 121, rr = i - k2h * 121;
            int k2 = h * 6 + k2h;
            float2 s = {0.f, 0.f};
            #pragma unroll
            for (int ll = 0; ll < 6; ++ll) {
                float w = WI2[k2 * 726 + ll * 121 + rr];
                float2 z = z2[ll * 121 + rr];
                s.x += w * z.x; s.y += w * z.y;
            }
            fh2[i] = s;
        }
        __syncthreads();
        // t2[k2h,m,g] = sum_n fh2[k2h,m,n]*E_A2[n,g]
        for (int i = tid; i < 792; i += 256) {
            int k2h = i / 132, rr = i - k2h * 132, m = rr / 12, g = rr - m * 12;
            float2 s = {0.f, 0.f};
            #pragma unroll
            for (int n = 0; n < 11; ++n) {
                float2 f = fh2[k2h * 121 + m * 11 + n], e = EA2[n * 12 + g];
                s.x += f.x * e.x - f.y * e.y;
                s.y += f.x * e.y + f.y * e.x;
            }
            t2[i] = s;
        }
        __syncthreads();
        // partial += W_INT[k2]*relu(Re sum_m E_A2[m,a]*t2[k2h,m,g])
        for (int i = tid; i < 864; i += 256) {
            int k2h = i / 144, rr = i - k2h * 144, a = rr / 12, g = rr - a * 12;
            float s = 0.f;
            #pragma unroll
            for (int m = 0; m < 11; ++m) {
                float2 e = EA2[m * 12 + a], t = t2[k2h * 132 + m * 12 + g];
                s += e.x * t.x - e.y * t.y;
            }
            if (s > 0.f) partial += WIT[h * 6 + k2h] * s;
        }
        __syncthreads();  // guard fh2/t2 rewrite in next half
    }
    for (int off = 32; off > 0; off >>= 1) partial += __shfl_down(partial, off, 64);
    if ((tid & 63) == 0) red[tid >> 6] = partial;
    __syncthreads();
    if (tid == 0) featg[b * 40 + o] = (red[0] + red[1] + red[2] + red[3]) * (1.0f / 144.0f);
}

// ---------------------------------------------------------------------------
// out[b,f] = sum_o feat[b,o]*w_lin[f,o] + b_lin[f]
// ---------------------------------------------------------------------------
__global__ __launch_bounds__(256) void final_kernel(const float* __restrict__ ws,
                                                    const float* __restrict__ wl,
                                                    const float* __restrict__ bl,
                                                    float* __restrict__ out) {
    int idx = blockIdx.x * 256 + threadIdx.x;
    if (idx >= 1280) return;
    int b = idx / 10, f = idx % 10;
    const float* feat = ws + OFF_FEAT;
    float s = bl[f];
    for (int o = 0; o < 40; ++o) s += feat[b * 40 + o] * wl[f * 40 + o];
    out[idx] = s;
}

// ---------------------------------------------------------------------------
extern "C" void kernel_launch(void* const* d_in, const int* in_sizes, int n_in,
                              void* d_out, int out_size, void* d_ws, size_t ws_size,
                              hipStream_t stream) {
    (void)in_sizes; (void)n_in; (void)out_size; (void)ws_size;
    const float* x  = (const float*)d_in[0];
    const float* k1 = (const float*)d_in[1];
    const float* k2 = (const float*)d_in[2];
    const float* wl = (const float*)d_in[3];
    const float* bl = (const float*)d_in[4];
    float* out = (float*)d_out;
    float* ws  = (float*)d_ws;

    build_tables_kernel<<<827, 256, 0, stream>>>(ws);           // 211550 elems
    psi1_kernel<<<15, 256, 0, stream>>>(ws, k1);                // 3800
    xform1_kernel<<<128, 256, 0, stream>>>(ws, x);              // per-batch
    psi2_kernel<<<2269, 256, 0, stream>>>(ws, k2);              // 580800
    stage1_kernel<<<128 * 20, 256, 0, stream>>>(ws);
    stage2_kernel<<<128 * 40, 256, 0, stream>>>(ws);
    final_kernel<<<5, 256, 0, stream>>>(ws, wl, bl, out);
}

// Round 3
// 985.694 us; speedup vs baseline: 1.5863x; 1.5863x over previous
//
#include <hip/hip_runtime.h>
#include <math.h>

// ---------------------------------------------------------------------------
// Problem dims: B_IN=15, B1=10, B2=6, F1=20, F2=40, F_OUT=10
// M1=19, C1=9, M2=11, C2=5, batch=128
// ---------------------------------------------------------------------------

// workspace layout (offsets in floats; all even -> float2 aligned)
constexpr int OFF_WS2   = 0;                     // W_S2_FWD  [30][10][19]
constexpr int OFF_WINV1 = OFF_WS2   + 5700;      // W_INV1    [20][10][19][19]
constexpr int OFF_WSO3  = OFF_WINV1 + 72200;     // W_SO3_FWD [20][6][11][11]
constexpr int OFF_WINV2 = OFF_WSO3  + 14520;     // W_INV2    [12][6][11][11]
constexpr int OFF_WINT  = OFF_WINV2 + 8712;      // W_INT     [12] (+pad)
constexpr int OFF_FE1   = OFF_WINT  + 16;        // FE1  cplx [19][30]
constexpr int OFF_EA1   = OFF_FE1   + 1140;      // E_A1 cplx [19][20]
constexpr int OFF_FF2   = OFF_EA1   + 760;       // FF2  cplx [11][20]
constexpr int OFF_EA2   = OFF_FF2   + 440;       // E_A2 cplx [11][12]
constexpr int OFF_BS2   = OFF_EA2   + 264;       // B_S2 cplx [24][10][19]
constexpr int OFF_BSO3  = OFF_BS2   + 9120;      // B_SO3 cplx[144][6][11][11]
constexpr int OFF_PSI   = OFF_BSO3  + 209088;    // psi  cplx [20][10][19]
constexpr int OFF_X     = OFF_PSI   + 7600;      // X    cplx [128][10][19]
constexpr int OFF_X2    = OFF_X     + 48640;     // X2   cplx [128][20][6][11][11]
constexpr int OFF_PSI2  = OFF_X2    + 3717120;   // psi2 cplx [20][40][6][11][11]
constexpr int OFF_FEAT  = OFF_PSI2  + 1161600;   // feat      [128][40]
// total = OFF_FEAT + 5120 = 5,262,040 floats  (~21.0 MB)

#define DPI 3.14159265358979323846

// ---------------------------------------------------------------------------
// table-building helpers (double precision, matches numpy reference)
// ---------------------------------------------------------------------------
__device__ __forceinline__ double dfact(int n) {
    double f = 1.0;
    for (int i = 2; i <= n; ++i) f *= (double)i;
    return f;
}
__device__ __forceinline__ double dpowi(double x, int n) {
    double r = 1.0;
    for (int i = 0; i < n; ++i) r *= x;
    return r;
}
__device__ double wig_d(int l, int mi, int ni, double beta) {
    // mi, ni in 0..2l ; m = mi-l, n = ni-l
    int m = mi - l, n = ni - l;
    double cb = cos(0.5 * beta), sb = sin(0.5 * beta);
    double pref = sqrt(dfact(l + m) * dfact(l - m) * dfact(l + n) * dfact(l - n));
    int s0 = (n - m) > 0 ? (n - m) : 0;
    int s1 = (l + n) < (l - m) ? (l + n) : (l - m);
    double v = 0.0;
    for (int s = s0; s <= s1; ++s) {
        double term = dpowi(cb, 2 * l + n - m - 2 * s) * dpowi(sb, m - n + 2 * s) /
                      (dfact(l + n - s) * dfact(s) * dfact(m - n + s) * dfact(l - m - s));
        v += ((m - n + s) & 1) ? -term : term;
    }
    return pref * v;
}
__device__ double wig_pad(int l, int m, int n, int c, double beta) {
    if (m < c - l || m > c + l || n < c - l || n > c + l) return 0.0;
    return wig_d(l, m - (c - l), n - (c - l), beta);
}
__device__ double quad_w(int b, int k) {
    double beta = DPI * (2 * k + 1) / (4.0 * b);
    double s = 0.0;
    for (int j = 0; j < b; ++j) s += sin((2 * j + 1) * beta) / (double)(2 * j + 1);
    return 2.0 / b * sin(beta) * s;
}

// total element ids: 5700+72200+14520+8712+12+570+380+220+132+4560+104544 = 211550
__global__ __launch_bounds__(256) void build_tables_kernel(float* ws) {
    int idx = blockIdx.x * 256 + threadIdx.x;
    // R0: W_S2_FWD [k=30][l=10][m=19]
    if (idx < 5700) {
        int k = idx / 190, r = idx % 190, l = r / 19, m = r % 19;
        double beta = DPI * (2 * k + 1) / 60.0;
        ws[OFF_WS2 + idx] = (float)(quad_w(15, k) * wig_pad(l, m, 9, 9, beta));
        return;
    }
    idx -= 5700;
    // R1: W_INV1 [k=20][l=10][m=19][n=19]
    if (idx < 72200) {
        int k = idx / 3610, r = idx % 3610, l = r / 361, r2 = r % 361, m = r2 / 19, n = r2 % 19;
        double beta = DPI * (2 * k + 1) / 40.0;
        ws[OFF_WINV1 + idx] = (float)((2 * l + 1) * wig_pad(l, m, n, 9, beta));
        return;
    }
    idx -= 72200;
    // R2: W_SO3_FWD [k=20][l=6][m=11][n=11]
    if (idx < 14520) {
        int k = idx / 726, r = idx % 726, l = r / 121, m = (r % 121) / 11, n = r % 11;
        double beta = DPI * (2 * k + 1) / 40.0;
        ws[OFF_WSO3 + idx] = (float)(quad_w(10, k) * wig_pad(l, m, n, 5, beta));
        return;
    }
    idx -= 14520;
    // R3: W_INV2 [k=12][l=6][11][11]
    if (idx < 8712) {
        int k = idx / 726, r = idx % 726, l = r / 121, m = (r % 121) / 11, n = r % 11;
        double beta = DPI * (2 * k + 1) / 24.0;
        ws[OFF_WINV2 + idx] = (float)((2 * l + 1) * wig_pad(l, m, n, 5, beta));
        return;
    }
    idx -= 8712;
    // R4: W_INT [12]
    if (idx < 12) { ws[OFF_WINT + idx] = (float)quad_w(6, idx); return; }
    idx -= 12;
    // R5: FE1 [m=19][t=30]  exp(-2*pi*i*(m-9)*t/30)
    if (idx < 570) {
        int m = idx / 30, t = idx % 30;
        double ang = -2.0 * DPI * (double)((m - 9) * t) / 30.0;
        ws[OFF_FE1 + 2 * idx] = (float)cos(ang);
        ws[OFF_FE1 + 2 * idx + 1] = (float)sin(ang);
        return;
    }
    idx -= 570;
    // R6: E_A1 [m=19][a=20]  exp(+2*pi*i*(m-9)*a/20)
    if (idx < 380) {
        int m = idx / 20, a = idx % 20;
        double ang = 2.0 * DPI * (double)((m - 9) * a) / 20.0;
        ws[OFF_EA1 + 2 * idx] = (float)cos(ang);
        ws[OFF_EA1 + 2 * idx + 1] = (float)sin(ang);
        return;
    }
    idx -= 380;
    // R7: FF2 [mi=11][a=20]  exp(-2*pi*i*(mi-5)*a/20)
    if (idx < 220) {
        int m = idx / 20, a = idx % 20;
        double ang = -2.0 * DPI * (double)((m - 5) * a) / 20.0;
        ws[OFF_FF2 + 2 * idx] = (float)cos(ang);
        ws[OFF_FF2 + 2 * idx + 1] = (float)sin(ang);
        return;
    }
    idx -= 220;
    // R8: E_A2 [m=11][a=12]  exp(+2*pi*i*(m-5)*a/12)
    if (idx < 132) {
        int m = idx / 12, a = idx % 12;
        double ang = 2.0 * DPI * (double)((m - 5) * a) / 12.0;
        ws[OFF_EA2 + 2 * idx] = (float)cos(ang);
        ws[OFF_EA2 + 2 * idx + 1] = (float)sin(ang);
        return;
    }
    idx -= 132;
    // R9: B_S2 [p=24][l=10][m=19]
    if (idx < 4560) {
        int p = idx / 190, r = idx % 190, l = r / 19, m = r % 19;
        int bi = p / 8, ai = p % 8;
        double beta = (bi + 1) * (DPI / 24.0);
        double alpha = 2.0 * DPI * ai / 8.0;
        double re = 0.0, im = 0.0;
        if (m - 9 >= -l && m - 9 <= l) {
            double d = wig_d(l, m - 9 + l, l, beta);
            double ang = -(double)(m - 9) * alpha;
            re = d * cos(ang); im = d * sin(ang);
        }
        ws[OFF_BS2 + 2 * idx] = (float)re;
        ws[OFF_BS2 + 2 * idx + 1] = (float)im;
        return;
    }
    idx -= 4560;
    // R10: B_SO3 [p=144][l=6][m=11][n=11]
    if (idx < 104544) {
        int p = idx / 726, r = idx % 726, l = r / 121, m = (r % 121) / 11, n = r % 11;
        int bi = p / 48, ai = (p % 48) / 6, gi = p % 6;
        double beta = (bi + 1) * (DPI / 24.0);
        double alpha = 2.0 * DPI * ai / 8.0;
        double gamma = 2.0 * DPI * gi / 6.0;
        double re = 0.0, im = 0.0;
        if (m - 5 >= -l && m - 5 <= l && n - 5 >= -l && n - 5 <= l) {
            double d = wig_d(l, m - 5 + l, n - 5 + l, beta);
            double ang = -((double)(m - 5) * alpha + (double)(n - 5) * gamma);
            re = d * cos(ang); im = d * sin(ang);
        }
        ws[OFF_BSO3 + 2 * idx] = (float)re;
        ws[OFF_BSO3 + 2 * idx + 1] = (float)im;
        return;
    }
}

// ---------------------------------------------------------------------------
// psi = kernel1 . B_S2  -> [o=20][l=10][m=19] complex
// ---------------------------------------------------------------------------
__global__ __launch_bounds__(256) void psi1_kernel(float* ws, const float* __restrict__ k1) {
    int idx = blockIdx.x * 256 + threadIdx.x;
    if (idx >= 3800) return;
    int o = idx / 190, r = idx % 190;
    const float2* BS2 = (const float2*)(ws + OFF_BS2);
    float2 s = {0.f, 0.f};
    for (int p = 0; p < 24; ++p) {
        float w = k1[o * 24 + p];
        float2 bv = BS2[p * 190 + r];
        s.x += w * bv.x; s.y += w * bv.y;
    }
    ((float2*)(ws + OFF_PSI))[idx] = s;
}

// ---------------------------------------------------------------------------
// psi2 = kernel2 . B_SO3 -> [i=20][o=40][l=6][m=11][n=11] complex
// ---------------------------------------------------------------------------
__global__ __launch_bounds__(256) void psi2_kernel(float* ws, const float* __restrict__ k2) {
    int idx = blockIdx.x * 256 + threadIdx.x;
    if (idx >= 580800) return;
    int i = idx / 29040, r = idx % 29040, o = r / 726, lmn = r % 726;
    const float2* BS = (const float2*)(ws + OFF_BSO3);
    float2 s = {0.f, 0.f};
    for (int p = 0; p < 144; ++p) {
        float w = k2[(i * 40 + o) * 144 + p];
        float2 bv = BS[p * 726 + lmn];
        s.x += w * bv.x; s.y += w * bv.y;
    }
    ((float2*)(ws + OFF_PSI2))[idx] = s;
}

// ---------------------------------------------------------------------------
// X[b,l,m] = sum_k W_S2_FWD[k,l,m] * (sum_t x[b,k,t] FE1[m,t])
// ---------------------------------------------------------------------------
__global__ __launch_bounds__(256) void xform1_kernel(float* ws, const float* __restrict__ x) {
    const int tid = threadIdx.x, b = blockIdx.x;
    const float2* FE1 = (const float2*)(ws + OFF_FE1);
    const float* WS2 = ws + OFF_WS2;
    float2* Xg = (float2*)(ws + OFF_X) + b * 190;
    __shared__ float xs[900];
    __shared__ float2 xm[570];
    for (int i = tid; i < 900; i += 256) xs[i] = x[b * 900 + i];
    __syncthreads();
    for (int i = tid; i < 570; i += 256) {
        int k = i / 19, m = i % 19;
        float2 s = {0.f, 0.f};
        #pragma unroll
        for (int t = 0; t < 30; ++t) {
            float v = xs[k * 30 + t];
            float2 e = FE1[m * 30 + t];
            s.x += v * e.x; s.y += v * e.y;
        }
        xm[k * 19 + m] = s;
    }
    __syncthreads();
    for (int i = tid; i < 190; i += 256) {
        int l = i / 19, m = i % 19;
        float2 s = {0.f, 0.f};
        for (int k = 0; k < 30; ++k) {
            float w = WS2[k * 190 + l * 19 + m];
            float2 v = xm[k * 19 + m];
            s.x += w * v.x; s.y += w * v.y;
        }
        Xg[i] = s;
    }
}

// ---------------------------------------------------------------------------
// stage1 v2: per (b,o). 2 k-values per pipeline pass, Z recomputed on the fly
// (no Zs buffer), X2 accumulator in registers. LDS = 23.5 KB -> 6 blocks/CU.
// ---------------------------------------------------------------------------
__global__ __launch_bounds__(256, 6) void stage1_kernel(float* ws) {
    const int tid = threadIdx.x;
    const int b = blockIdx.x / 20;
    const int o = blockIdx.x % 20;
    const float2* Xg  = (const float2*)(ws + OFF_X) + b * 190;
    const float2* Pg  = (const float2*)(ws + OFF_PSI) + o * 190;
    const float*  WI1 = ws + OFF_WINV1;
    const float*  WS3 = ws + OFF_WSO3;
    const float2* EA1 = (const float2*)(ws + OFF_EA1);
    const float2* FF2 = (const float2*)(ws + OFF_FF2);
    float2* X2g = (float2*)(ws + OFF_X2) + (b * 20 + o) * 726;

    __shared__ float2 Xs[190];
    __shared__ float2 Ps[190];
    __shared__ float2 fh[2][361];
    __shared__ float2 tt[2][380];
    __shared__ float  yy[2][400];
    __shared__ float2 uu[2][220];
    __shared__ float2 ymn[2][121];

    // register accumulator for X2 (each thread owns up to 3 of 726 items)
    const int j0 = tid, j1 = tid + 256, j2 = tid + 512;
    const int jm0 = j0 % 121, jm1 = j1 % 121;
    const bool has2 = (j2 < 726);
    const int jm2 = has2 ? (j2 % 121) : 0;
    float2 acc0 = {0.f, 0.f}, acc1 = {0.f, 0.f}, acc2 = {0.f, 0.f};

    for (int i = tid; i < 190; i += 256) { Xs[i] = Xg[i]; Ps[i] = Pg[i]; }
    __syncthreads();

    for (int kk = 0; kk < 20; kk += 2) {
        // fh[kl][m,n] = sum_l W_INV1[kk+kl,l,m,n] * X[l,m]*conj(psi[l,n])
        for (int i = tid; i < 722; i += 256) {
            int kl = i / 361, idx = i - kl * 361;
            int m = idx / 19, n = idx - m * 19;
            const float* w = WI1 + (kk + kl) * 3610 + idx;
            float2 s = {0.f, 0.f};
            #pragma unroll
            for (int l = 0; l < 10; ++l) {
                float2 a = Xs[l * 19 + m], c = Ps[l * 19 + n];
                float zr = a.x * c.x + a.y * c.y;
                float zi = a.y * c.x - a.x * c.y;
                float wv = w[l * 361];
                s.x += wv * zr; s.y += wv * zi;
            }
            fh[kl][idx] = s;
        }
        __syncthreads();
        // tt[kl][m,g] = sum_n fh[kl][m,n]*E_G1[n,g]
        for (int i = tid; i < 760; i += 256) {
            int kl = i / 380, r = i - kl * 380;
            int m = r / 20, g = r - m * 20;
            float2 s = {0.f, 0.f};
            #pragma unroll
            for (int n = 0; n < 19; ++n) {
                float2 f = fh[kl][m * 19 + n], e = EA1[n * 20 + g];
                s.x += f.x * e.x - f.y * e.y;
                s.y += f.x * e.y + f.y * e.x;
            }
            tt[kl][r] = s;
        }
        __syncthreads();
        // yy[kl][a,g] = relu(Re sum_m E_A1[m,a]*tt[kl][m,g])
        for (int i = tid; i < 800; i += 256) {
            int kl = i / 400, r = i - kl * 400;
            int a = r / 20, g = r - a * 20;
            float s = 0.f;
            #pragma unroll
            for (int m = 0; m < 19; ++m) {
                float2 e = EA1[m * 20 + a], t = tt[kl][m * 20 + g];
                s += e.x * t.x - e.y * t.y;
            }
            yy[kl][r] = s > 0.f ? s : 0.f;
        }
        __syncthreads();
        // uu[kl][mi,g] = sum_a yy[kl][a,g]*FF2[mi,a]
        for (int i = tid; i < 440; i += 256) {
            int kl = i / 220, r = i - kl * 220;
            int mi = r / 20, g = r - mi * 20;
            float2 s = {0.f, 0.f};
            #pragma unroll
            for (int a = 0; a < 20; ++a) {
                float v = yy[kl][a * 20 + g];
                float2 e = FF2[mi * 20 + a];
                s.x += v * e.x; s.y += v * e.y;
            }
            uu[kl][r] = s;
        }
        __syncthreads();
        // ymn[kl][mi,ni] = sum_g uu[kl][mi,g]*FF2[ni,g]
        if (tid < 242) {
            int kl = tid / 121, r = tid - kl * 121;
            int mi = r / 11, ni = r - mi * 11;
            float2 s = {0.f, 0.f};
            #pragma unroll
            for (int g = 0; g < 20; ++g) {
                float2 u = uu[kl][mi * 20 + g], e = FF2[ni * 20 + g];
                s.x += u.x * e.x - u.y * e.y;
                s.y += u.x * e.y + u.y * e.x;
            }
            ymn[kl][r] = s;
        }
        __syncthreads();
        // acc += W_SO3_FWD[kk+kl] * ymn[kl]   (registers; no trailing barrier:
        // next ymn write is 4 barriers away, fh/tt/... buffers are guarded)
        {
            float w0 = WS3[kk * 726 + j0], w1 = WS3[(kk + 1) * 726 + j0];
            float2 v0 = ymn[0][jm0], v1 = ymn[1][jm0];
            acc0.x += w0 * v0.x + w1 * v1.x; acc0.y += w0 * v0.y + w1 * v1.y;
            w0 = WS3[kk * 726 + j1]; w1 = WS3[(kk + 1) * 726 + j1];
            v0 = ymn[0][jm1]; v1 = ymn[1][jm1];
            acc1.x += w0 * v0.x + w1 * v1.x; acc1.y += w0 * v0.y + w1 * v1.y;
            if (has2) {
                w0 = WS3[kk * 726 + j2]; w1 = WS3[(kk + 1) * 726 + j2];
                v0 = ymn[0][jm2]; v1 = ymn[1][jm2];
                acc2.x += w0 * v0.x + w1 * v1.x; acc2.y += w0 * v0.y + w1 * v1.y;
            }
        }
    }
    X2g[j0] = acc0;
    X2g[j1] = acc1;
    if (has2) X2g[j2] = acc2;
}

// ---------------------------------------------------------------------------
// stage2 v3: per (b,o). k2 processed in two halves of 6 -> LDS 29.6 KB.
// NO min-waves launch bound: the (256,5) bound in v2 forced VGPR_Count=48 and
// the compiler spilled the i-loop accumulators to scratch (3.1 GB WRITE_SIZE,
// 983 us). Let the allocator pick its natural budget (round-1 ran spill-free).
// ---------------------------------------------------------------------------
__global__ __launch_bounds__(256) void stage2_kernel(float* ws) {
    const int tid = threadIdx.x;
    const int b = blockIdx.x / 40;
    const int o = blockIdx.x % 40;
    const float2* X2g = (const float2*)(ws + OFF_X2) + b * 20 * 726;
    const float2* P2g = (const float2*)(ws + OFF_PSI2);
    const float*  WI2 = ws + OFF_WINV2;
    const float2* EA2 = (const float2*)(ws + OFF_EA2);
    const float*  WIT = ws + OFF_WINT;
    float* featg = ws + OFF_FEAT;

    __shared__ float2 xi[726];
    __shared__ float2 pp[726];
    __shared__ float2 z2[726];
    __shared__ float2 fh2[726];   // [6][121] per half
    __shared__ float2 t2[792];    // [6][132] per half
    __shared__ float red[4];

    // each thread owns z2 indices tid, tid+256, tid+512(<726)
    const int i0 = tid, i1 = tid + 256, i2 = tid + 512;
    float2 a0 = {0.f, 0.f}, a1 = {0.f, 0.f}, a2 = {0.f, 0.f};
    int l, r;
    l = i0 / 121; r = i0 % 121;
    const int xo0 = l * 121 + (r / 11) * 11, po0 = l * 121 + (r % 11) * 11;
    l = i1 / 121; r = i1 % 121;
    const int xo1 = l * 121 + (r / 11) * 11, po1 = l * 121 + (r % 11) * 11;
    int xo2 = 0, po2 = 0;
    const bool has2 = (i2 < 726);
    if (has2) { l = i2 / 121; r = i2 % 121; xo2 = l * 121 + (r / 11) * 11; po2 = l * 121 + (r % 11) * 11; }

    for (int i = 0; i < 20; ++i) {
        for (int j = tid; j < 726; j += 256) {
            xi[j] = X2g[i * 726 + j];
            pp[j] = P2g[(i * 40 + o) * 726 + j];
        }
        __syncthreads();
        #pragma unroll
        for (int k = 0; k < 11; ++k) {
            float2 u = xi[xo0 + k], v = pp[po0 + k];
            a0.x += u.x * v.x + u.y * v.y; a0.y += u.y * v.x - u.x * v.y;
        }
        #pragma unroll
        for (int k = 0; k < 11; ++k) {
            float2 u = xi[xo1 + k], v = pp[po1 + k];
            a1.x += u.x * v.x + u.y * v.y; a1.y += u.y * v.x - u.x * v.y;
        }
        if (has2) {
            #pragma unroll
            for (int k = 0; k < 11; ++k) {
                float2 u = xi[xo2 + k], v = pp[po2 + k];
                a2.x += u.x * v.x + u.y * v.y; a2.y += u.y * v.x - u.x * v.y;
            }
        }
        __syncthreads();
    }
    z2[i0] = a0;
    z2[i1] = a1;
    if (has2) z2[i2] = a2;
    __syncthreads();

    float partial = 0.f;
    for (int h = 0; h < 2; ++h) {
        // fh2[k2h,m,n] = sum_l W_INV2[h*6+k2h,l,m,n]*z2[l,m,n]
        for (int i = tid; i < 726; i += 256) {
            int k2h = i / 121, rr = i - k2h * 121;
            int k2 = h * 6 + k2h;
            float2 s = {0.f, 0.f};
            #pragma unroll
            for (int ll = 0; ll < 6; ++ll) {
                float w = WI2[k2 * 726 + ll * 121 + rr];
                float2 z = z2[ll * 121 + rr];
                s.x += w * z.x; s.y += w * z.y;
            }
            fh2[i] = s;
        }
        __syncthreads();
        // t2[k2h,m,g] = sum_n fh2[k2h,m,n]*E_A2[n,g]
        for (int i = tid; i < 792; i += 256) {
            int k2h = i / 132, rr = i - k2h * 132, m = rr / 12, g = rr - m * 12;
            float2 s = {0.f, 0.f};
            #pragma unroll
            for (int n = 0; n < 11; ++n) {
                float2 f = fh2[k2h * 121 + m * 11 + n], e = EA2[n * 12 + g];
                s.x += f.x * e.x - f.y * e.y;
                s.y += f.x * e.y + f.y * e.x;
            }
            t2[i] = s;
        }
        __syncthreads();
        // partial += W_INT[k2]*relu(Re sum_m E_A2[m,a]*t2[k2h,m,g])
        for (int i = tid; i < 864; i += 256) {
            int k2h = i / 144, rr = i - k2h * 144, a = rr / 12, g = rr - a * 12;
            float s = 0.f;
            #pragma unroll
            for (int m = 0; m < 11; ++m) {
                float2 e = EA2[m * 12 + a], t = t2[k2h * 132 + m * 12 + g];
                s += e.x * t.x - e.y * t.y;
            }
            if (s > 0.f) partial += WIT[h * 6 + k2h] * s;
        }
        __syncthreads();  // guard fh2/t2 rewrite in next half
    }
    for (int off = 32; off > 0; off >>= 1) partial += __shfl_down(partial, off, 64);
    if ((tid & 63) == 0) red[tid >> 6] = partial;
    __syncthreads();
    if (tid == 0) featg[b * 40 + o] = (red[0] + red[1] + red[2] + red[3]) * (1.0f / 144.0f);
}

// ---------------------------------------------------------------------------
// out[b,f] = sum_o feat[b,o]*w_lin[f,o] + b_lin[f]
// ---------------------------------------------------------------------------
__global__ __launch_bounds__(256) void final_kernel(const float* __restrict__ ws,
                                                    const float* __restrict__ wl,
                                                    const float* __restrict__ bl,
                                                    float* __restrict__ out) {
    int idx = blockIdx.x * 256 + threadIdx.x;
    if (idx >= 1280) return;
    int b = idx / 10, f = idx % 10;
    const float* feat = ws + OFF_FEAT;
    float s = bl[f];
    for (int o = 0; o < 40; ++o) s += feat[b * 40 + o] * wl[f * 40 + o];
    out[idx] = s;
}

// ---------------------------------------------------------------------------
extern "C" void kernel_launch(void* const* d_in, const int* in_sizes, int n_in,
                              void* d_out, int out_size, void* d_ws, size_t ws_size,
                              hipStream_t stream) {
    (void)in_sizes; (void)n_in; (void)out_size; (void)ws_size;
    const float* x  = (const float*)d_in[0];
    const float* k1 = (const float*)d_in[1];
    const float* k2 = (const float*)d_in[2];
    const float* wl = (const float*)d_in[3];
    const float* bl = (const float*)d_in[4];
    float* out = (float*)d_out;
    float* ws  = (float*)d_ws;

    build_tables_kernel<<<827, 256, 0, stream>>>(ws);           // 211550 elems
    psi1_kernel<<<15, 256, 0, stream>>>(ws, k1);                // 3800
    xform1_kernel<<<128, 256, 0, stream>>>(ws, x);              // per-batch
    psi2_kernel<<<2269, 256, 0, stream>>>(ws, k2);              // 580800
    stage1_kernel<<<128 * 20, 256, 0, stream>>>(ws);
    stage2_kernel<<<128 * 40, 256, 0, stream>>>(ws);
    final_kernel<<<5, 256, 0, stream>>>(ws, wl, bl, out);
}

// Round 4
// 872.422 us; speedup vs baseline: 1.7922x; 1.1298x over previous
//
#include <hip/hip_runtime.h>
#include <math.h>

// ---------------------------------------------------------------------------
// Problem dims: B_IN=15, B1=10, B2=6, F1=20, F2=40, F_OUT=10
// M1=19, C1=9, M2=11, C2=5, batch=128
// ---------------------------------------------------------------------------

// workspace layout (offsets in floats; all even -> float2 aligned)
constexpr int OFF_WS2   = 0;                     // W_S2_FWD  [30][10][19]
constexpr int OFF_WINV1 = OFF_WS2   + 5700;      // W_INV1    [20][10][19][19]
constexpr int OFF_WSO3  = OFF_WINV1 + 72200;     // W_SO3_FWD [20][6][11][11]
constexpr int OFF_WINV2 = OFF_WSO3  + 14520;     // W_INV2    [12][6][11][11]
constexpr int OFF_WINT  = OFF_WINV2 + 8712;      // W_INT     [12] (+pad)
constexpr int OFF_FE1   = OFF_WINT  + 16;        // FE1  cplx [19][30]
constexpr int OFF_EA1   = OFF_FE1   + 1140;      // E_A1 cplx [19][20]
constexpr int OFF_FF2   = OFF_EA1   + 760;       // FF2  cplx [11][20]
constexpr int OFF_EA2   = OFF_FF2   + 440;       // E_A2 cplx [11][12]
constexpr int OFF_BS2   = OFF_EA2   + 264;       // B_S2 cplx [24][10][19]
constexpr int OFF_BSO3  = OFF_BS2   + 9120;      // B_SO3 cplx[144][6][11][11]
constexpr int OFF_PSI   = OFF_BSO3  + 209088;    // psi  cplx [20][10][19]
constexpr int OFF_X     = OFF_PSI   + 7600;      // X    cplx [128][10][19]
constexpr int OFF_X2    = OFF_X     + 48640;     // X2   cplx [128][20][6][11][11]
constexpr int OFF_PSI2  = OFF_X2    + 3717120;   // psi2 cplx [20][40][6][11][11]
constexpr int OFF_FEAT  = OFF_PSI2  + 1161600;   // feat      [128][40]
// total = OFF_FEAT + 5120 = 5,262,040 floats  (~21.0 MB)

#define DPI 3.14159265358979323846

// ---------------------------------------------------------------------------
// table-building helpers (double precision, matches numpy reference)
// ---------------------------------------------------------------------------
__device__ __forceinline__ double dfact(int n) {
    double f = 1.0;
    for (int i = 2; i <= n; ++i) f *= (double)i;
    return f;
}
__device__ __forceinline__ double dpowi(double x, int n) {
    double r = 1.0;
    for (int i = 0; i < n; ++i) r *= x;
    return r;
}
__device__ double wig_d(int l, int mi, int ni, double beta) {
    // mi, ni in 0..2l ; m = mi-l, n = ni-l
    int m = mi - l, n = ni - l;
    double cb = cos(0.5 * beta), sb = sin(0.5 * beta);
    double pref = sqrt(dfact(l + m) * dfact(l - m) * dfact(l + n) * dfact(l - n));
    int s0 = (n - m) > 0 ? (n - m) : 0;
    int s1 = (l + n) < (l - m) ? (l + n) : (l - m);
    double v = 0.0;
    for (int s = s0; s <= s1; ++s) {
        double term = dpowi(cb, 2 * l + n - m - 2 * s) * dpowi(sb, m - n + 2 * s) /
                      (dfact(l + n - s) * dfact(s) * dfact(m - n + s) * dfact(l - m - s));
        v += ((m - n + s) & 1) ? -term : term;
    }
    return pref * v;
}
__device__ double wig_pad(int l, int m, int n, int c, double beta) {
    if (m < c - l || m > c + l || n < c - l || n > c + l) return 0.0;
    return wig_d(l, m - (c - l), n - (c - l), beta);
}
__device__ double quad_w(int b, int k) {
    double beta = DPI * (2 * k + 1) / (4.0 * b);
    double s = 0.0;
    for (int j = 0; j < b; ++j) s += sin((2 * j + 1) * beta) / (double)(2 * j + 1);
    return 2.0 / b * sin(beta) * s;
}

// total element ids: 5700+72200+14520+8712+12+570+380+220+132+4560+104544 = 211550
__global__ __launch_bounds__(256) void build_tables_kernel(float* ws) {
    int idx = blockIdx.x * 256 + threadIdx.x;
    // R0: W_S2_FWD [k=30][l=10][m=19]
    if (idx < 5700) {
        int k = idx / 190, r = idx % 190, l = r / 19, m = r % 19;
        double beta = DPI * (2 * k + 1) / 60.0;
        ws[OFF_WS2 + idx] = (float)(quad_w(15, k) * wig_pad(l, m, 9, 9, beta));
        return;
    }
    idx -= 5700;
    // R1: W_INV1 [k=20][l=10][m=19][n=19]
    if (idx < 72200) {
        int k = idx / 3610, r = idx % 3610, l = r / 361, r2 = r % 361, m = r2 / 19, n = r2 % 19;
        double beta = DPI * (2 * k + 1) / 40.0;
        ws[OFF_WINV1 + idx] = (float)((2 * l + 1) * wig_pad(l, m, n, 9, beta));
        return;
    }
    idx -= 72200;
    // R2: W_SO3_FWD [k=20][l=6][m=11][n=11]
    if (idx < 14520) {
        int k = idx / 726, r = idx % 726, l = r / 121, m = (r % 121) / 11, n = r % 11;
        double beta = DPI * (2 * k + 1) / 40.0;
        ws[OFF_WSO3 + idx] = (float)(quad_w(10, k) * wig_pad(l, m, n, 5, beta));
        return;
    }
    idx -= 14520;
    // R3: W_INV2 [k=12][l=6][11][11]
    if (idx < 8712) {
        int k = idx / 726, r = idx % 726, l = r / 121, m = (r % 121) / 11, n = r % 11;
        double beta = DPI * (2 * k + 1) / 24.0;
        ws[OFF_WINV2 + idx] = (float)((2 * l + 1) * wig_pad(l, m, n, 5, beta));
        return;
    }
    idx -= 8712;
    // R4: W_INT [12]
    if (idx < 12) { ws[OFF_WINT + idx] = (float)quad_w(6, idx); return; }
    idx -= 12;
    // R5: FE1 [m=19][t=30]  exp(-2*pi*i*(m-9)*t/30)
    if (idx < 570) {
        int m = idx / 30, t = idx % 30;
        double ang = -2.0 * DPI * (double)((m - 9) * t) / 30.0;
        ws[OFF_FE1 + 2 * idx] = (float)cos(ang);
        ws[OFF_FE1 + 2 * idx + 1] = (float)sin(ang);
        return;
    }
    idx -= 570;
    // R6: E_A1 [m=19][a=20]  exp(+2*pi*i*(m-9)*a/20)
    if (idx < 380) {
        int m = idx / 20, a = idx % 20;
        double ang = 2.0 * DPI * (double)((m - 9) * a) / 20.0;
        ws[OFF_EA1 + 2 * idx] = (float)cos(ang);
        ws[OFF_EA1 + 2 * idx + 1] = (float)sin(ang);
        return;
    }
    idx -= 380;
    // R7: FF2 [mi=11][a=20]  exp(-2*pi*i*(mi-5)*a/20)
    if (idx < 220) {
        int m = idx / 20, a = idx % 20;
        double ang = -2.0 * DPI * (double)((m - 5) * a) / 20.0;
        ws[OFF_FF2 + 2 * idx] = (float)cos(ang);
        ws[OFF_FF2 + 2 * idx + 1] = (float)sin(ang);
        return;
    }
    idx -= 220;
    // R8: E_A2 [m=11][a=12]  exp(+2*pi*i*(m-5)*a/12)
    if (idx < 132) {
        int m = idx / 12, a = idx % 12;
        double ang = 2.0 * DPI * (double)((m - 5) * a) / 12.0;
        ws[OFF_EA2 + 2 * idx] = (float)cos(ang);
        ws[OFF_EA2 + 2 * idx + 1] = (float)sin(ang);
        return;
    }
    idx -= 132;
    // R9: B_S2 [p=24][l=10][m=19]
    if (idx < 4560) {
        int p = idx / 190, r = idx % 190, l = r / 19, m = r % 19;
        int bi = p / 8, ai = p % 8;
        double beta = (bi + 1) * (DPI / 24.0);
        double alpha = 2.0 * DPI * ai / 8.0;
        double re = 0.0, im = 0.0;
        if (m - 9 >= -l && m - 9 <= l) {
            double d = wig_d(l, m - 9 + l, l, beta);
            double ang = -(double)(m - 9) * alpha;
            re = d * cos(ang); im = d * sin(ang);
        }
        ws[OFF_BS2 + 2 * idx] = (float)re;
        ws[OFF_BS2 + 2 * idx + 1] = (float)im;
        return;
    }
    idx -= 4560;
    // R10: B_SO3 [p=144][l=6][m=11][n=11]
    if (idx < 104544) {
        int p = idx / 726, r = idx % 726, l = r / 121, m = (r % 121) / 11, n = r % 11;
        int bi = p / 48, ai = (p % 48) / 6, gi = p % 6;
        double beta = (bi + 1) * (DPI / 24.0);
        double alpha = 2.0 * DPI * ai / 8.0;
        double gamma = 2.0 * DPI * gi / 6.0;
        double re = 0.0, im = 0.0;
        if (m - 5 >= -l && m - 5 <= l && n - 5 >= -l && n - 5 <= l) {
            double d = wig_d(l, m - 5 + l, n - 5 + l, beta);
            double ang = -((double)(m - 5) * alpha + (double)(n - 5) * gamma);
            re = d * cos(ang); im = d * sin(ang);
        }
        ws[OFF_BSO3 + 2 * idx] = (float)re;
        ws[OFF_BSO3 + 2 * idx + 1] = (float)im;
        return;
    }
}

// ---------------------------------------------------------------------------
// psi = kernel1 . B_S2  -> [o=20][l=10][m=19] complex
// ---------------------------------------------------------------------------
__global__ __launch_bounds__(256) void psi1_kernel(float* ws, const float* __restrict__ k1) {
    int idx = blockIdx.x * 256 + threadIdx.x;
    if (idx >= 3800) return;
    int o = idx / 190, r = idx % 190;
    const float2* BS2 = (const float2*)(ws + OFF_BS2);
    float2 s = {0.f, 0.f};
    for (int p = 0; p < 24; ++p) {
        float w = k1[o * 24 + p];
        float2 bv = BS2[p * 190 + r];
        s.x += w * bv.x; s.y += w * bv.y;
    }
    ((float2*)(ws + OFF_PSI))[idx] = s;
}

// ---------------------------------------------------------------------------
// psi2 = kernel2 . B_SO3 -> [i=20][o=40][l=6][m=11][n=11] complex
// ---------------------------------------------------------------------------
__global__ __launch_bounds__(256) void psi2_kernel(float* ws, const float* __restrict__ k2) {
    int idx = blockIdx.x * 256 + threadIdx.x;
    if (idx >= 580800) return;
    int i = idx / 29040, r = idx % 29040, o = r / 726, lmn = r % 726;
    const float2* BS = (const float2*)(ws + OFF_BSO3);
    float2 s = {0.f, 0.f};
    for (int p = 0; p < 144; ++p) {
        float w = k2[(i * 40 + o) * 144 + p];
        float2 bv = BS[p * 726 + lmn];
        s.x += w * bv.x; s.y += w * bv.y;
    }
    ((float2*)(ws + OFF_PSI2))[idx] = s;
}

// ---------------------------------------------------------------------------
// X[b,l,m] = sum_k W_S2_FWD[k,l,m] * (sum_t x[b,k,t] FE1[m,t])
// ---------------------------------------------------------------------------
__global__ __launch_bounds__(256) void xform1_kernel(float* ws, const float* __restrict__ x) {
    const int tid = threadIdx.x, b = blockIdx.x;
    const float2* FE1 = (const float2*)(ws + OFF_FE1);
    const float* WS2 = ws + OFF_WS2;
    float2* Xg = (float2*)(ws + OFF_X) + b * 190;
    __shared__ float xs[900];
    __shared__ float2 xm[570];
    for (int i = tid; i < 900; i += 256) xs[i] = x[b * 900 + i];
    __syncthreads();
    for (int i = tid; i < 570; i += 256) {
        int k = i / 19, m = i % 19;
        float2 s = {0.f, 0.f};
        #pragma unroll
        for (int t = 0; t < 30; ++t) {
            float v = xs[k * 30 + t];
            float2 e = FE1[m * 30 + t];
            s.x += v * e.x; s.y += v * e.y;
        }
        xm[k * 19 + m] = s;
    }
    __syncthreads();
    for (int i = tid; i < 190; i += 256) {
        int l = i / 19, m = i % 19;
        float2 s = {0.f, 0.f};
        for (int k = 0; k < 30; ++k) {
            float w = WS2[k * 190 + l * 19 + m];
            float2 v = xm[k * 19 + m];
            s.x += w * v.x; s.y += w * v.y;
        }
        Xg[i] = s;
    }
}

// ---------------------------------------------------------------------------
// stage1 v3: per (b,o). WAVE-SYNCHRONOUS: each of the 4 waves owns a private
// LDS pipeline buffer and processes k = wave, wave+4, ... (5 k's). No
// __syncthreads() inside the k-loop (v2 had 100 block barriers; waves idled
// at sync with VALUBusy 49.5%). Within a wave, DS ops issue in order and the
// compiler tracks lgkmcnt; wave_barrier() pins section ordering (no runtime
// cost). X2 accumulated in registers, one cross-wave LDS reduce at the end.
// LDS = 48.9 KB -> 3 blocks/CU.
// ---------------------------------------------------------------------------
__global__ __launch_bounds__(256, 3) void stage1_kernel(float* ws) {
    const int tid = threadIdx.x;
    const int wave = tid >> 6, lane = tid & 63;
    const int b = blockIdx.x / 20;
    const int o = blockIdx.x % 20;
    const float2* Xg   = (const float2*)(ws + OFF_X) + b * 190;
    const float2* Pg   = (const float2*)(ws + OFF_PSI) + o * 190;
    const float*  WI1  = ws + OFF_WINV1;
    const float*  WS3  = ws + OFF_WSO3;
    const float2* EA1g = (const float2*)(ws + OFF_EA1);
    const float2* FF2g = (const float2*)(ws + OFF_FF2);
    float2* X2g = (float2*)(ws + OFF_X2) + (b * 20 + o) * 726;

    __shared__ float2 Xs[190], Ps[190], EA1s[380], FF2s[220];
    __shared__ float wbuf[4][2564];   // per-wave pipeline buffers

    float2* fh  = (float2*)&wbuf[wave][0];     // 361 cplx
    float2* tt  = (float2*)&wbuf[wave][722];   // 380 cplx
    float*  yy  = &wbuf[wave][1482];           // 400 f32
    float2* uu  = (float2*)&wbuf[wave][1882];  // 220 cplx
    float2* ymn = (float2*)&wbuf[wave][2322];  // 121 cplx

    for (int i = tid; i < 190; i += 256) { Xs[i] = Xg[i]; Ps[i] = Pg[i]; }
    for (int i = tid; i < 380; i += 256) EA1s[i] = EA1g[i];
    for (int i = tid; i < 220; i += 256) FF2s[i] = FF2g[i];

    int jm[12];
    float2 acc[12];
    #pragma unroll
    for (int t = 0; t < 12; ++t) {
        int j = lane + 64 * t;
        jm[t] = (j < 726) ? (j % 121) : 0;
        acc[t] = make_float2(0.f, 0.f);
    }
    __syncthreads();

    for (int k = wave; k < 20; k += 4) {
        const float* wk = WI1 + k * 3610;
        // fh[m,n] = sum_l W_INV1[k,l,m,n] * X[l,m]*conj(psi[l,n])
        for (int i = lane; i < 361; i += 64) {
            int m = i / 19, n = i - m * 19;
            float2 s = {0.f, 0.f};
            #pragma unroll
            for (int l = 0; l < 10; ++l) {
                float2 a = Xs[l * 19 + m], c = Ps[l * 19 + n];
                float zr = a.x * c.x + a.y * c.y;
                float zi = a.y * c.x - a.x * c.y;
                float wv = wk[l * 361 + i];
                s.x += wv * zr; s.y += wv * zi;
            }
            fh[i] = s;
        }
        __builtin_amdgcn_wave_barrier();
        // tt[m,g] = sum_n fh[m,n]*E_G1[n,g]
        for (int i = lane; i < 380; i += 64) {
            int m = i / 20, g = i - m * 20;
            float2 s = {0.f, 0.f};
            #pragma unroll
            for (int n = 0; n < 19; ++n) {
                float2 f = fh[m * 19 + n], e = EA1s[n * 20 + g];
                s.x += f.x * e.x - f.y * e.y;
                s.y += f.x * e.y + f.y * e.x;
            }
            tt[i] = s;
        }
        __builtin_amdgcn_wave_barrier();
        // yy[a,g] = relu(Re sum_m E_A1[m,a]*tt[m,g])
        for (int i = lane; i < 400; i += 64) {
            int a = i / 20, g = i - a * 20;
            float s = 0.f;
            #pragma unroll
            for (int m = 0; m < 19; ++m) {
                float2 e = EA1s[m * 20 + a], t = tt[m * 20 + g];
                s += e.x * t.x - e.y * t.y;
            }
            yy[i] = s > 0.f ? s : 0.f;
        }
        __builtin_amdgcn_wave_barrier();
        // uu[mi,g] = sum_a yy[a,g]*FF2[mi,a]
        for (int i = lane; i < 220; i += 64) {
            int mi = i / 20, g = i - mi * 20;
            float2 s = {0.f, 0.f};
            #pragma unroll
            for (int a = 0; a < 20; ++a) {
                float v = yy[a * 20 + g];
                float2 e = FF2s[mi * 20 + a];
                s.x += v * e.x; s.y += v * e.y;
            }
            uu[i] = s;
        }
        __builtin_amdgcn_wave_barrier();
        // ymn[mi,ni] = sum_g uu[mi,g]*FF2[ni,g]
        for (int i = lane; i < 121; i += 64) {
            int mi = i / 11, ni = i - mi * 11;
            float2 s = {0.f, 0.f};
            #pragma unroll
            for (int g = 0; g < 20; ++g) {
                float2 u = uu[mi * 20 + g], e = FF2s[ni * 20 + g];
                s.x += u.x * e.x - u.y * e.y;
                s.y += u.x * e.y + u.y * e.x;
            }
            ymn[i] = s;
        }
        __builtin_amdgcn_wave_barrier();
        // acc[j] += W_SO3_FWD[k,j] * ymn[j%121]
        const float* wsk = WS3 + k * 726;
        #pragma unroll
        for (int t = 0; t < 12; ++t) {
            int j = lane + 64 * t;
            if (j < 726) {
                float w = wsk[j];
                float2 v = ymn[jm[t]];
                acc[t].x += w * v.x; acc[t].y += w * v.y;
            }
        }
        __builtin_amdgcn_wave_barrier();
    }
    // cross-wave reduction of acc -> X2 (reuse wbuf as 4 x 726 float2)
    __syncthreads();
    float2* myred = (float2*)wbuf[wave];
    #pragma unroll
    for (int t = 0; t < 12; ++t) {
        int j = lane + 64 * t;
        if (j < 726) myred[j] = acc[t];
    }
    __syncthreads();
    for (int i = tid; i < 726; i += 256) {
        float2 s0 = ((float2*)wbuf[0])[i];
        float2 s1 = ((float2*)wbuf[1])[i];
        float2 s2 = ((float2*)wbuf[2])[i];
        float2 s3 = ((float2*)wbuf[3])[i];
        X2g[i] = make_float2(s0.x + s1.x + s2.x + s3.x, s0.y + s1.y + s2.y + s3.y);
    }
}

// ---------------------------------------------------------------------------
// stage2 v3: per (b,o). k2 processed in two halves of 6 -> LDS 29.6 KB.
// NO min-waves launch bound (the (256,5) bound forced VGPR=48 and spilled).
// ---------------------------------------------------------------------------
__global__ __launch_bounds__(256) void stage2_kernel(float* ws) {
    const int tid = threadIdx.x;
    const int b = blockIdx.x / 40;
    const int o = blockIdx.x % 40;
    const float2* X2g = (const float2*)(ws + OFF_X2) + b * 20 * 726;
    const float2* P2g = (const float2*)(ws + OFF_PSI2);
    const float*  WI2 = ws + OFF_WINV2;
    const float2* EA2 = (const float2*)(ws + OFF_EA2);
    const float*  WIT = ws + OFF_WINT;
    float* featg = ws + OFF_FEAT;

    __shared__ float2 xi[726];
    __shared__ float2 pp[726];
    __shared__ float2 z2[726];
    __shared__ float2 fh2[726];   // [6][121] per half
    __shared__ float2 t2[792];    // [6][132] per half
    __shared__ float red[4];

    // each thread owns z2 indices tid, tid+256, tid+512(<726)
    const int i0 = tid, i1 = tid + 256, i2 = tid + 512;
    float2 a0 = {0.f, 0.f}, a1 = {0.f, 0.f}, a2 = {0.f, 0.f};
    int l, r;
    l = i0 / 121; r = i0 % 121;
    const int xo0 = l * 121 + (r / 11) * 11, po0 = l * 121 + (r % 11) * 11;
    l = i1 / 121; r = i1 % 121;
    const int xo1 = l * 121 + (r / 11) * 11, po1 = l * 121 + (r % 11) * 11;
    int xo2 = 0, po2 = 0;
    const bool has2 = (i2 < 726);
    if (has2) { l = i2 / 121; r = i2 % 121; xo2 = l * 121 + (r / 11) * 11; po2 = l * 121 + (r % 11) * 11; }

    for (int i = 0; i < 20; ++i) {
        for (int j = tid; j < 726; j += 256) {
            xi[j] = X2g[i * 726 + j];
            pp[j] = P2g[(i * 40 + o) * 726 + j];
        }
        __syncthreads();
        #pragma unroll
        for (int k = 0; k < 11; ++k) {
            float2 u = xi[xo0 + k], v = pp[po0 + k];
            a0.x += u.x * v.x + u.y * v.y; a0.y += u.y * v.x - u.x * v.y;
        }
        #pragma unroll
        for (int k = 0; k < 11; ++k) {
            float2 u = xi[xo1 + k], v = pp[po1 + k];
            a1.x += u.x * v.x + u.y * v.y; a1.y += u.y * v.x - u.x * v.y;
        }
        if (has2) {
            #pragma unroll
            for (int k = 0; k < 11; ++k) {
                float2 u = xi[xo2 + k], v = pp[po2 + k];
                a2.x += u.x * v.x + u.y * v.y; a2.y += u.y * v.x - u.x * v.y;
            }
        }
        __syncthreads();
    }
    z2[i0] = a0;
    z2[i1] = a1;
    if (has2) z2[i2] = a2;
    __syncthreads();

    float partial = 0.f;
    for (int h = 0; h < 2; ++h) {
        // fh2[k2h,m,n] = sum_l W_INV2[h*6+k2h,l,m,n]*z2[l,m,n]
        for (int i = tid; i < 726; i += 256) {
            int k2h = i / 121, rr = i - k2h * 121;
            int k2 = h * 6 + k2h;
            float2 s = {0.f, 0.f};
            #pragma unroll
            for (int ll = 0; ll < 6; ++ll) {
                float w = WI2[k2 * 726 + ll * 121 + rr];
                float2 z = z2[ll * 121 + rr];
                s.x += w * z.x; s.y += w * z.y;
            }
            fh2[i] = s;
        }
        __syncthreads();
        // t2[k2h,m,g] = sum_n fh2[k2h,m,n]*E_A2[n,g]
        for (int i = tid; i < 792; i += 256) {
            int k2h = i / 132, rr = i - k2h * 132, m = rr / 12, g = rr - m * 12;
            float2 s = {0.f, 0.f};
            #pragma unroll
            for (int n = 0; n < 11; ++n) {
                float2 f = fh2[k2h * 121 + m * 11 + n], e = EA2[n * 12 + g];
                s.x += f.x * e.x - f.y * e.y;
                s.y += f.x * e.y + f.y * e.x;
            }
            t2[i] = s;
        }
        __syncthreads();
        // partial += W_INT[k2]*relu(Re sum_m E_A2[m,a]*t2[k2h,m,g])
        for (int i = tid; i < 864; i += 256) {
            int k2h = i / 144, rr = i - k2h * 144, a = rr / 12, g = rr - a * 12;
            float s = 0.f;
            #pragma unroll
            for (int m = 0; m < 11; ++m) {
                float2 e = EA2[m * 12 + a], t = t2[k2h * 132 + m * 12 + g];
                s += e.x * t.x - e.y * t.y;
            }
            if (s > 0.f) partial += WIT[h * 6 + k2h] * s;
        }
        __syncthreads();  // guard fh2/t2 rewrite in next half
    }
    for (int off = 32; off > 0; off >>= 1) partial += __shfl_down(partial, off, 64);
    if ((tid & 63) == 0) red[tid >> 6] = partial;
    __syncthreads();
    if (tid == 0) featg[b * 40 + o] = (red[0] + red[1] + red[2] + red[3]) * (1.0f / 144.0f);
}

// ---------------------------------------------------------------------------
// out[b,f] = sum_o feat[b,o]*w_lin[f,o] + b_lin[f]
// ---------------------------------------------------------------------------
__global__ __launch_bounds__(256) void final_kernel(const float* __restrict__ ws,
                                                    const float* __restrict__ wl,
                                                    const float* __restrict__ bl,
                                                    float* __restrict__ out) {
    int idx = blockIdx.x * 256 + threadIdx.x;
    if (idx >= 1280) return;
    int b = idx / 10, f = idx % 10;
    const float* feat = ws + OFF_FEAT;
    float s = bl[f];
    for (int o = 0; o < 40; ++o) s += feat[b * 40 + o] * wl[f * 40 + o];
    out[idx] = s;
}

// ---------------------------------------------------------------------------
extern "C" void kernel_launch(void* const* d_in, const int* in_sizes, int n_in,
                              void* d_out, int out_size, void* d_ws, size_t ws_size,
                              hipStream_t stream) {
    (void)in_sizes; (void)n_in; (void)out_size; (void)ws_size;
    const float* x  = (const float*)d_in[0];
    const float* k1 = (const float*)d_in[1];
    const float* k2 = (const float*)d_in[2];
    const float* wl = (const float*)d_in[3];
    const float* bl = (const float*)d_in[4];
    float* out = (float*)d_out;
    float* ws  = (float*)d_ws;

    build_tables_kernel<<<827, 256, 0, stream>>>(ws);           // 211550 elems
    psi1_kernel<<<15, 256, 0, stream>>>(ws, k1);                // 3800
    xform1_kernel<<<128, 256, 0, stream>>>(ws, x);              // per-batch
    psi2_kernel<<<2269, 256, 0, stream>>>(ws, k2);              // 580800
    stage1_kernel<<<128 * 20, 256, 0, stream>>>(ws);
    stage2_kernel<<<128 * 40, 256, 0, stream>>>(ws);
    final_kernel<<<5, 256, 0, stream>>>(ws, wl, bl, out);
}

// Round 5
// 689.797 us; speedup vs baseline: 2.2667x; 1.2648x over previous
//
#include <hip/hip_runtime.h>
#include <math.h>

// ---------------------------------------------------------------------------
// Problem dims: B_IN=15, B1=10, B2=6, F1=20, F2=40, F_OUT=10
// M1=19, C1=9, M2=11, C2=5, batch=128
// ---------------------------------------------------------------------------

// workspace layout (offsets in floats; all even -> float2 aligned)
constexpr int OFF_WS2   = 0;                     // W_S2_FWD  [30][10][19]
constexpr int OFF_WINV1 = OFF_WS2   + 5700;      // W_INV1    [20][10][19][19]
constexpr int OFF_WSO3  = OFF_WINV1 + 72200;     // W_SO3_FWD [20][6][11][11]
constexpr int OFF_WINV2 = OFF_WSO3  + 14520;     // W_INV2    [12][6][11][11]
constexpr int OFF_WINT  = OFF_WINV2 + 8712;      // W_INT     [12] (+pad)
constexpr int OFF_FE1   = OFF_WINT  + 16;        // FE1  cplx [19][30]
constexpr int OFF_EA1   = OFF_FE1   + 1140;      // E_A1 cplx [19][20]
constexpr int OFF_FF2   = OFF_EA1   + 760;       // FF2  cplx [11][20]
constexpr int OFF_EA2   = OFF_FF2   + 440;       // E_A2 cplx [11][12]
constexpr int OFF_BS2   = OFF_EA2   + 264;       // B_S2 cplx [24][10][19]
constexpr int OFF_BSO3  = OFF_BS2   + 9120;      // B_SO3 cplx[144][6][11][11]
constexpr int OFF_PSI   = OFF_BSO3  + 209088;    // psi  cplx [20][10][19]
constexpr int OFF_X     = OFF_PSI   + 7600;      // X    cplx [128][10][19]
constexpr int OFF_X2    = OFF_X     + 48640;     // X2   cplx [128][20][6][11][11]
constexpr int OFF_PSI2  = OFF_X2    + 3717120;   // psi2 cplx [20][40][6][11][11]
constexpr int OFF_FEAT  = OFF_PSI2  + 1161600;   // feat      [128][40]

#define DPI 3.14159265358979323846

// ---------------------------------------------------------------------------
// table-building helpers (double precision, matches numpy reference)
// ---------------------------------------------------------------------------
__device__ __forceinline__ double dfact(int n) {
    double f = 1.0;
    for (int i = 2; i <= n; ++i) f *= (double)i;
    return f;
}
__device__ __forceinline__ double dpowi(double x, int n) {
    double r = 1.0;
    for (int i = 0; i < n; ++i) r *= x;
    return r;
}
__device__ double wig_d(int l, int mi, int ni, double beta) {
    int m = mi - l, n = ni - l;
    double cb = cos(0.5 * beta), sb = sin(0.5 * beta);
    double pref = sqrt(dfact(l + m) * dfact(l - m) * dfact(l + n) * dfact(l - n));
    int s0 = (n - m) > 0 ? (n - m) : 0;
    int s1 = (l + n) < (l - m) ? (l + n) : (l - m);
    double v = 0.0;
    for (int s = s0; s <= s1; ++s) {
        double term = dpowi(cb, 2 * l + n - m - 2 * s) * dpowi(sb, m - n + 2 * s) /
                      (dfact(l + n - s) * dfact(s) * dfact(m - n + s) * dfact(l - m - s));
        v += ((m - n + s) & 1) ? -term : term;
    }
    return pref * v;
}
__device__ double wig_pad(int l, int m, int n, int c, double beta) {
    if (m < c - l || m > c + l || n < c - l || n > c + l) return 0.0;
    return wig_d(l, m - (c - l), n - (c - l), beta);
}
__device__ double quad_w(int b, int k) {
    double beta = DPI * (2 * k + 1) / (4.0 * b);
    double s = 0.0;
    for (int j = 0; j < b; ++j) s += sin((2 * j + 1) * beta) / (double)(2 * j + 1);
    return 2.0 / b * sin(beta) * s;
}

__global__ __launch_bounds__(256) void build_tables_kernel(float* ws) {
    int idx = blockIdx.x * 256 + threadIdx.x;
    if (idx < 5700) {
        int k = idx / 190, r = idx % 190, l = r / 19, m = r % 19;
        double beta = DPI * (2 * k + 1) / 60.0;
        ws[OFF_WS2 + idx] = (float)(quad_w(15, k) * wig_pad(l, m, 9, 9, beta));
        return;
    }
    idx -= 5700;
    if (idx < 72200) {
        int k = idx / 3610, r = idx % 3610, l = r / 361, r2 = r % 361, m = r2 / 19, n = r2 % 19;
        double beta = DPI * (2 * k + 1) / 40.0;
        ws[OFF_WINV1 + idx] = (float)((2 * l + 1) * wig_pad(l, m, n, 9, beta));
        return;
    }
    idx -= 72200;
    if (idx < 14520) {
        int k = idx / 726, r = idx % 726, l = r / 121, m = (r % 121) / 11, n = r % 11;
        double beta = DPI * (2 * k + 1) / 40.0;
        ws[OFF_WSO3 + idx] = (float)(quad_w(10, k) * wig_pad(l, m, n, 5, beta));
        return;
    }
    idx -= 14520;
    if (idx < 8712) {
        int k = idx / 726, r = idx % 726, l = r / 121, m = (r % 121) / 11, n = r % 11;
        double beta = DPI * (2 * k + 1) / 24.0;
        ws[OFF_WINV2 + idx] = (float)((2 * l + 1) * wig_pad(l, m, n, 5, beta));
        return;
    }
    idx -= 8712;
    if (idx < 12) { ws[OFF_WINT + idx] = (float)quad_w(6, idx); return; }
    idx -= 12;
    if (idx < 570) {
        int m = idx / 30, t = idx % 30;
        double ang = -2.0 * DPI * (double)((m - 9) * t) / 30.0;
        ws[OFF_FE1 + 2 * idx] = (float)cos(ang);
        ws[OFF_FE1 + 2 * idx + 1] = (float)sin(ang);
        return;
    }
    idx -= 570;
    if (idx < 380) {
        int m = idx / 20, a = idx % 20;
        double ang = 2.0 * DPI * (double)((m - 9) * a) / 20.0;
        ws[OFF_EA1 + 2 * idx] = (float)cos(ang);
        ws[OFF_EA1 + 2 * idx + 1] = (float)sin(ang);
        return;
    }
    idx -= 380;
    if (idx < 220) {
        int m = idx / 20, a = idx % 20;
        double ang = -2.0 * DPI * (double)((m - 5) * a) / 20.0;
        ws[OFF_FF2 + 2 * idx] = (float)cos(ang);
        ws[OFF_FF2 + 2 * idx + 1] = (float)sin(ang);
        return;
    }
    idx -= 220;
    if (idx < 132) {
        int m = idx / 12, a = idx % 12;
        double ang = 2.0 * DPI * (double)((m - 5) * a) / 12.0;
        ws[OFF_EA2 + 2 * idx] = (float)cos(ang);
        ws[OFF_EA2 + 2 * idx + 1] = (float)sin(ang);
        return;
    }
    idx -= 132;
    if (idx < 4560) {
        int p = idx / 190, r = idx % 190, l = r / 19, m = r % 19;
        int bi = p / 8, ai = p % 8;
        double beta = (bi + 1) * (DPI / 24.0);
        double alpha = 2.0 * DPI * ai / 8.0;
        double re = 0.0, im = 0.0;
        if (m - 9 >= -l && m - 9 <= l) {
            double d = wig_d(l, m - 9 + l, l, beta);
            double ang = -(double)(m - 9) * alpha;
            re = d * cos(ang); im = d * sin(ang);
        }
        ws[OFF_BS2 + 2 * idx] = (float)re;
        ws[OFF_BS2 + 2 * idx + 1] = (float)im;
        return;
    }
    idx -= 4560;
    if (idx < 104544) {
        int p = idx / 726, r = idx % 726, l = r / 121, m = (r % 121) / 11, n = r % 11;
        int bi = p / 48, ai = (p % 48) / 6, gi = p % 6;
        double beta = (bi + 1) * (DPI / 24.0);
        double alpha = 2.0 * DPI * ai / 8.0;
        double gamma = 2.0 * DPI * gi / 6.0;
        double re = 0.0, im = 0.0;
        if (m - 5 >= -l && m - 5 <= l && n - 5 >= -l && n - 5 <= l) {
            double d = wig_d(l, m - 5 + l, n - 5 + l, beta);
            double ang = -((double)(m - 5) * alpha + (double)(n - 5) * gamma);
            re = d * cos(ang); im = d * sin(ang);
        }
        ws[OFF_BSO3 + 2 * idx] = (float)re;
        ws[OFF_BSO3 + 2 * idx + 1] = (float)im;
        return;
    }
}

// ---------------------------------------------------------------------------
__global__ __launch_bounds__(256) void psi1_kernel(float* ws, const float* __restrict__ k1) {
    int idx = blockIdx.x * 256 + threadIdx.x;
    if (idx >= 3800) return;
    int o = idx / 190, r = idx % 190;
    const float2* BS2 = (const float2*)(ws + OFF_BS2);
    float2 s = {0.f, 0.f};
    for (int p = 0; p < 24; ++p) {
        float w = k1[o * 24 + p];
        float2 bv = BS2[p * 190 + r];
        s.x += w * bv.x; s.y += w * bv.y;
    }
    ((float2*)(ws + OFF_PSI))[idx] = s;
}

__global__ __launch_bounds__(256) void psi2_kernel(float* ws, const float* __restrict__ k2) {
    int idx = blockIdx.x * 256 + threadIdx.x;
    if (idx >= 580800) return;
    int i = idx / 29040, r = idx % 29040, o = r / 726, lmn = r % 726;
    const float2* BS = (const float2*)(ws + OFF_BSO3);
    float2 s = {0.f, 0.f};
    for (int p = 0; p < 144; ++p) {
        float w = k2[(i * 40 + o) * 144 + p];
        float2 bv = BS[p * 726 + lmn];
        s.x += w * bv.x; s.y += w * bv.y;
    }
    ((float2*)(ws + OFF_PSI2))[idx] = s;
}

__global__ __launch_bounds__(256) void xform1_kernel(float* ws, const float* __restrict__ x) {
    const int tid = threadIdx.x, b = blockIdx.x;
    const float2* FE1 = (const float2*)(ws + OFF_FE1);
    const float* WS2 = ws + OFF_WS2;
    float2* Xg = (float2*)(ws + OFF_X) + b * 190;
    __shared__ float xs[900];
    __shared__ float2 xm[570];
    for (int i = tid; i < 900; i += 256) xs[i] = x[b * 900 + i];
    __syncthreads();
    for (int i = tid; i < 570; i += 256) {
        int k = i / 19, m = i % 19;
        float2 s = {0.f, 0.f};
        #pragma unroll
        for (int t = 0; t < 30; ++t) {
            float v = xs[k * 30 + t];
            float2 e = FE1[m * 30 + t];
            s.x += v * e.x; s.y += v * e.y;
        }
        xm[k * 19 + m] = s;
    }
    __syncthreads();
    for (int i = tid; i < 190; i += 256) {
        int l = i / 19, m = i % 19;
        float2 s = {0.f, 0.f};
        for (int k = 0; k < 30; ++k) {
            float w = WS2[k * 190 + l * 19 + m];
            float2 v = xm[k * 19 + m];
            s.x += w * v.x; s.y += w * v.y;
        }
        Xg[i] = s;
    }
}

// ---------------------------------------------------------------------------
// stage1 v4: column-register pipeline. Wave-synchronous (r4-validated). Lane =
// (g-column, k-sublane): 64 lanes = 20 g x 3 k. Wave handles its 5 k's in
// groups {3,2}. tt/y/uu live in REGISTERS (v3 kept them in LDS: ~900 wave-LDS
// instructions per k -> LDS-pipe-bound at VALUBusy 49.6%). Wave-uniform
// E_A1[m,a]/FF2[mi,a] reads go via __restrict__ global pointers (scalar pipe),
// not LDS. fh build zero-skips l < max(|m-9|,|n-9|) (W_INV1 padding zeros).
// LDS = 39.5 KB -> 4 blocks/CU.
// ---------------------------------------------------------------------------
__global__ __launch_bounds__(256) void stage1_kernel(
    const float* __restrict__ WI1, const float* __restrict__ WS3,
    const float* __restrict__ EA1, const float* __restrict__ FF2,
    const float2* __restrict__ Xall, const float2* __restrict__ Pall,
    float2* __restrict__ X2out)
{
    const int tid = threadIdx.x;
    const int wave = tid >> 6, lane = tid & 63;
    const int b = blockIdx.x / 20;
    const int o = blockIdx.x % 20;
    const float2* Xg = Xall + b * 190;
    const float2* Pg = Pall + o * 190;
    float2* X2g = X2out + (b * 20 + o) * 726;
    const float2* EA1c = (const float2*)EA1;
    const float2* FF2c = (const float2*)FF2;

    __shared__ float2 Xs[190], Ps[190], FF2s[220];
    __shared__ float wbuf[4][2166];  // per-wave: fh 3x361 cplx; aliased by uu(660)+ymn(363) cplx

    const int g = lane % 20, j = lane / 20;   // j==3 -> idle helper lane

    // hoist E_G1 column g into registers (reused across all k)
    float2 eg[19];
    #pragma unroll
    for (int n = 0; n < 19; ++n) eg[n] = EA1c[n * 20 + g];

    for (int i = tid; i < 190; i += 256) { Xs[i] = Xg[i]; Ps[i] = Pg[i]; }
    for (int i = tid; i < 220; i += 256) FF2s[i] = FF2c[i];

    float2 acc[12];
    #pragma unroll
    for (int t = 0; t < 12; ++t) acc[t] = make_float2(0.f, 0.f);
    __syncthreads();

    for (int pass = 0; pass < 2; ++pass) {
        const int nk = pass ? 2 : 3;
        const int kbase = wave + pass * 12;   // k = kbase + 4*jj
        float2* fhbuf = (float2*)&wbuf[wave][0];

        // (a) cooperative fh build: fh[jj][m,n] = sum_l W_INV1[k,l,m,n]*X[l,m]*conj(P[l,n])
        for (int i = lane; i < 361 * nk; i += 64) {
            int jj = i / 361, idx = i - jj * 361;
            int m = idx / 19, n = idx - m * 19;
            int am = m > 9 ? m - 9 : 9 - m, an = n > 9 ? n - 9 : 9 - n;
            int lmin = am > an ? am : an;
            const float* wk = WI1 + (kbase + 4 * jj) * 3610 + idx;
            float2 s = {0.f, 0.f};
            for (int l = lmin; l < 10; ++l) {
                float2 a = Xs[l * 19 + m], c = Ps[l * 19 + n];
                float wv = wk[l * 361];
                s.x += wv * (a.x * c.x + a.y * c.y);
                s.y += wv * (a.y * c.x - a.x * c.y);
            }
            fhbuf[i] = s;
        }
        __builtin_amdgcn_wave_barrier();

        // (b) per-lane column pipeline: tt_m scalar -> y[20] -> relu -> uu[11]
        const bool active = (j < nk);
        const float2* fhj = fhbuf + (active ? j * 361 : 0);
        float ybuf[20];
        #pragma unroll
        for (int a = 0; a < 20; ++a) ybuf[a] = 0.f;

        for (int m = 0; m < 19; ++m) {
            float2 t = {0.f, 0.f};
            #pragma unroll
            for (int n = 0; n < 19; ++n) {
                float2 f = fhj[m * 19 + n];
                t.x += f.x * eg[n].x - f.y * eg[n].y;
                t.y += f.x * eg[n].y + f.y * eg[n].x;
            }
            #pragma unroll
            for (int a = 0; a < 20; ++a) {
                float2 e = EA1c[m * 20 + a];   // wave-uniform -> scalar load
                ybuf[a] += e.x * t.x - e.y * t.y;
            }
        }
        float2 uacc[11];
        #pragma unroll
        for (int mi = 0; mi < 11; ++mi) uacc[mi] = make_float2(0.f, 0.f);
        #pragma unroll
        for (int a = 0; a < 20; ++a) {
            float y = ybuf[a] > 0.f ? ybuf[a] : 0.f;
            #pragma unroll
            for (int mi = 0; mi < 11; ++mi) {
                float2 e = FF2c[mi * 20 + a];  // wave-uniform -> scalar load
                uacc[mi].x += e.x * y; uacc[mi].y += e.y * y;
            }
        }
        // (c) uu -> LDS (aliases fh buffer; all fh reads precede in program order)
        float2* uubuf = (float2*)&wbuf[wave][0];
        if (active) {
            #pragma unroll
            for (int mi = 0; mi < 11; ++mi) uubuf[j * 220 + mi * 20 + g] = uacc[mi];
        }
        __builtin_amdgcn_wave_barrier();

        // (d) ymn[jj][mi,ni] = sum_g uu[jj][mi,g]*FF2[ni,g]
        float2* ymnbuf = (float2*)&wbuf[wave][1320];
        for (int i = lane; i < 121 * nk; i += 64) {
            int jj = i / 121, rr = i - jj * 121;
            int mi = rr / 11, ni = rr - mi * 11;
            float2 s = {0.f, 0.f};
            #pragma unroll
            for (int gg = 0; gg < 20; ++gg) {
                float2 u = uubuf[jj * 220 + mi * 20 + gg];
                float2 e = FF2s[ni * 20 + gg];
                s.x += u.x * e.x - u.y * e.y;
                s.y += u.x * e.y + u.y * e.x;
            }
            ymnbuf[i] = s;
        }
        __builtin_amdgcn_wave_barrier();

        // (e) acc[j] += W_SO3_FWD[k,j] * ymn[jj][j%121]
        for (int jj = 0; jj < nk; ++jj) {
            const float* wsk = WS3 + (kbase + 4 * jj) * 726;
            #pragma unroll
            for (int t = 0; t < 12; ++t) {
                int jdx = lane + 64 * t;
                if (jdx < 726) {
                    float w = wsk[jdx];
                    float2 v = ymnbuf[jj * 121 + jdx % 121];
                    acc[t].x += w * v.x; acc[t].y += w * v.y;
                }
            }
        }
        __builtin_amdgcn_wave_barrier();
    }

    // cross-wave reduction of acc -> X2
    __syncthreads();
    float2* myred = (float2*)&wbuf[wave][0];
    #pragma unroll
    for (int t = 0; t < 12; ++t) {
        int jdx = lane + 64 * t;
        if (jdx < 726) myred[jdx] = acc[t];
    }
    __syncthreads();
    for (int i = tid; i < 726; i += 256) {
        float2 s0 = ((float2*)&wbuf[0][0])[i];
        float2 s1 = ((float2*)&wbuf[1][0])[i];
        float2 s2 = ((float2*)&wbuf[2][0])[i];
        float2 s3 = ((float2*)&wbuf[3][0])[i];
        X2g[i] = make_float2(s0.x + s1.x + s2.x + s3.x, s0.y + s1.y + s2.y + s3.y);
    }
}

// ---------------------------------------------------------------------------
// stage2 v4: as v3 (no min-waves bound -- (256,5) spilled), plus exact
// zero-range restriction in the hot Z2 k-loop (X2 and psi2 are provably zero
// for |k-5|>l; ~38% fewer iterations) and lmin skip in fh2.
// ---------------------------------------------------------------------------
__global__ __launch_bounds__(256) void stage2_kernel(float* ws) {
    const int tid = threadIdx.x;
    const int b = blockIdx.x / 40;
    const int o = blockIdx.x % 40;
    const float2* X2g = (const float2*)(ws + OFF_X2) + b * 20 * 726;
    const float2* P2g = (const float2*)(ws + OFF_PSI2);
    const float*  WI2 = ws + OFF_WINV2;
    const float2* EA2 = (const float2*)(ws + OFF_EA2);
    const float*  WIT = ws + OFF_WINT;
    float* featg = ws + OFF_FEAT;

    __shared__ float2 xi[726];
    __shared__ float2 pp[726];
    __shared__ float2 z2[726];
    __shared__ float2 fh2[726];
    __shared__ float2 t2[792];
    __shared__ float red[4];

    const int i0 = tid, i1 = tid + 256, i2 = tid + 512;
    float2 a0 = {0.f, 0.f}, a1 = {0.f, 0.f}, a2 = {0.f, 0.f};
    const int l0 = i0 / 121, r0 = i0 % 121;
    const int xo0 = l0 * 121 + (r0 / 11) * 11, po0 = l0 * 121 + (r0 % 11) * 11;
    const int l1 = i1 / 121, r1 = i1 % 121;
    const int xo1 = l1 * 121 + (r1 / 11) * 11, po1 = l1 * 121 + (r1 % 11) * 11;
    const bool has2 = (i2 < 726);
    const int l2v = has2 ? i2 / 121 : 0, r2 = has2 ? i2 % 121 : 0;
    const int xo2 = l2v * 121 + (r2 / 11) * 11, po2 = l2v * 121 + (r2 % 11) * 11;

    for (int i = 0; i < 20; ++i) {
        for (int jj = tid; jj < 726; jj += 256) {
            xi[jj] = X2g[i * 726 + jj];
            pp[jj] = P2g[(i * 40 + o) * 726 + jj];
        }
        __syncthreads();
        for (int k = 5 - l0; k <= 5 + l0; ++k) {
            float2 u = xi[xo0 + k], v = pp[po0 + k];
            a0.x += u.x * v.x + u.y * v.y; a0.y += u.y * v.x - u.x * v.y;
        }
        for (int k = 5 - l1; k <= 5 + l1; ++k) {
            float2 u = xi[xo1 + k], v = pp[po1 + k];
            a1.x += u.x * v.x + u.y * v.y; a1.y += u.y * v.x - u.x * v.y;
        }
        if (has2) {
            for (int k = 5 - l2v; k <= 5 + l2v; ++k) {
                float2 u = xi[xo2 + k], v = pp[po2 + k];
                a2.x += u.x * v.x + u.y * v.y; a2.y += u.y * v.x - u.x * v.y;
            }
        }
        __syncthreads();
    }
    z2[i0] = a0;
    z2[i1] = a1;
    if (has2) z2[i2] = a2;
    __syncthreads();

    float partial = 0.f;
    for (int h = 0; h < 2; ++h) {
        for (int i = tid; i < 726; i += 256) {
            int k2h = i / 121, rr = i - k2h * 121;
            int k2 = h * 6 + k2h;
            int m = rr / 11, n = rr - m * 11;
            int am = m > 5 ? m - 5 : 5 - m, an = n > 5 ? n - 5 : 5 - n;
            int lmin = am > an ? am : an;
            float2 s = {0.f, 0.f};
            for (int ll = lmin; ll < 6; ++ll) {
                float w = WI2[k2 * 726 + ll * 121 + rr];
                float2 z = z2[ll * 121 + rr];
                s.x += w * z.x; s.y += w * z.y;
            }
            fh2[i] = s;
        }
        __syncthreads();
        for (int i = tid; i < 792; i += 256) {
            int k2h = i / 132, rr = i - k2h * 132, m = rr / 12, g = rr - m * 12;
            float2 s = {0.f, 0.f};
            #pragma unroll
            for (int n = 0; n < 11; ++n) {
                float2 f = fh2[k2h * 121 + m * 11 + n], e = EA2[n * 12 + g];
                s.x += f.x * e.x - f.y * e.y;
                s.y += f.x * e.y + f.y * e.x;
            }
            t2[i] = s;
        }
        __syncthreads();
        for (int i = tid; i < 864; i += 256) {
            int k2h = i / 144, rr = i - k2h * 144, a = rr / 12, g = rr - a * 12;
            float s = 0.f;
            #pragma unroll
            for (int m = 0; m < 11; ++m) {
                float2 e = EA2[m * 12 + a], t = t2[k2h * 132 + m * 12 + g];
                s += e.x * t.x - e.y * t.y;
            }
            if (s > 0.f) partial += WIT[h * 6 + k2h] * s;
        }
        __syncthreads();
    }
    for (int off = 32; off > 0; off >>= 1) partial += __shfl_down(partial, off, 64);
    if ((tid & 63) == 0) red[tid >> 6] = partial;
    __syncthreads();
    if (tid == 0) featg[b * 40 + o] = (red[0] + red[1] + red[2] + red[3]) * (1.0f / 144.0f);
}

// ---------------------------------------------------------------------------
__global__ __launch_bounds__(256) void final_kernel(const float* __restrict__ ws,
                                                    const float* __restrict__ wl,
                                                    const float* __restrict__ bl,
                                                    float* __restrict__ out) {
    int idx = blockIdx.x * 256 + threadIdx.x;
    if (idx >= 1280) return;
    int b = idx / 10, f = idx % 10;
    const float* feat = ws + OFF_FEAT;
    float s = bl[f];
    for (int o = 0; o < 40; ++o) s += feat[b * 40 + o] * wl[f * 40 + o];
    out[idx] = s;
}

// ---------------------------------------------------------------------------
extern "C" void kernel_launch(void* const* d_in, const int* in_sizes, int n_in,
                              void* d_out, int out_size, void* d_ws, size_t ws_size,
                              hipStream_t stream) {
    (void)in_sizes; (void)n_in; (void)out_size; (void)ws_size;
    const float* x  = (const float*)d_in[0];
    const float* k1 = (const float*)d_in[1];
    const float* k2 = (const float*)d_in[2];
    const float* wl = (const float*)d_in[3];
    const float* bl = (const float*)d_in[4];
    float* out = (float*)d_out;
    float* ws  = (float*)d_ws;

    build_tables_kernel<<<827, 256, 0, stream>>>(ws);
    psi1_kernel<<<15, 256, 0, stream>>>(ws, k1);
    xform1_kernel<<<128, 256, 0, stream>>>(ws, x);
    psi2_kernel<<<2269, 256, 0, stream>>>(ws, k2);
    stage1_kernel<<<128 * 20, 256, 0, stream>>>(
        ws + OFF_WINV1, ws + OFF_WSO3, ws + OFF_EA1, ws + OFF_FF2,
        (const float2*)(ws + OFF_X), (const float2*)(ws + OFF_PSI),
        (float2*)(ws + OFF_X2));
    stage2_kernel<<<128 * 40, 256, 0, stream>>>(ws);
    final_kernel<<<5, 256, 0, stream>>>(ws, wl, bl, out);
}

// Round 6
// 675.002 us; speedup vs baseline: 2.3164x; 1.0219x over previous
//
#include <hip/hip_runtime.h>
#include <math.h>

// ---------------------------------------------------------------------------
// Problem dims: B_IN=15, B1=10, B2=6, F1=20, F2=40, F_OUT=10
// M1=19, C1=9, M2=11, C2=5, batch=128
// ---------------------------------------------------------------------------

constexpr int OFF_WS2   = 0;                     // W_S2_FWD  [30][10][19]
constexpr int OFF_WINV1 = OFF_WS2   + 5700;      // W_INV1    [20][10][19][19]
constexpr int OFF_WSO3  = OFF_WINV1 + 72200;     // W_SO3_FWD [20][6][11][11]
constexpr int OFF_WINV2 = OFF_WSO3  + 14520;     // W_INV2    [12][6][11][11]
constexpr int OFF_WINT  = OFF_WINV2 + 8712;      // W_INT     [12] (+pad)
constexpr int OFF_FE1   = OFF_WINT  + 16;        // FE1  cplx [19][30]
constexpr int OFF_EA1   = OFF_FE1   + 1140;      // E_A1 cplx [19][20]
constexpr int OFF_FF2   = OFF_EA1   + 760;       // FF2  cplx [11][20]
constexpr int OFF_EA2   = OFF_FF2   + 440;       // E_A2 cplx [11][12]
constexpr int OFF_BS2   = OFF_EA2   + 264;       // B_S2 cplx [24][10][19]
constexpr int OFF_BSO3  = OFF_BS2   + 9120;      // B_SO3 cplx[144][6][11][11]
constexpr int OFF_PSI   = OFF_BSO3  + 209088;    // psi  cplx [20][10][19]
constexpr int OFF_X     = OFF_PSI   + 7600;      // X    cplx [128][10][19]
constexpr int OFF_X2    = OFF_X     + 48640;     // X2   cplx [128][20][6][11][11]
constexpr int OFF_PSI2  = OFF_X2    + 3717120;   // psi2 cplx [20][40][6][11][11]
constexpr int OFF_FEAT  = OFF_PSI2  + 1161600;   // feat      [128][40]
constexpr int OFF_VTAB  = OFF_FEAT  + 5120;      // int[286] valid (l,m,n) list

#define DPI 3.14159265358979323846

// ---------------------------------------------------------------------------
__device__ __forceinline__ double dfact(int n) {
    double f = 1.0;
    for (int i = 2; i <= n; ++i) f *= (double)i;
    return f;
}
__device__ __forceinline__ double dpowi(double x, int n) {
    double r = 1.0;
    for (int i = 0; i < n; ++i) r *= x;
    return r;
}
__device__ double wig_d(int l, int mi, int ni, double beta) {
    int m = mi - l, n = ni - l;
    double cb = cos(0.5 * beta), sb = sin(0.5 * beta);
    double pref = sqrt(dfact(l + m) * dfact(l - m) * dfact(l + n) * dfact(l - n));
    int s0 = (n - m) > 0 ? (n - m) : 0;
    int s1 = (l + n) < (l - m) ? (l + n) : (l - m);
    double v = 0.0;
    for (int s = s0; s <= s1; ++s) {
        double term = dpowi(cb, 2 * l + n - m - 2 * s) * dpowi(sb, m - n + 2 * s) /
                      (dfact(l + n - s) * dfact(s) * dfact(m - n + s) * dfact(l - m - s));
        v += ((m - n + s) & 1) ? -term : term;
    }
    return pref * v;
}
__device__ double wig_pad(int l, int m, int n, int c, double beta) {
    if (m < c - l || m > c + l || n < c - l || n > c + l) return 0.0;
    return wig_d(l, m - (c - l), n - (c - l), beta);
}
__device__ double quad_w(int b, int k) {
    double beta = DPI * (2 * k + 1) / (4.0 * b);
    double s = 0.0;
    for (int j = 0; j < b; ++j) s += sin((2 * j + 1) * beta) / (double)(2 * j + 1);
    return 2.0 / b * sin(beta) * s;
}

// element ids: ... + 286 (VTAB) = 211836 total
__global__ __launch_bounds__(256) void build_tables_kernel(float* ws) {
    int idx = blockIdx.x * 256 + threadIdx.x;
    if (idx < 5700) {
        int k = idx / 190, r = idx % 190, l = r / 19, m = r % 19;
        double beta = DPI * (2 * k + 1) / 60.0;
        ws[OFF_WS2 + idx] = (float)(quad_w(15, k) * wig_pad(l, m, 9, 9, beta));
        return;
    }
    idx -= 5700;
    if (idx < 72200) {
        int k = idx / 3610, r = idx % 3610, l = r / 361, r2 = r % 361, m = r2 / 19, n = r2 % 19;
        double beta = DPI * (2 * k + 1) / 40.0;
        ws[OFF_WINV1 + idx] = (float)((2 * l + 1) * wig_pad(l, m, n, 9, beta));
        return;
    }
    idx -= 72200;
    if (idx < 14520) {
        int k = idx / 726, r = idx % 726, l = r / 121, m = (r % 121) / 11, n = r % 11;
        double beta = DPI * (2 * k + 1) / 40.0;
        ws[OFF_WSO3 + idx] = (float)(quad_w(10, k) * wig_pad(l, m, n, 5, beta));
        return;
    }
    idx -= 14520;
    if (idx < 8712) {
        int k = idx / 726, r = idx % 726, l = r / 121, m = (r % 121) / 11, n = r % 11;
        double beta = DPI * (2 * k + 1) / 24.0;
        ws[OFF_WINV2 + idx] = (float)((2 * l + 1) * wig_pad(l, m, n, 5, beta));
        return;
    }
    idx -= 8712;
    if (idx < 12) { ws[OFF_WINT + idx] = (float)quad_w(6, idx); return; }
    idx -= 12;
    if (idx < 570) {
        int m = idx / 30, t = idx % 30;
        double ang = -2.0 * DPI * (double)((m - 9) * t) / 30.0;
        ws[OFF_FE1 + 2 * idx] = (float)cos(ang);
        ws[OFF_FE1 + 2 * idx + 1] = (float)sin(ang);
        return;
    }
    idx -= 570;
    if (idx < 380) {
        int m = idx / 20, a = idx % 20;
        double ang = 2.0 * DPI * (double)((m - 9) * a) / 20.0;
        ws[OFF_EA1 + 2 * idx] = (float)cos(ang);
        ws[OFF_EA1 + 2 * idx + 1] = (float)sin(ang);
        return;
    }
    idx -= 380;
    if (idx < 220) {
        int m = idx / 20, a = idx % 20;
        double ang = -2.0 * DPI * (double)((m - 5) * a) / 20.0;
        ws[OFF_FF2 + 2 * idx] = (float)cos(ang);
        ws[OFF_FF2 + 2 * idx + 1] = (float)sin(ang);
        return;
    }
    idx -= 220;
    if (idx < 132) {
        int m = idx / 12, a = idx % 12;
        double ang = 2.0 * DPI * (double)((m - 5) * a) / 12.0;
        ws[OFF_EA2 + 2 * idx] = (float)cos(ang);
        ws[OFF_EA2 + 2 * idx + 1] = (float)sin(ang);
        return;
    }
    idx -= 132;
    if (idx < 4560) {
        int p = idx / 190, r = idx % 190, l = r / 19, m = r % 19;
        int bi = p / 8, ai = p % 8;
        double beta = (bi + 1) * (DPI / 24.0);
        double alpha = 2.0 * DPI * ai / 8.0;
        double re = 0.0, im = 0.0;
        if (m - 9 >= -l && m - 9 <= l) {
            double d = wig_d(l, m - 9 + l, l, beta);
            double ang = -(double)(m - 9) * alpha;
            re = d * cos(ang); im = d * sin(ang);
        }
        ws[OFF_BS2 + 2 * idx] = (float)re;
        ws[OFF_BS2 + 2 * idx + 1] = (float)im;
        return;
    }
    idx -= 4560;
    if (idx < 104544) {
        int p = idx / 726, r = idx % 726, l = r / 121, m = (r % 121) / 11, n = r % 11;
        int bi = p / 48, ai = (p % 48) / 6, gi = p % 6;
        double beta = (bi + 1) * (DPI / 24.0);
        double alpha = 2.0 * DPI * ai / 8.0;
        double gamma = 2.0 * DPI * gi / 6.0;
        double re = 0.0, im = 0.0;
        if (m - 5 >= -l && m - 5 <= l && n - 5 >= -l && n - 5 <= l) {
            double d = wig_d(l, m - 5 + l, n - 5 + l, beta);
            double ang = -((double)(m - 5) * alpha + (double)(n - 5) * gamma);
            re = d * cos(ang); im = d * sin(ang);
        }
        ws[OFF_BSO3 + 2 * idx] = (float)re;
        ws[OFF_BSO3 + 2 * idx + 1] = (float)im;
        return;
    }
    idx -= 104544;
    // R11: VTAB[286] — valid (l,m,n) triplets of the 6x11x11 block structure
    if (idx < 286) {
        int l = 0, cum = 0;
        while (idx >= cum + (2 * l + 1) * (2 * l + 1)) { cum += (2 * l + 1) * (2 * l + 1); ++l; }
        int rem = idx - cum, w = 2 * l + 1;
        int m = 5 - l + rem / w, n = 5 - l + rem % w;
        ((int*)(ws + OFF_VTAB))[idx] = l | (m << 4) | (n << 8);
        return;
    }
}

// ---------------------------------------------------------------------------
__global__ __launch_bounds__(256) void psi1_kernel(float* ws, const float* __restrict__ k1) {
    int idx = blockIdx.x * 256 + threadIdx.x;
    if (idx >= 3800) return;
    int o = idx / 190, r = idx % 190;
    const float2* BS2 = (const float2*)(ws + OFF_BS2);
    float2 s = {0.f, 0.f};
    for (int p = 0; p < 24; ++p) {
        float w = k1[o * 24 + p];
        float2 bv = BS2[p * 190 + r];
        s.x += w * bv.x; s.y += w * bv.y;
    }
    ((float2*)(ws + OFF_PSI))[idx] = s;
}

__global__ __launch_bounds__(256) void psi2_kernel(float* ws, const float* __restrict__ k2) {
    int idx = blockIdx.x * 256 + threadIdx.x;
    if (idx >= 580800) return;
    int i = idx / 29040, r = idx % 29040, o = r / 726, lmn = r % 726;
    const float2* BS = (const float2*)(ws + OFF_BSO3);
    float2 s = {0.f, 0.f};
    for (int p = 0; p < 144; ++p) {
        float w = k2[(i * 40 + o) * 144 + p];
        float2 bv = BS[p * 726 + lmn];
        s.x += w * bv.x; s.y += w * bv.y;
    }
    ((float2*)(ws + OFF_PSI2))[idx] = s;
}

__global__ __launch_bounds__(256) void xform1_kernel(float* ws, const float* __restrict__ x) {
    const int tid = threadIdx.x, b = blockIdx.x;
    const float2* FE1 = (const float2*)(ws + OFF_FE1);
    const float* WS2 = ws + OFF_WS2;
    float2* Xg = (float2*)(ws + OFF_X) + b * 190;
    __shared__ float xs[900];
    __shared__ float2 xm[570];
    for (int i = tid; i < 900; i += 256) xs[i] = x[b * 900 + i];
    __syncthreads();
    for (int i = tid; i < 570; i += 256) {
        int k = i / 19, m = i % 19;
        float2 s = {0.f, 0.f};
        #pragma unroll
        for (int t = 0; t < 30; ++t) {
            float v = xs[k * 30 + t];
            float2 e = FE1[m * 30 + t];
            s.x += v * e.x; s.y += v * e.y;
        }
        xm[k * 19 + m] = s;
    }
    __syncthreads();
    for (int i = tid; i < 190; i += 256) {
        int l = i / 19, m = i % 19;
        float2 s = {0.f, 0.f};
        for (int k = 0; k < 30; ++k) {
            float w = WS2[k * 190 + l * 19 + m];
            float2 v = xm[k * 19 + m];
            s.x += w * v.x; s.y += w * v.y;
        }
        Xg[i] = s;
    }
}

// ---------------------------------------------------------------------------
// stage1 v4 (unchanged, r5-validated): column-register wave-synchronous.
// ---------------------------------------------------------------------------
__global__ __launch_bounds__(256) void stage1_kernel(
    const float* __restrict__ WI1, const float* __restrict__ WS3,
    const float* __restrict__ EA1, const float* __restrict__ FF2,
    const float2* __restrict__ Xall, const float2* __restrict__ Pall,
    float2* __restrict__ X2out)
{
    const int tid = threadIdx.x;
    const int wave = tid >> 6, lane = tid & 63;
    const int b = blockIdx.x / 20;
    const int o = blockIdx.x % 20;
    const float2* Xg = Xall + b * 190;
    const float2* Pg = Pall + o * 190;
    float2* X2g = X2out + (b * 20 + o) * 726;
    const float2* EA1c = (const float2*)EA1;
    const float2* FF2c = (const float2*)FF2;

    __shared__ float2 Xs[190], Ps[190], FF2s[220];
    __shared__ float wbuf[4][2166];

    const int g = lane % 20, j = lane / 20;

    float2 eg[19];
    #pragma unroll
    for (int n = 0; n < 19; ++n) eg[n] = EA1c[n * 20 + g];

    for (int i = tid; i < 190; i += 256) { Xs[i] = Xg[i]; Ps[i] = Pg[i]; }
    for (int i = tid; i < 220; i += 256) FF2s[i] = FF2c[i];

    float2 acc[12];
    #pragma unroll
    for (int t = 0; t < 12; ++t) acc[t] = make_float2(0.f, 0.f);
    __syncthreads();

    for (int pass = 0; pass < 2; ++pass) {
        const int nk = pass ? 2 : 3;
        const int kbase = wave + pass * 12;
        float2* fhbuf = (float2*)&wbuf[wave][0];

        for (int i = lane; i < 361 * nk; i += 64) {
            int jj = i / 361, idx = i - jj * 361;
            int m = idx / 19, n = idx - m * 19;
            int am = m > 9 ? m - 9 : 9 - m, an = n > 9 ? n - 9 : 9 - n;
            int lmin = am > an ? am : an;
            const float* wk = WI1 + (kbase + 4 * jj) * 3610 + idx;
            float2 s = {0.f, 0.f};
            for (int l = lmin; l < 10; ++l) {
                float2 a = Xs[l * 19 + m], c = Ps[l * 19 + n];
                float wv = wk[l * 361];
                s.x += wv * (a.x * c.x + a.y * c.y);
                s.y += wv * (a.y * c.x - a.x * c.y);
            }
            fhbuf[i] = s;
        }
        __builtin_amdgcn_wave_barrier();

        const bool active = (j < nk);
        const float2* fhj = fhbuf + (active ? j * 361 : 0);
        float ybuf[20];
        #pragma unroll
        for (int a = 0; a < 20; ++a) ybuf[a] = 0.f;

        for (int m = 0; m < 19; ++m) {
            float2 t = {0.f, 0.f};
            #pragma unroll
            for (int n = 0; n < 19; ++n) {
                float2 f = fhj[m * 19 + n];
                t.x += f.x * eg[n].x - f.y * eg[n].y;
                t.y += f.x * eg[n].y + f.y * eg[n].x;
            }
            #pragma unroll
            for (int a = 0; a < 20; ++a) {
                float2 e = EA1c[m * 20 + a];
                ybuf[a] += e.x * t.x - e.y * t.y;
            }
        }
        float2 uacc[11];
        #pragma unroll
        for (int mi = 0; mi < 11; ++mi) uacc[mi] = make_float2(0.f, 0.f);
        #pragma unroll
        for (int a = 0; a < 20; ++a) {
            float y = ybuf[a] > 0.f ? ybuf[a] : 0.f;
            #pragma unroll
            for (int mi = 0; mi < 11; ++mi) {
                float2 e = FF2c[mi * 20 + a];
                uacc[mi].x += e.x * y; uacc[mi].y += e.y * y;
            }
        }
        float2* uubuf = (float2*)&wbuf[wave][0];
        if (active) {
            #pragma unroll
            for (int mi = 0; mi < 11; ++mi) uubuf[j * 220 + mi * 20 + g] = uacc[mi];
        }
        __builtin_amdgcn_wave_barrier();

        float2* ymnbuf = (float2*)&wbuf[wave][1320];
        for (int i = lane; i < 121 * nk; i += 64) {
            int jj = i / 121, rr = i - jj * 121;
            int mi = rr / 11, ni = rr - mi * 11;
            float2 s = {0.f, 0.f};
            #pragma unroll
            for (int gg = 0; gg < 20; ++gg) {
                float2 u = uubuf[jj * 220 + mi * 20 + gg];
                float2 e = FF2s[ni * 20 + gg];
                s.x += u.x * e.x - u.y * e.y;
                s.y += u.x * e.y + u.y * e.x;
            }
            ymnbuf[i] = s;
        }
        __builtin_amdgcn_wave_barrier();

        for (int jj = 0; jj < nk; ++jj) {
            const float* wsk = WS3 + (kbase + 4 * jj) * 726;
            #pragma unroll
            for (int t = 0; t < 12; ++t) {
                int jdx = lane + 64 * t;
                if (jdx < 726) {
                    float w = wsk[jdx];
                    float2 v = ymnbuf[jj * 121 + jdx % 121];
                    acc[t].x += w * v.x; acc[t].y += w * v.y;
                }
            }
        }
        __builtin_amdgcn_wave_barrier();
    }

    __syncthreads();
    float2* myred = (float2*)&wbuf[wave][0];
    #pragma unroll
    for (int t = 0; t < 12; ++t) {
        int jdx = lane + 64 * t;
        if (jdx < 726) myred[jdx] = acc[t];
    }
    __syncthreads();
    for (int i = tid; i < 726; i += 256) {
        float2 s0 = ((float2*)&wbuf[0][0])[i];
        float2 s1 = ((float2*)&wbuf[1][0])[i];
        float2 s2 = ((float2*)&wbuf[2][0])[i];
        float2 s3 = ((float2*)&wbuf[3][0])[i];
        X2g[i] = make_float2(s0.x + s1.x + s2.x + s3.x, s0.y + s1.y + s2.y + s3.y);
    }
}

// ---------------------------------------------------------------------------
// stage2 v5: wave-synchronous valid-element Z2. Each wave owns i=w,w+4,...
// (5 i's), stages its own X2[b,i]/psi2[i,o] into private LDS (float4), and
// each lane accumulates ~4.5 VALID (l,m,n) elements (286 of 726; the rest are
// structurally zero since W_SO3_FWD/B_SO3 are zero outside the l-block),
// k restricted to [5-l,5+l]. Zero block barriers in the i-loop (v4 had 40).
// Cross-wave reduce rebuilds z2[726]; phase C (fh2/t2/reduce) unchanged.
// LDS 52.3 KB -> 3 blocks/CU.
// ---------------------------------------------------------------------------
__global__ __launch_bounds__(256) void stage2_kernel(float* ws) {
    const int tid = threadIdx.x;
    const int wave = tid >> 6, lane = tid & 63;
    const int b = blockIdx.x / 40;
    const int o = blockIdx.x % 40;
    const float2* X2g = (const float2*)(ws + OFF_X2) + b * 20 * 726;
    const float2* P2g = (const float2*)(ws + OFF_PSI2);
    const float*  WI2 = ws + OFF_WINV2;
    const float2* EA2 = (const float2*)(ws + OFF_EA2);
    const float*  WIT = ws + OFF_WINT;
    const int*   VTAB = (const int*)(ws + OFF_VTAB);
    float* featg = ws + OFF_FEAT;

    // flat LDS: [0..11616) 4 wave regions of 2904 floats (xiW 1452 | ppW 1452)
    //           [11616..13068) z2s (726 float2)
    // phase C aliases: fh2 = sm[0..1452), t2 = sm[1452..3036)
    __shared__ float sm[13068];
    __shared__ float red[4];
    float* wreg = sm + wave * 2904;

    // decode this lane's valid elements
    int xo[5], po[5], klen[5];
    float2 acc[5];
    #pragma unroll
    for (int t = 0; t < 5; ++t) {
        int v = lane + 64 * t;
        acc[t] = make_float2(0.f, 0.f);
        if (v < 286) {
            int w = VTAB[v];
            int l = w & 15, m = (w >> 4) & 15, n = (w >> 8) & 15;
            xo[t] = l * 121 + m * 11 + 5 - l;
            po[t] = l * 121 + n * 11 + 5 - l;
            klen[t] = 2 * l + 1;
        } else { xo[t] = 0; po[t] = 0; klen[t] = 0; }
    }

    // phase A: wave-synchronous i-loop, no block barriers
    for (int ii = wave; ii < 20; ii += 4) {
        const float4* xs = (const float4*)(X2g + ii * 726);
        const float4* ps = (const float4*)(P2g + (ii * 40 + o) * 726);
        float4* xiW4 = (float4*)wreg;
        float4* ppW4 = (float4*)(wreg + 1452);
        for (int v = lane; v < 363; v += 64) { xiW4[v] = xs[v]; ppW4[v] = ps[v]; }
        __builtin_amdgcn_wave_barrier();
        const float2* xiW = (const float2*)xiW4;
        const float2* ppW = (const float2*)ppW4;
        #pragma unroll
        for (int t = 0; t < 5; ++t) {
            for (int k = 0; k < klen[t]; ++k) {
                float2 u = xiW[xo[t] + k], v2 = ppW[po[t] + k];
                acc[t].x += u.x * v2.x + u.y * v2.y;
                acc[t].y += u.y * v2.x - u.x * v2.y;
            }
        }
        __builtin_amdgcn_wave_barrier();
    }

    // write per-wave partials (reuse wave region; own reads are done in-order)
    float2* part = (float2*)wreg;
    #pragma unroll
    for (int t = 0; t < 5; ++t) {
        int v = lane + 64 * t;
        if (v < 286) part[v] = acc[t];
    }
    __syncthreads();

    // phase B: rebuild z2[726] (zeros for invalid), summing 4 wave partials
    float2* z2s = (float2*)(sm + 11616);
    for (int idx = tid; idx < 726; idx += 256) {
        int l = idx / 121, r = idx - l * 121, m = r / 11, n = r - m * 11;
        int am = m > 5 ? m - 5 : 5 - m, an = n > 5 ? n - 5 : 5 - n;
        float2 s = {0.f, 0.f};
        if (am <= l && an <= l) {
            int v = l * (4 * l * l - 1) / 3 + (m - 5 + l) * (2 * l + 1) + (n - 5 + l);
            #pragma unroll
            for (int w = 0; w < 4; ++w) {
                float2 p = ((float2*)(sm + w * 2904))[v];
                s.x += p.x; s.y += p.y;
            }
        }
        z2s[idx] = s;
    }
    __syncthreads();

    // phase C: fh2 -> t2 -> weighted relu-sum (as v4, aliased into sm[0..])
    float2* fh2 = (float2*)sm;
    float2* t2  = (float2*)(sm + 1452);
    float partial = 0.f;
    for (int h = 0; h < 2; ++h) {
        for (int i = tid; i < 726; i += 256) {
            int k2h = i / 121, rr = i - k2h * 121;
            int k2 = h * 6 + k2h;
            int m = rr / 11, n = rr - m * 11;
            int am = m > 5 ? m - 5 : 5 - m, an = n > 5 ? n - 5 : 5 - n;
            int lmin = am > an ? am : an;
            float2 s = {0.f, 0.f};
            for (int ll = lmin; ll < 6; ++ll) {
                float w = WI2[k2 * 726 + ll * 121 + rr];
                float2 z = z2s[ll * 121 + rr];
                s.x += w * z.x; s.y += w * z.y;
            }
            fh2[i] = s;
        }
        __syncthreads();
        for (int i = tid; i < 792; i += 256) {
            int k2h = i / 132, rr = i - k2h * 132, m = rr / 12, g = rr - m * 12;
            float2 s = {0.f, 0.f};
            #pragma unroll
            for (int n = 0; n < 11; ++n) {
                float2 f = fh2[k2h * 121 + m * 11 + n], e = EA2[n * 12 + g];
                s.x += f.x * e.x - f.y * e.y;
                s.y += f.x * e.y + f.y * e.x;
            }
            t2[i] = s;
        }
        __syncthreads();
        for (int i = tid; i < 864; i += 256) {
            int k2h = i / 144, rr = i - k2h * 144, a = rr / 12, g = rr - a * 12;
            float s = 0.f;
            #pragma unroll
            for (int m = 0; m < 11; ++m) {
                float2 e = EA2[m * 12 + a], t = t2[k2h * 132 + m * 12 + g];
                s += e.x * t.x - e.y * t.y;
            }
            if (s > 0.f) partial += WIT[h * 6 + k2h] * s;
        }
        __syncthreads();
    }
    for (int off = 32; off > 0; off >>= 1) partial += __shfl_down(partial, off, 64);
    if ((tid & 63) == 0) red[tid >> 6] = partial;
    __syncthreads();
    if (tid == 0) featg[b * 40 + o] = (red[0] + red[1] + red[2] + red[3]) * (1.0f / 144.0f);
}

// ---------------------------------------------------------------------------
__global__ __launch_bounds__(256) void final_kernel(const float* __restrict__ ws,
                                                    const float* __restrict__ wl,
                                                    const float* __restrict__ bl,
                                                    float* __restrict__ out) {
    int idx = blockIdx.x * 256 + threadIdx.x;
    if (idx >= 1280) return;
    int b = idx / 10, f = idx % 10;
    const float* feat = ws + OFF_FEAT;
    float s = bl[f];
    for (int o = 0; o < 40; ++o) s += feat[b * 40 + o] * wl[f * 40 + o];
    out[idx] = s;
}

// ---------------------------------------------------------------------------
extern "C" void kernel_launch(void* const* d_in, const int* in_sizes, int n_in,
                              void* d_out, int out_size, void* d_ws, size_t ws_size,
                              hipStream_t stream) {
    (void)in_sizes; (void)n_in; (void)out_size; (void)ws_size;
    const float* x  = (const float*)d_in[0];
    const float* k1 = (const float*)d_in[1];
    const float* k2 = (const float*)d_in[2];
    const float* wl = (const float*)d_in[3];
    const float* bl = (const float*)d_in[4];
    float* out = (float*)d_out;
    float* ws  = (float*)d_ws;

    build_tables_kernel<<<828, 256, 0, stream>>>(ws);   // 211836 elems
    psi1_kernel<<<15, 256, 0, stream>>>(ws, k1);
    xform1_kernel<<<128, 256, 0, stream>>>(ws, x);
    psi2_kernel<<<2269, 256, 0, stream>>>(ws, k2);
    stage1_kernel<<<128 * 20, 256, 0, stream>>>(
        ws + OFF_WINV1, ws + OFF_WSO3, ws + OFF_EA1, ws + OFF_FF2,
        (const float2*)(ws + OFF_X), (const float2*)(ws + OFF_PSI),
        (float2*)(ws + OFF_X2));
    stage2_kernel<<<128 * 40, 256, 0, stream>>>(ws);
    final_kernel<<<5, 256, 0, stream>>>(ws, wl, bl, out);
}

// Round 7
// 642.500 us; speedup vs baseline: 2.4336x; 1.0506x over previous
//
#include <hip/hip_runtime.h>
#include <math.h>

// ---------------------------------------------------------------------------
// Problem dims: B_IN=15, B1=10, B2=6, F1=20, F2=40, F_OUT=10
// M1=19, C1=9, M2=11, C2=5, batch=128
// VALID(l,m,n): |m-5|<=l && |n-5|<=l -> 286 of 726; packed base(l)=l(4l^2-1)/3
// ---------------------------------------------------------------------------

constexpr int OFF_WS2   = 0;                      // W_S2_FWD  [30][10][19]
constexpr int OFF_WINV1 = OFF_WS2   + 5700;       // W_INV1    [20][10][19][19]
constexpr int OFF_WSO3  = OFF_WINV1 + 72200;      // W_SO3_FWD [20][6][11][11]
constexpr int OFF_WINV2 = OFF_WSO3  + 14520;      // W_INV2    [12][6][11][11]
constexpr int OFF_WINT  = OFF_WINV2 + 8712;       // W_INT     [12] (+pad)
constexpr int OFF_FE1   = OFF_WINT  + 16;         // FE1  cplx [19][30]
constexpr int OFF_EA1   = OFF_FE1   + 1140;       // E_A1 cplx [19][20]
constexpr int OFF_FF2   = OFF_EA1   + 760;        // FF2  cplx [11][20]
constexpr int OFF_EA2   = OFF_FF2   + 440;        // E_A2 cplx [11][12]
constexpr int OFF_BS2   = OFF_EA2   + 264;        // B_S2 cplx [24][10][19]
constexpr int OFF_BSO3  = OFF_BS2   + 9120;       // B_SO3 cplx[144][6][11][11]
constexpr int OFF_PSI   = OFF_BSO3  + 209088;     // psi  cplx [20][10][19]
constexpr int OFF_X     = OFF_PSI   + 7600;       // X    cplx [128][10][19]
constexpr int OFF_X2P   = OFF_X     + 48640;      // X2 packed [128][20][286] cplx
constexpr int OFF_PSI2P = OFF_X2P   + 1464320;    // psi2 packed [20][40][286] cplx
constexpr int OFF_FEAT  = OFF_PSI2P + 457600;     // feat      [128][40]
constexpr int OFF_VTAB  = OFF_FEAT  + 5120;       // int[286] valid (l,m,n) list

#define DPI 3.14159265358979323846

// ---------------------------------------------------------------------------
__device__ __forceinline__ double dfact(int n) {
    double f = 1.0;
    for (int i = 2; i <= n; ++i) f *= (double)i;
    return f;
}
__device__ __forceinline__ double dpowi(double x, int n) {
    double r = 1.0;
    for (int i = 0; i < n; ++i) r *= x;
    return r;
}
__device__ double wig_d(int l, int mi, int ni, double beta) {
    int m = mi - l, n = ni - l;
    double cb = cos(0.5 * beta), sb = sin(0.5 * beta);
    double pref = sqrt(dfact(l + m) * dfact(l - m) * dfact(l + n) * dfact(l - n));
    int s0 = (n - m) > 0 ? (n - m) : 0;
    int s1 = (l + n) < (l - m) ? (l + n) : (l - m);
    double v = 0.0;
    for (int s = s0; s <= s1; ++s) {
        double term = dpowi(cb, 2 * l + n - m - 2 * s) * dpowi(sb, m - n + 2 * s) /
                      (dfact(l + n - s) * dfact(s) * dfact(m - n + s) * dfact(l - m - s));
        v += ((m - n + s) & 1) ? -term : term;
    }
    return pref * v;
}
__device__ double wig_pad(int l, int m, int n, int c, double beta) {
    if (m < c - l || m > c + l || n < c - l || n > c + l) return 0.0;
    return wig_d(l, m - (c - l), n - (c - l), beta);
}
__device__ double quad_w(int b, int k) {
    double beta = DPI * (2 * k + 1) / (4.0 * b);
    double s = 0.0;
    for (int j = 0; j < b; ++j) s += sin((2 * j + 1) * beta) / (double)(2 * j + 1);
    return 2.0 / b * sin(beta) * s;
}

// element ids total = 211836
__global__ __launch_bounds__(256) void build_tables_kernel(float* ws) {
    int idx = blockIdx.x * 256 + threadIdx.x;
    if (idx < 5700) {
        int k = idx / 190, r = idx % 190, l = r / 19, m = r % 19;
        double beta = DPI * (2 * k + 1) / 60.0;
        ws[OFF_WS2 + idx] = (float)(quad_w(15, k) * wig_pad(l, m, 9, 9, beta));
        return;
    }
    idx -= 5700;
    if (idx < 72200) {
        int k = idx / 3610, r = idx % 3610, l = r / 361, r2 = r % 361, m = r2 / 19, n = r2 % 19;
        double beta = DPI * (2 * k + 1) / 40.0;
        ws[OFF_WINV1 + idx] = (float)((2 * l + 1) * wig_pad(l, m, n, 9, beta));
        return;
    }
    idx -= 72200;
    if (idx < 14520) {
        int k = idx / 726, r = idx % 726, l = r / 121, m = (r % 121) / 11, n = r % 11;
        double beta = DPI * (2 * k + 1) / 40.0;
        ws[OFF_WSO3 + idx] = (float)(quad_w(10, k) * wig_pad(l, m, n, 5, beta));
        return;
    }
    idx -= 14520;
    if (idx < 8712) {
        int k = idx / 726, r = idx % 726, l = r / 121, m = (r % 121) / 11, n = r % 11;
        double beta = DPI * (2 * k + 1) / 24.0;
        ws[OFF_WINV2 + idx] = (float)((2 * l + 1) * wig_pad(l, m, n, 5, beta));
        return;
    }
    idx -= 8712;
    if (idx < 12) { ws[OFF_WINT + idx] = (float)quad_w(6, idx); return; }
    idx -= 12;
    if (idx < 570) {
        int m = idx / 30, t = idx % 30;
        double ang = -2.0 * DPI * (double)((m - 9) * t) / 30.0;
        ws[OFF_FE1 + 2 * idx] = (float)cos(ang);
        ws[OFF_FE1 + 2 * idx + 1] = (float)sin(ang);
        return;
    }
    idx -= 570;
    if (idx < 380) {
        int m = idx / 20, a = idx % 20;
        double ang = 2.0 * DPI * (double)((m - 9) * a) / 20.0;
        ws[OFF_EA1 + 2 * idx] = (float)cos(ang);
        ws[OFF_EA1 + 2 * idx + 1] = (float)sin(ang);
        return;
    }
    idx -= 380;
    if (idx < 220) {
        int m = idx / 20, a = idx % 20;
        double ang = -2.0 * DPI * (double)((m - 5) * a) / 20.0;
        ws[OFF_FF2 + 2 * idx] = (float)cos(ang);
        ws[OFF_FF2 + 2 * idx + 1] = (float)sin(ang);
        return;
    }
    idx -= 220;
    if (idx < 132) {
        int m = idx / 12, a = idx % 12;
        double ang = 2.0 * DPI * (double)((m - 5) * a) / 12.0;
        ws[OFF_EA2 + 2 * idx] = (float)cos(ang);
        ws[OFF_EA2 + 2 * idx + 1] = (float)sin(ang);
        return;
    }
    idx -= 132;
    if (idx < 4560) {
        int p = idx / 190, r = idx % 190, l = r / 19, m = r % 19;
        int bi = p / 8, ai = p % 8;
        double beta = (bi + 1) * (DPI / 24.0);
        double alpha = 2.0 * DPI * ai / 8.0;
        double re = 0.0, im = 0.0;
        if (m - 9 >= -l && m - 9 <= l) {
            double d = wig_d(l, m - 9 + l, l, beta);
            double ang = -(double)(m - 9) * alpha;
            re = d * cos(ang); im = d * sin(ang);
        }
        ws[OFF_BS2 + 2 * idx] = (float)re;
        ws[OFF_BS2 + 2 * idx + 1] = (float)im;
        return;
    }
    idx -= 4560;
    if (idx < 104544) {
        int p = idx / 726, r = idx % 726, l = r / 121, m = (r % 121) / 11, n = r % 11;
        int bi = p / 48, ai = (p % 48) / 6, gi = p % 6;
        double beta = (bi + 1) * (DPI / 24.0);
        double alpha = 2.0 * DPI * ai / 8.0;
        double gamma = 2.0 * DPI * gi / 6.0;
        double re = 0.0, im = 0.0;
        if (m - 5 >= -l && m - 5 <= l && n - 5 >= -l && n - 5 <= l) {
            double d = wig_d(l, m - 5 + l, n - 5 + l, beta);
            double ang = -((double)(m - 5) * alpha + (double)(n - 5) * gamma);
            re = d * cos(ang); im = d * sin(ang);
        }
        ws[OFF_BSO3 + 2 * idx] = (float)re;
        ws[OFF_BSO3 + 2 * idx + 1] = (float)im;
        return;
    }
    idx -= 104544;
    // VTAB[286]: valid (l,m,n) triplets in packed order
    if (idx < 286) {
        int l = 0, cum = 0;
        while (idx >= cum + (2 * l + 1) * (2 * l + 1)) { cum += (2 * l + 1) * (2 * l + 1); ++l; }
        int rem = idx - cum, w = 2 * l + 1;
        int m = 5 - l + rem / w, n = 5 - l + rem % w;
        ((int*)(ws + OFF_VTAB))[idx] = l | (m << 4) | (n << 8);
        return;
    }
}

// ---------------------------------------------------------------------------
__global__ __launch_bounds__(256) void psi1_kernel(float* ws, const float* __restrict__ k1) {
    int idx = blockIdx.x * 256 + threadIdx.x;
    if (idx >= 3800) return;
    int o = idx / 190, r = idx % 190;
    const float2* BS2 = (const float2*)(ws + OFF_BS2);
    float2 s = {0.f, 0.f};
    for (int p = 0; p < 24; ++p) {
        float w = k1[o * 24 + p];
        float2 bv = BS2[p * 190 + r];
        s.x += w * bv.x; s.y += w * bv.y;
    }
    ((float2*)(ws + OFF_PSI))[idx] = s;
}

// psi2 packed: [i][o][286] — only valid elements computed (was 580800, now 228800)
__global__ __launch_bounds__(256) void psi2_kernel(float* ws, const float* __restrict__ k2) {
    int idx = blockIdx.x * 256 + threadIdx.x;
    if (idx >= 228800) return;
    int i = idx / 11440, r = idx % 11440, o = r / 286, v = r % 286;
    int w = ((const int*)(ws + OFF_VTAB))[v];
    int l = w & 15, m = (w >> 4) & 15, n = (w >> 8) & 15;
    int lmn = l * 121 + m * 11 + n;
    const float2* BS = (const float2*)(ws + OFF_BSO3);
    float2 s = {0.f, 0.f};
    for (int p = 0; p < 144; ++p) {
        float wv = k2[(i * 40 + o) * 144 + p];
        float2 bv = BS[p * 726 + lmn];
        s.x += wv * bv.x; s.y += wv * bv.y;
    }
    ((float2*)(ws + OFF_PSI2P))[idx] = s;
}

__global__ __launch_bounds__(256) void xform1_kernel(float* ws, const float* __restrict__ x) {
    const int tid = threadIdx.x, b = blockIdx.x;
    const float2* FE1 = (const float2*)(ws + OFF_FE1);
    const float* WS2 = ws + OFF_WS2;
    float2* Xg = (float2*)(ws + OFF_X) + b * 190;
    __shared__ float xs[900];
    __shared__ float2 xm[570];
    for (int i = tid; i < 900; i += 256) xs[i] = x[b * 900 + i];
    __syncthreads();
    for (int i = tid; i < 570; i += 256) {
        int k = i / 19, m = i % 19;
        float2 s = {0.f, 0.f};
        #pragma unroll
        for (int t = 0; t < 30; ++t) {
            float v = xs[k * 30 + t];
            float2 e = FE1[m * 30 + t];
            s.x += v * e.x; s.y += v * e.y;
        }
        xm[k * 19 + m] = s;
    }
    __syncthreads();
    for (int i = tid; i < 190; i += 256) {
        int l = i / 19, m = i % 19;
        float2 s = {0.f, 0.f};
        for (int k = 0; k < 30; ++k) {
            float w = WS2[k * 190 + l * 19 + m];
            float2 v = xm[k * 19 + m];
            s.x += w * v.x; s.y += w * v.y;
        }
        Xg[i] = s;
    }
}

// ---------------------------------------------------------------------------
// stage1 v5: Hermitian-halved column pipeline + packed X2 output.
// Real input => fh[-m,-n] = conj(fh[m,n]): build only rows m>=0 (190 of 361),
// t[m] m=0..9, y[a] = t0.x + sum 2Re(t_m E), uu d=0..5 + conj mirror.
// ---------------------------------------------------------------------------
__global__ __launch_bounds__(256) void stage1_kernel(
    const float* __restrict__ WI1, const float* __restrict__ WS3,
    const float* __restrict__ EA1, const float* __restrict__ FF2,
    const float2* __restrict__ Xall, const float2* __restrict__ Pall,
    float2* __restrict__ X2out)
{
    const int tid = threadIdx.x;
    const int wave = tid >> 6, lane = tid & 63;
    const int b = blockIdx.x / 20;
    const int o = blockIdx.x % 20;
    const float2* Xg = Xall + b * 190;
    const float2* Pg = Pall + o * 190;
    float2* X2g = X2out + (b * 20 + o) * 286;   // packed row
    const float2* EA1c = (const float2*)EA1;
    const float2* FF2c = (const float2*)FF2;

    __shared__ float2 Xs[190], Ps[190], FF2s[220];
    __shared__ float wbuf[4][2048];
    // per-wave layout (floats): fh rows m>=0: nk*190 cplx (<=1140) at 0,
    // aliased by uu nk*220 cplx (<=1320) at 0; ymn nk*121 cplx at 1320.

    const int g = lane % 20, j = lane / 20;

    float2 eg[19];
    #pragma unroll
    for (int n = 0; n < 19; ++n) eg[n] = EA1c[n * 20 + g];

    for (int i = tid; i < 190; i += 256) { Xs[i] = Xg[i]; Ps[i] = Pg[i]; }
    for (int i = tid; i < 220; i += 256) FF2s[i] = FF2c[i];

    float2 acc[12];
    #pragma unroll
    for (int t = 0; t < 12; ++t) acc[t] = make_float2(0.f, 0.f);
    __syncthreads();

    for (int pass = 0; pass < 2; ++pass) {
        const int nk = pass ? 2 : 3;
        const int kbase = wave + pass * 12;
        float2* fhbuf = (float2*)&wbuf[wave][0];

        // (a) fh rows mi=9..18 only: fh[jj][mrow,ni]
        for (int i = lane; i < 190 * nk; i += 64) {
            int jj = i / 190, idx = i - jj * 190;
            int mrow = idx / 19, ni = idx - mrow * 19;
            int mi = mrow + 9;
            int an = ni > 9 ? ni - 9 : 9 - ni;
            int lmin = mrow > an ? mrow : an;
            const float* wk = WI1 + (kbase + 4 * jj) * 3610 + mi * 19 + ni;
            float2 s = {0.f, 0.f};
            for (int l = lmin; l < 10; ++l) {
                float2 a = Xs[l * 19 + mi], c = Ps[l * 19 + ni];
                float wv = wk[l * 361];
                s.x += wv * (a.x * c.x + a.y * c.y);
                s.y += wv * (a.y * c.x - a.x * c.y);
            }
            fhbuf[i] = s;
        }
        __builtin_amdgcn_wave_barrier();

        // (b) per-lane column pipeline (Hermitian-halved)
        const bool active = (j < nk);
        const float2* fhj = fhbuf + (active ? j * 190 : 0);
        float ybuf[20];
        {   // m = 0 (center row): y init = Re(t0)
            float2 t = {0.f, 0.f};
            #pragma unroll
            for (int n = 0; n < 19; ++n) {
                float2 f = fhj[n];
                t.x += f.x * eg[n].x - f.y * eg[n].y;
                t.y += f.x * eg[n].y + f.y * eg[n].x;
            }
            #pragma unroll
            for (int a = 0; a < 20; ++a) ybuf[a] = t.x;
        }
        for (int mrow = 1; mrow < 10; ++mrow) {
            float2 t = {0.f, 0.f};
            #pragma unroll
            for (int n = 0; n < 19; ++n) {
                float2 f = fhj[mrow * 19 + n];
                t.x += f.x * eg[n].x - f.y * eg[n].y;
                t.y += f.x * eg[n].y + f.y * eg[n].x;
            }
            t.x *= 2.f; t.y *= 2.f;
            #pragma unroll
            for (int a = 0; a < 20; ++a) {
                float2 e = EA1c[(9 + mrow) * 20 + a];   // wave-uniform -> scalar
                ybuf[a] += t.x * e.x - t.y * e.y;
            }
        }
        // uu: d = 0..5 only (y real => uu[5-d] = conj(uu[5+d]))
        float2 uacc[6];
        #pragma unroll
        for (int d = 0; d < 6; ++d) uacc[d] = make_float2(0.f, 0.f);
        #pragma unroll
        for (int a = 0; a < 20; ++a) {
            float y = ybuf[a] > 0.f ? ybuf[a] : 0.f;
            uacc[0].x += y;                    // FF2[5,a] = 1 exactly
            #pragma unroll
            for (int d = 1; d < 6; ++d) {
                float2 e = FF2c[(5 + d) * 20 + a];   // wave-uniform -> scalar
                uacc[d].x += e.x * y; uacc[d].y += e.y * y;
            }
        }
        // (c) uu -> LDS with conj mirror (aliases fh; wave in-order DS)
        float2* uubuf = (float2*)&wbuf[wave][0];
        if (active) {
            uubuf[j * 220 + 5 * 20 + g] = make_float2(uacc[0].x, 0.f);
            #pragma unroll
            for (int d = 1; d < 6; ++d) {
                uubuf[j * 220 + (5 + d) * 20 + g] = uacc[d];
                uubuf[j * 220 + (5 - d) * 20 + g] = make_float2(uacc[d].x, -uacc[d].y);
            }
        }
        __builtin_amdgcn_wave_barrier();

        // (d) ymn[jj][mi,ni] = sum_g uu[jj][mi,g]*FF2[ni,g]
        float2* ymnbuf = (float2*)&wbuf[wave][1320];
        for (int i = lane; i < 121 * nk; i += 64) {
            int jj = i / 121, rr = i - jj * 121;
            int mi = rr / 11, ni = rr - mi * 11;
            float2 s = {0.f, 0.f};
            #pragma unroll
            for (int gg = 0; gg < 20; ++gg) {
                float2 u = uubuf[jj * 220 + mi * 20 + gg];
                float2 e = FF2s[ni * 20 + gg];
                s.x += u.x * e.x - u.y * e.y;
                s.y += u.x * e.y + u.y * e.x;
            }
            ymnbuf[i] = s;
        }
        __builtin_amdgcn_wave_barrier();

        // (e) acc[j] += W_SO3_FWD[k,j] * ymn[jj][j%121]
        for (int jj = 0; jj < nk; ++jj) {
            const float* wsk = WS3 + (kbase + 4 * jj) * 726;
            #pragma unroll
            for (int t = 0; t < 12; ++t) {
                int jdx = lane + 64 * t;
                if (jdx < 726) {
                    float w = wsk[jdx];
                    float2 v = ymnbuf[jj * 121 + jdx % 121];
                    acc[t].x += w * v.x; acc[t].y += w * v.y;
                }
            }
        }
        __builtin_amdgcn_wave_barrier();
    }

    // cross-wave reduce, then packed write (valid elements only)
    __syncthreads();
    float2* myred = (float2*)&wbuf[wave][0];
    #pragma unroll
    for (int t = 0; t < 12; ++t) {
        int jdx = lane + 64 * t;
        if (jdx < 726) myred[jdx] = acc[t];
    }
    __syncthreads();
    for (int i = tid; i < 726; i += 256) {
        float2 s0 = ((float2*)&wbuf[0][0])[i];
        float2 s1 = ((float2*)&wbuf[1][0])[i];
        float2 s2 = ((float2*)&wbuf[2][0])[i];
        float2 s3 = ((float2*)&wbuf[3][0])[i];
        int l = i / 121, r = i - l * 121, m = r / 11, n = r - m * 11;
        int dm = m - 5, dn = n - 5;
        int adm = dm < 0 ? -dm : dm, adn = dn < 0 ? -dn : dn;
        if (adm <= l && adn <= l) {
            int pidx = l * (4 * l * l - 1) / 3 + (dm + l) * (2 * l + 1) + (dn + l);
            X2g[pidx] = make_float2(s0.x + s1.x + s2.x + s3.x, s0.y + s1.y + s2.y + s3.y);
        }
    }
}

// ---------------------------------------------------------------------------
// stage2 v6: packed X2/psi2 rows (286 cplx = 2.3 KB each; psi2p 1.8 MB is
// L2-resident). Wave-synchronous i-loop as v5; phase A traffic 1.19 GB ->
// ~0.47 GB. LDS 24 KB.
// ---------------------------------------------------------------------------
__global__ __launch_bounds__(256) void stage2_kernel(float* ws) {
    const int tid = threadIdx.x;
    const int wave = tid >> 6, lane = tid & 63;
    const int b = blockIdx.x / 40;
    const int o = blockIdx.x % 40;
    const float2* X2p = (const float2*)(ws + OFF_X2P) + b * 20 * 286;
    const float2* P2p = (const float2*)(ws + OFF_PSI2P);
    const float*  WI2 = ws + OFF_WINV2;
    const float2* EA2 = (const float2*)(ws + OFF_EA2);
    const float*  WIT = ws + OFF_WINT;
    const int*   VTAB = (const int*)(ws + OFF_VTAB);
    float* featg = ws + OFF_FEAT;

    // sm layout (floats): [0..4576) 4 wave regions of 1144 (xiW 572 | ppW 572)
    //                     [4576..6028) z2s (726 cplx)
    // phase C aliases: fh2 = sm[0..1452), t2 = sm[1452..3036)
    __shared__ float sm[6028];
    __shared__ float red[4];
    float* wreg = sm + wave * 1144;

    int xo[5], po[5], klen[5];
    float2 acc[5];
    #pragma unroll
    for (int t = 0; t < 5; ++t) {
        int v = lane + 64 * t;
        acc[t] = make_float2(0.f, 0.f);
        if (v < 286) {
            int w = VTAB[v];
            int l = w & 15, m = (w >> 4) & 15, n = (w >> 8) & 15;
            int base = l * (4 * l * l - 1) / 3, span = 2 * l + 1;
            xo[t] = base + (m - 5 + l) * span;
            po[t] = base + (n - 5 + l) * span;
            klen[t] = span;
        } else { xo[t] = 0; po[t] = 0; klen[t] = 0; }
    }

    // phase A: wave-synchronous i-loop, packed rows (143 float4 each)
    for (int ii = wave; ii < 20; ii += 4) {
        const float4* xs = (const float4*)(X2p + ii * 286);
        const float4* ps = (const float4*)(P2p + (ii * 40 + o) * 286);
        float4* xiW4 = (float4*)wreg;
        float4* ppW4 = (float4*)(wreg + 572);
        for (int v = lane; v < 143; v += 64) { xiW4[v] = xs[v]; ppW4[v] = ps[v]; }
        __builtin_amdgcn_wave_barrier();
        const float2* xiW = (const float2*)xiW4;
        const float2* ppW = (const float2*)ppW4;
        #pragma unroll
        for (int t = 0; t < 5; ++t) {
            for (int k = 0; k < klen[t]; ++k) {
                float2 u = xiW[xo[t] + k], v2 = ppW[po[t] + k];
                acc[t].x += u.x * v2.x + u.y * v2.y;
                acc[t].y += u.y * v2.x - u.x * v2.y;
            }
        }
        __builtin_amdgcn_wave_barrier();
    }

    // per-wave partials (packed order) into wave region
    float2* part = (float2*)wreg;
    #pragma unroll
    for (int t = 0; t < 5; ++t) {
        int v = lane + 64 * t;
        if (v < 286) part[v] = acc[t];
    }
    __syncthreads();

    // phase B: rebuild z2[726] (zeros invalid), summing 4 wave partials
    float2* z2s = (float2*)(sm + 4576);
    for (int idx = tid; idx < 726; idx += 256) {
        int l = idx / 121, r = idx - l * 121, m = r / 11, n = r - m * 11;
        int am = m > 5 ? m - 5 : 5 - m, an = n > 5 ? n - 5 : 5 - n;
        float2 s = {0.f, 0.f};
        if (am <= l && an <= l) {
            int v = l * (4 * l * l - 1) / 3 + (m - 5 + l) * (2 * l + 1) + (n - 5 + l);
            #pragma unroll
            for (int w = 0; w < 4; ++w) {
                float2 p = ((float2*)(sm + w * 1144))[v];
                s.x += p.x; s.y += p.y;
            }
        }
        z2s[idx] = s;
    }
    __syncthreads();

    // phase C: fh2 -> t2 -> weighted relu-sum
    float2* fh2 = (float2*)sm;
    float2* t2  = (float2*)(sm + 1452);
    float partial = 0.f;
    for (int h = 0; h < 2; ++h) {
        for (int i = tid; i < 726; i += 256) {
            int k2h = i / 121, rr = i - k2h * 121;
            int k2 = h * 6 + k2h;
            int m = rr / 11, n = rr - m * 11;
            int am = m > 5 ? m - 5 : 5 - m, an = n > 5 ? n - 5 : 5 - n;
            int lmin = am > an ? am : an;
            float2 s = {0.f, 0.f};
            for (int ll = lmin; ll < 6; ++ll) {
                float w = WI2[k2 * 726 + ll * 121 + rr];
                float2 z = z2s[ll * 121 + rr];
                s.x += w * z.x; s.y += w * z.y;
            }
            fh2[i] = s;
        }
        __syncthreads();
        for (int i = tid; i < 792; i += 256) {
            int k2h = i / 132, rr = i - k2h * 132, m = rr / 12, g = rr - m * 12;
            float2 s = {0.f, 0.f};
            #pragma unroll
            for (int n = 0; n < 11; ++n) {
                float2 f = fh2[k2h * 121 + m * 11 + n], e = EA2[n * 12 + g];
                s.x += f.x * e.x - f.y * e.y;
                s.y += f.x * e.y + f.y * e.x;
            }
            t2[i] = s;
        }
        __syncthreads();
        for (int i = tid; i < 864; i += 256) {
            int k2h = i / 144, rr = i - k2h * 144, a = rr / 12, g = rr - a * 12;
            float s = 0.f;
            #pragma unroll
            for (int m = 0; m < 11; ++m) {
                float2 e = EA2[m * 12 + a], t = t2[k2h * 132 + m * 12 + g];
                s += e.x * t.x - e.y * t.y;
            }
            if (s > 0.f) partial += WIT[h * 6 + k2h] * s;
        }
        __syncthreads();
    }
    for (int off = 32; off > 0; off >>= 1) partial += __shfl_down(partial, off, 64);
    if ((tid & 63) == 0) red[tid >> 6] = partial;
    __syncthreads();
    if (tid == 0) featg[b * 40 + o] = (red[0] + red[1] + red[2] + red[3]) * (1.0f / 144.0f);
}

// ---------------------------------------------------------------------------
__global__ __launch_bounds__(256) void final_kernel(const float* __restrict__ ws,
                                                    const float* __restrict__ wl,
                                                    const float* __restrict__ bl,
                                                    float* __restrict__ out) {
    int idx = blockIdx.x * 256 + threadIdx.x;
    if (idx >= 1280) return;
    int b = idx / 10, f = idx % 10;
    const float* feat = ws + OFF_FEAT;
    float s = bl[f];
    for (int o = 0; o < 40; ++o) s += feat[b * 40 + o] * wl[f * 40 + o];
    out[idx] = s;
}

// ---------------------------------------------------------------------------
extern "C" void kernel_launch(void* const* d_in, const int* in_sizes, int n_in,
                              void* d_out, int out_size, void* d_ws, size_t ws_size,
                              hipStream_t stream) {
    (void)in_sizes; (void)n_in; (void)out_size; (void)ws_size;
    const float* x  = (const float*)d_in[0];
    const float* k1 = (const float*)d_in[1];
    const float* k2 = (const float*)d_in[2];
    const float* wl = (const float*)d_in[3];
    const float* bl = (const float*)d_in[4];
    float* out = (float*)d_out;
    float* ws  = (float*)d_ws;

    build_tables_kernel<<<828, 256, 0, stream>>>(ws);   // 211836 elems
    psi1_kernel<<<15, 256, 0, stream>>>(ws, k1);
    xform1_kernel<<<128, 256, 0, stream>>>(ws, x);
    psi2_kernel<<<894, 256, 0, stream>>>(ws, k2);       // 228800 packed
    stage1_kernel<<<128 * 20, 256, 0, stream>>>(
        ws + OFF_WINV1, ws + OFF_WSO3, ws + OFF_EA1, ws + OFF_FF2,
        (const float2*)(ws + OFF_X), (const float2*)(ws + OFF_PSI),
        (float2*)(ws + OFF_X2P));
    stage2_kernel<<<128 * 40, 256, 0, stream>>>(ws);
    final_kernel<<<5, 256, 0, stream>>>(ws, wl, bl, out);
}

// Round 8
// 452.011 us; speedup vs baseline: 3.4592x; 1.4214x over previous
//
#include <hip/hip_runtime.h>
#include <math.h>

// ---------------------------------------------------------------------------
// Problem dims: B_IN=15, B1=10, B2=6, F1=20, F2=40, F_OUT=10
// M1=19, C1=9, M2=11, C2=5, batch=128
// VALID(l,m,n): |m-5|<=l && |n-5|<=l -> 286 of 726; packed base(l)=l(4l^2-1)/3
// ---------------------------------------------------------------------------

constexpr int OFF_WS2   = 0;                      // W_S2_FWD  [30][10][19]
constexpr int OFF_WINV1 = OFF_WS2   + 5700;       // W_INV1    [20][10][19][19]
constexpr int OFF_WSO3  = OFF_WINV1 + 72200;      // W_SO3_FWD [20][6][11][11]
constexpr int OFF_WINV2 = OFF_WSO3  + 14520;      // W_INV2    [12][6][11][11]
constexpr int OFF_WINT  = OFF_WINV2 + 8712;       // W_INT     [12] (+pad)
constexpr int OFF_FE1   = OFF_WINT  + 16;         // FE1  cplx [19][30]
constexpr int OFF_EA1   = OFF_FE1   + 1140;       // E_A1 cplx [19][20]
constexpr int OFF_FF2   = OFF_EA1   + 760;        // FF2  cplx [11][20]
constexpr int OFF_EA2   = OFF_FF2   + 440;        // E_A2 cplx [11][12]
constexpr int OFF_BS2   = OFF_EA2   + 264;        // B_S2 cplx [24][10][19]
constexpr int OFF_BSO3  = OFF_BS2   + 9120;       // B_SO3 cplx[144][6][11][11]
constexpr int OFF_PSI   = OFF_BSO3  + 209088;     // psi  cplx [20][10][19]
constexpr int OFF_X     = OFF_PSI   + 7600;       // X    cplx [128][10][19]
constexpr int OFF_X2P   = OFF_X     + 48640;      // X2 packed [128][20][286] cplx
constexpr int OFF_PSI2P = OFF_X2P   + 1464320;    // psi2 packed [20][40][286] cplx
constexpr int OFF_FEAT  = OFF_PSI2P + 457600;     // feat      [128][40]
constexpr int OFF_VTAB  = OFF_FEAT  + 5120;       // int[286] valid (l,m,n) list

#define DPI 3.14159265358979323846

// ---------------------------------------------------------------------------
__device__ __forceinline__ double dfact(int n) {
    double f = 1.0;
    for (int i = 2; i <= n; ++i) f *= (double)i;
    return f;
}
__device__ __forceinline__ double dpowi(double x, int n) {
    double r = 1.0;
    for (int i = 0; i < n; ++i) r *= x;
    return r;
}
__device__ double wig_d(int l, int mi, int ni, double beta) {
    int m = mi - l, n = ni - l;
    double cb = cos(0.5 * beta), sb = sin(0.5 * beta);
    double pref = sqrt(dfact(l + m) * dfact(l - m) * dfact(l + n) * dfact(l - n));
    int s0 = (n - m) > 0 ? (n - m) : 0;
    int s1 = (l + n) < (l - m) ? (l + n) : (l - m);
    double v = 0.0;
    for (int s = s0; s <= s1; ++s) {
        double term = dpowi(cb, 2 * l + n - m - 2 * s) * dpowi(sb, m - n + 2 * s) /
                      (dfact(l + n - s) * dfact(s) * dfact(m - n + s) * dfact(l - m - s));
        v += ((m - n + s) & 1) ? -term : term;
    }
    return pref * v;
}
__device__ double wig_pad(int l, int m, int n, int c, double beta) {
    if (m < c - l || m > c + l || n < c - l || n > c + l) return 0.0;
    return wig_d(l, m - (c - l), n - (c - l), beta);
}
__device__ double quad_w(int b, int k) {
    double beta = DPI * (2 * k + 1) / (4.0 * b);
    double s = 0.0;
    for (int j = 0; j < b; ++j) s += sin((2 * j + 1) * beta) / (double)(2 * j + 1);
    return 2.0 / b * sin(beta) * s;
}

// element ids total = 211836
__global__ __launch_bounds__(256) void build_tables_kernel(float* ws) {
    int idx = blockIdx.x * 256 + threadIdx.x;
    if (idx < 5700) {
        int k = idx / 190, r = idx % 190, l = r / 19, m = r % 19;
        double beta = DPI * (2 * k + 1) / 60.0;
        ws[OFF_WS2 + idx] = (float)(quad_w(15, k) * wig_pad(l, m, 9, 9, beta));
        return;
    }
    idx -= 5700;
    if (idx < 72200) {
        int k = idx / 3610, r = idx % 3610, l = r / 361, r2 = r % 361, m = r2 / 19, n = r2 % 19;
        double beta = DPI * (2 * k + 1) / 40.0;
        ws[OFF_WINV1 + idx] = (float)((2 * l + 1) * wig_pad(l, m, n, 9, beta));
        return;
    }
    idx -= 72200;
    if (idx < 14520) {
        int k = idx / 726, r = idx % 726, l = r / 121, m = (r % 121) / 11, n = r % 11;
        double beta = DPI * (2 * k + 1) / 40.0;
        ws[OFF_WSO3 + idx] = (float)(quad_w(10, k) * wig_pad(l, m, n, 5, beta));
        return;
    }
    idx -= 14520;
    if (idx < 8712) {
        int k = idx / 726, r = idx % 726, l = r / 121, m = (r % 121) / 11, n = r % 11;
        double beta = DPI * (2 * k + 1) / 24.0;
        ws[OFF_WINV2 + idx] = (float)((2 * l + 1) * wig_pad(l, m, n, 5, beta));
        return;
    }
    idx -= 8712;
    if (idx < 12) { ws[OFF_WINT + idx] = (float)quad_w(6, idx); return; }
    idx -= 12;
    if (idx < 570) {
        int m = idx / 30, t = idx % 30;
        double ang = -2.0 * DPI * (double)((m - 9) * t) / 30.0;
        ws[OFF_FE1 + 2 * idx] = (float)cos(ang);
        ws[OFF_FE1 + 2 * idx + 1] = (float)sin(ang);
        return;
    }
    idx -= 570;
    if (idx < 380) {
        int m = idx / 20, a = idx % 20;
        double ang = 2.0 * DPI * (double)((m - 9) * a) / 20.0;
        ws[OFF_EA1 + 2 * idx] = (float)cos(ang);
        ws[OFF_EA1 + 2 * idx + 1] = (float)sin(ang);
        return;
    }
    idx -= 380;
    if (idx < 220) {
        int m = idx / 20, a = idx % 20;
        double ang = -2.0 * DPI * (double)((m - 5) * a) / 20.0;
        ws[OFF_FF2 + 2 * idx] = (float)cos(ang);
        ws[OFF_FF2 + 2 * idx + 1] = (float)sin(ang);
        return;
    }
    idx -= 220;
    if (idx < 132) {
        int m = idx / 12, a = idx % 12;
        double ang = 2.0 * DPI * (double)((m - 5) * a) / 12.0;
        ws[OFF_EA2 + 2 * idx] = (float)cos(ang);
        ws[OFF_EA2 + 2 * idx + 1] = (float)sin(ang);
        return;
    }
    idx -= 132;
    if (idx < 4560) {
        int p = idx / 190, r = idx % 190, l = r / 19, m = r % 19;
        int bi = p / 8, ai = p % 8;
        double beta = (bi + 1) * (DPI / 24.0);
        double alpha = 2.0 * DPI * ai / 8.0;
        double re = 0.0, im = 0.0;
        if (m - 9 >= -l && m - 9 <= l) {
            double d = wig_d(l, m - 9 + l, l, beta);
            double ang = -(double)(m - 9) * alpha;
            re = d * cos(ang); im = d * sin(ang);
        }
        ws[OFF_BS2 + 2 * idx] = (float)re;
        ws[OFF_BS2 + 2 * idx + 1] = (float)im;
        return;
    }
    idx -= 4560;
    if (idx < 104544) {
        int p = idx / 726, r = idx % 726, l = r / 121, m = (r % 121) / 11, n = r % 11;
        int bi = p / 48, ai = (p % 48) / 6, gi = p % 6;
        double beta = (bi + 1) * (DPI / 24.0);
        double alpha = 2.0 * DPI * ai / 8.0;
        double gamma = 2.0 * DPI * gi / 6.0;
        double re = 0.0, im = 0.0;
        if (m - 5 >= -l && m - 5 <= l && n - 5 >= -l && n - 5 <= l) {
            double d = wig_d(l, m - 5 + l, n - 5 + l, beta);
            double ang = -((double)(m - 5) * alpha + (double)(n - 5) * gamma);
            re = d * cos(ang); im = d * sin(ang);
        }
        ws[OFF_BSO3 + 2 * idx] = (float)re;
        ws[OFF_BSO3 + 2 * idx + 1] = (float)im;
        return;
    }
    idx -= 104544;
    // VTAB[286]: valid (l,m,n) triplets in packed order
    if (idx < 286) {
        int l = 0, cum = 0;
        while (idx >= cum + (2 * l + 1) * (2 * l + 1)) { cum += (2 * l + 1) * (2 * l + 1); ++l; }
        int rem = idx - cum, w = 2 * l + 1;
        int m = 5 - l + rem / w, n = 5 - l + rem % w;
        ((int*)(ws + OFF_VTAB))[idx] = l | (m << 4) | (n << 8);
        return;
    }
}

// ---------------------------------------------------------------------------
__global__ __launch_bounds__(256) void psi1_kernel(float* ws, const float* __restrict__ k1) {
    int idx = blockIdx.x * 256 + threadIdx.x;
    if (idx >= 3800) return;
    int o = idx / 190, r = idx % 190;
    const float2* BS2 = (const float2*)(ws + OFF_BS2);
    float2 s = {0.f, 0.f};
    for (int p = 0; p < 24; ++p) {
        float w = k1[o * 24 + p];
        float2 bv = BS2[p * 190 + r];
        s.x += w * bv.x; s.y += w * bv.y;
    }
    ((float2*)(ws + OFF_PSI))[idx] = s;
}

// psi2 packed: [i][o][286]
__global__ __launch_bounds__(256) void psi2_kernel(float* ws, const float* __restrict__ k2) {
    int idx = blockIdx.x * 256 + threadIdx.x;
    if (idx >= 228800) return;
    int i = idx / 11440, r = idx % 11440, o = r / 286, v = r % 286;
    int w = ((const int*)(ws + OFF_VTAB))[v];
    int l = w & 15, m = (w >> 4) & 15, n = (w >> 8) & 15;
    int lmn = l * 121 + m * 11 + n;
    const float2* BS = (const float2*)(ws + OFF_BSO3);
    float2 s = {0.f, 0.f};
    for (int p = 0; p < 144; ++p) {
        float wv = k2[(i * 40 + o) * 144 + p];
        float2 bv = BS[p * 726 + lmn];
        s.x += wv * bv.x; s.y += wv * bv.y;
    }
    ((float2*)(ws + OFF_PSI2P))[idx] = s;
}

__global__ __launch_bounds__(256) void xform1_kernel(float* ws, const float* __restrict__ x) {
    const int tid = threadIdx.x, b = blockIdx.x;
    const float2* FE1 = (const float2*)(ws + OFF_FE1);
    const float* WS2 = ws + OFF_WS2;
    float2* Xg = (float2*)(ws + OFF_X) + b * 190;
    __shared__ float xs[900];
    __shared__ float2 xm[570];
    for (int i = tid; i < 900; i += 256) xs[i] = x[b * 900 + i];
    __syncthreads();
    for (int i = tid; i < 570; i += 256) {
        int k = i / 19, m = i % 19;
        float2 s = {0.f, 0.f};
        #pragma unroll
        for (int t = 0; t < 30; ++t) {
            float v = xs[k * 30 + t];
            float2 e = FE1[m * 30 + t];
            s.x += v * e.x; s.y += v * e.y;
        }
        xm[k * 19 + m] = s;
    }
    __syncthreads();
    for (int i = tid; i < 190; i += 256) {
        int l = i / 19, m = i % 19;
        float2 s = {0.f, 0.f};
        for (int k = 0; k < 30; ++k) {
            float w = WS2[k * 190 + l * 19 + m];
            float2 v = xm[k * 19 + m];
            s.x += w * v.x; s.y += w * v.y;
        }
        Xg[i] = s;
    }
}

// ---------------------------------------------------------------------------
// stage1 v6: Hermitian-halved pipeline (v5 math) + register-pressure fix.
// v5 compiled to 220 VGPRs (compiler fully unrolled the 9-iter mrow loop,
// hoisting LDS/scalar loads -> occupancy 11.7%, dur 371us worse than v4's
// 296us at 72 VGPR). Fix: #pragma unroll 1 on the mrow loop + a (256,3)
// launch-bounds guardrail (~168 VGPR cap; natural need is ~100, no spill).
// ---------------------------------------------------------------------------
__global__ __launch_bounds__(256, 3) void stage1_kernel(
    const float* __restrict__ WI1, const float* __restrict__ WS3,
    const float* __restrict__ EA1, const float* __restrict__ FF2,
    const float2* __restrict__ Xall, const float2* __restrict__ Pall,
    float2* __restrict__ X2out)
{
    const int tid = threadIdx.x;
    const int wave = tid >> 6, lane = tid & 63;
    const int b = blockIdx.x / 20;
    const int o = blockIdx.x % 20;
    const float2* Xg = Xall + b * 190;
    const float2* Pg = Pall + o * 190;
    float2* X2g = X2out + (b * 20 + o) * 286;   // packed row
    const float2* EA1c = (const float2*)EA1;
    const float2* FF2c = (const float2*)FF2;

    __shared__ float2 Xs[190], Ps[190], FF2s[220];
    __shared__ float wbuf[4][2048];

    const int g = lane % 20, j = lane / 20;

    float2 eg[19];
    #pragma unroll
    for (int n = 0; n < 19; ++n) eg[n] = EA1c[n * 20 + g];

    for (int i = tid; i < 190; i += 256) { Xs[i] = Xg[i]; Ps[i] = Pg[i]; }
    for (int i = tid; i < 220; i += 256) FF2s[i] = FF2c[i];

    float2 acc[12];
    #pragma unroll
    for (int t = 0; t < 12; ++t) acc[t] = make_float2(0.f, 0.f);
    __syncthreads();

    for (int pass = 0; pass < 2; ++pass) {
        const int nk = pass ? 2 : 3;
        const int kbase = wave + pass * 12;
        float2* fhbuf = (float2*)&wbuf[wave][0];

        // (a) fh rows mi=9..18 only
        for (int i = lane; i < 190 * nk; i += 64) {
            int jj = i / 190, idx = i - jj * 190;
            int mrow = idx / 19, ni = idx - mrow * 19;
            int mi = mrow + 9;
            int an = ni > 9 ? ni - 9 : 9 - ni;
            int lmin = mrow > an ? mrow : an;
            const float* wk = WI1 + (kbase + 4 * jj) * 3610 + mi * 19 + ni;
            float2 s = {0.f, 0.f};
            for (int l = lmin; l < 10; ++l) {
                float2 a = Xs[l * 19 + mi], c = Ps[l * 19 + ni];
                float wv = wk[l * 361];
                s.x += wv * (a.x * c.x + a.y * c.y);
                s.y += wv * (a.y * c.x - a.x * c.y);
            }
            fhbuf[i] = s;
        }
        __builtin_amdgcn_wave_barrier();

        // (b) per-lane column pipeline (Hermitian-halved)
        const bool active = (j < nk);
        const float2* fhj = fhbuf + (active ? j * 190 : 0);
        float ybuf[20];
        {   // m = 0 (center row): y init = Re(t0)
            float2 t = {0.f, 0.f};
            #pragma unroll
            for (int n = 0; n < 19; ++n) {
                float2 f = fhj[n];
                t.x += f.x * eg[n].x - f.y * eg[n].y;
                t.y += f.x * eg[n].y + f.y * eg[n].x;
            }
            #pragma unroll
            for (int a = 0; a < 20; ++a) ybuf[a] = t.x;
        }
        #pragma unroll 1   // keep live ranges small: 220->~100 VGPR (r7 lesson)
        for (int mrow = 1; mrow < 10; ++mrow) {
            float2 t = {0.f, 0.f};
            #pragma unroll
            for (int n = 0; n < 19; ++n) {
                float2 f = fhj[mrow * 19 + n];
                t.x += f.x * eg[n].x - f.y * eg[n].y;
                t.y += f.x * eg[n].y + f.y * eg[n].x;
            }
            t.x *= 2.f; t.y *= 2.f;
            #pragma unroll
            for (int a = 0; a < 20; ++a) {
                float2 e = EA1c[(9 + mrow) * 20 + a];   // wave-uniform -> scalar
                ybuf[a] += t.x * e.x - t.y * e.y;
            }
        }
        // uu: d = 0..5 only (y real => uu[5-d] = conj(uu[5+d]))
        float2 uacc[6];
        #pragma unroll
        for (int d = 0; d < 6; ++d) uacc[d] = make_float2(0.f, 0.f);
        #pragma unroll
        for (int a = 0; a < 20; ++a) {
            float y = ybuf[a] > 0.f ? ybuf[a] : 0.f;
            uacc[0].x += y;                    // FF2[5,a] = 1 exactly
            #pragma unroll
            for (int d = 1; d < 6; ++d) {
                float2 e = FF2c[(5 + d) * 20 + a];   // wave-uniform -> scalar
                uacc[d].x += e.x * y; uacc[d].y += e.y * y;
            }
        }
        // (c) uu -> LDS with conj mirror
        float2* uubuf = (float2*)&wbuf[wave][0];
        if (active) {
            uubuf[j * 220 + 5 * 20 + g] = make_float2(uacc[0].x, 0.f);
            #pragma unroll
            for (int d = 1; d < 6; ++d) {
                uubuf[j * 220 + (5 + d) * 20 + g] = uacc[d];
                uubuf[j * 220 + (5 - d) * 20 + g] = make_float2(uacc[d].x, -uacc[d].y);
            }
        }
        __builtin_amdgcn_wave_barrier();

        // (d) ymn[jj][mi,ni] = sum_g uu[jj][mi,g]*FF2[ni,g]
        float2* ymnbuf = (float2*)&wbuf[wave][1320];
        for (int i = lane; i < 121 * nk; i += 64) {
            int jj = i / 121, rr = i - jj * 121;
            int mi = rr / 11, ni = rr - mi * 11;
            float2 s = {0.f, 0.f};
            #pragma unroll
            for (int gg = 0; gg < 20; ++gg) {
                float2 u = uubuf[jj * 220 + mi * 20 + gg];
                float2 e = FF2s[ni * 20 + gg];
                s.x += u.x * e.x - u.y * e.y;
                s.y += u.x * e.y + u.y * e.x;
            }
            ymnbuf[i] = s;
        }
        __builtin_amdgcn_wave_barrier();

        // (e) acc[j] += W_SO3_FWD[k,j] * ymn[jj][j%121]
        for (int jj = 0; jj < nk; ++jj) {
            const float* wsk = WS3 + (kbase + 4 * jj) * 726;
            #pragma unroll
            for (int t = 0; t < 12; ++t) {
                int jdx = lane + 64 * t;
                if (jdx < 726) {
                    float w = wsk[jdx];
                    float2 v = ymnbuf[jj * 121 + jdx % 121];
                    acc[t].x += w * v.x; acc[t].y += w * v.y;
                }
            }
        }
        __builtin_amdgcn_wave_barrier();
    }

    // cross-wave reduce, then packed write (valid elements only)
    __syncthreads();
    float2* myred = (float2*)&wbuf[wave][0];
    #pragma unroll
    for (int t = 0; t < 12; ++t) {
        int jdx = lane + 64 * t;
        if (jdx < 726) myred[jdx] = acc[t];
    }
    __syncthreads();
    for (int i = tid; i < 726; i += 256) {
        float2 s0 = ((float2*)&wbuf[0][0])[i];
        float2 s1 = ((float2*)&wbuf[1][0])[i];
        float2 s2 = ((float2*)&wbuf[2][0])[i];
        float2 s3 = ((float2*)&wbuf[3][0])[i];
        int l = i / 121, r = i - l * 121, m = r / 11, n = r - m * 11;
        int dm = m - 5, dn = n - 5;
        int adm = dm < 0 ? -dm : dm, adn = dn < 0 ? -dn : dn;
        if (adm <= l && adn <= l) {
            int pidx = l * (4 * l * l - 1) / 3 + (dm + l) * (2 * l + 1) + (dn + l);
            X2g[pidx] = make_float2(s0.x + s1.x + s2.x + s3.x, s0.y + s1.y + s2.y + s3.y);
        }
    }
}

// ---------------------------------------------------------------------------
// stage2 v6 (unchanged, r7-validated): packed rows, wave-synchronous i-loop.
// ---------------------------------------------------------------------------
__global__ __launch_bounds__(256) void stage2_kernel(float* ws) {
    const int tid = threadIdx.x;
    const int wave = tid >> 6, lane = tid & 63;
    const int b = blockIdx.x / 40;
    const int o = blockIdx.x % 40;
    const float2* X2p = (const float2*)(ws + OFF_X2P) + b * 20 * 286;
    const float2* P2p = (const float2*)(ws + OFF_PSI2P);
    const float*  WI2 = ws + OFF_WINV2;
    const float2* EA2 = (const float2*)(ws + OFF_EA2);
    const float*  WIT = ws + OFF_WINT;
    const int*   VTAB = (const int*)(ws + OFF_VTAB);
    float* featg = ws + OFF_FEAT;

    __shared__ float sm[6028];
    __shared__ float red[4];
    float* wreg = sm + wave * 1144;

    int xo[5], po[5], klen[5];
    float2 acc[5];
    #pragma unroll
    for (int t = 0; t < 5; ++t) {
        int v = lane + 64 * t;
        acc[t] = make_float2(0.f, 0.f);
        if (v < 286) {
            int w = VTAB[v];
            int l = w & 15, m = (w >> 4) & 15, n = (w >> 8) & 15;
            int base = l * (4 * l * l - 1) / 3, span = 2 * l + 1;
            xo[t] = base + (m - 5 + l) * span;
            po[t] = base + (n - 5 + l) * span;
            klen[t] = span;
        } else { xo[t] = 0; po[t] = 0; klen[t] = 0; }
    }

    for (int ii = wave; ii < 20; ii += 4) {
        const float4* xs = (const float4*)(X2p + ii * 286);
        const float4* ps = (const float4*)(P2p + (ii * 40 + o) * 286);
        float4* xiW4 = (float4*)wreg;
        float4* ppW4 = (float4*)(wreg + 572);
        for (int v = lane; v < 143; v += 64) { xiW4[v] = xs[v]; ppW4[v] = ps[v]; }
        __builtin_amdgcn_wave_barrier();
        const float2* xiW = (const float2*)xiW4;
        const float2* ppW = (const float2*)ppW4;
        #pragma unroll
        for (int t = 0; t < 5; ++t) {
            for (int k = 0; k < klen[t]; ++k) {
                float2 u = xiW[xo[t] + k], v2 = ppW[po[t] + k];
                acc[t].x += u.x * v2.x + u.y * v2.y;
                acc[t].y += u.y * v2.x - u.x * v2.y;
            }
        }
        __builtin_amdgcn_wave_barrier();
    }

    float2* part = (float2*)wreg;
    #pragma unroll
    for (int t = 0; t < 5; ++t) {
        int v = lane + 64 * t;
        if (v < 286) part[v] = acc[t];
    }
    __syncthreads();

    float2* z2s = (float2*)(sm + 4576);
    for (int idx = tid; idx < 726; idx += 256) {
        int l = idx / 121, r = idx - l * 121, m = r / 11, n = r - m * 11;
        int am = m > 5 ? m - 5 : 5 - m, an = n > 5 ? n - 5 : 5 - n;
        float2 s = {0.f, 0.f};
        if (am <= l && an <= l) {
            int v = l * (4 * l * l - 1) / 3 + (m - 5 + l) * (2 * l + 1) + (n - 5 + l);
            #pragma unroll
            for (int w = 0; w < 4; ++w) {
                float2 p = ((float2*)(sm + w * 1144))[v];
                s.x += p.x; s.y += p.y;
            }
        }
        z2s[idx] = s;
    }
    __syncthreads();

    float2* fh2 = (float2*)sm;
    float2* t2  = (float2*)(sm + 1452);
    float partial = 0.f;
    for (int h = 0; h < 2; ++h) {
        for (int i = tid; i < 726; i += 256) {
            int k2h = i / 121, rr = i - k2h * 121;
            int k2 = h * 6 + k2h;
            int m = rr / 11, n = rr - m * 11;
            int am = m > 5 ? m - 5 : 5 - m, an = n > 5 ? n - 5 : 5 - n;
            int lmin = am > an ? am : an;
            float2 s = {0.f, 0.f};
            for (int ll = lmin; ll < 6; ++ll) {
                float w = WI2[k2 * 726 + ll * 121 + rr];
                float2 z = z2s[ll * 121 + rr];
                s.x += w * z.x; s.y += w * z.y;
            }
            fh2[i] = s;
        }
        __syncthreads();
        for (int i = tid; i < 792; i += 256) {
            int k2h = i / 132, rr = i - k2h * 132, m = rr / 12, g = rr - m * 12;
            float2 s = {0.f, 0.f};
            #pragma unroll
            for (int n = 0; n < 11; ++n) {
                float2 f = fh2[k2h * 121 + m * 11 + n], e = EA2[n * 12 + g];
                s.x += f.x * e.x - f.y * e.y;
                s.y += f.x * e.y + f.y * e.x;
            }
            t2[i] = s;
        }
        __syncthreads();
        for (int i = tid; i < 864; i += 256) {
            int k2h = i / 144, rr = i - k2h * 144, a = rr / 12, g = rr - a * 12;
            float s = 0.f;
            #pragma unroll
            for (int m = 0; m < 11; ++m) {
                float2 e = EA2[m * 12 + a], t = t2[k2h * 132 + m * 12 + g];
                s += e.x * t.x - e.y * t.y;
            }
            if (s > 0.f) partial += WIT[h * 6 + k2h] * s;
        }
        __syncthreads();
    }
    for (int off = 32; off > 0; off >>= 1) partial += __shfl_down(partial, off, 64);
    if ((tid & 63) == 0) red[tid >> 6] = partial;
    __syncthreads();
    if (tid == 0) featg[b * 40 + o] = (red[0] + red[1] + red[2] + red[3]) * (1.0f / 144.0f);
}

// ---------------------------------------------------------------------------
__global__ __launch_bounds__(256) void final_kernel(const float* __restrict__ ws,
                                                    const float* __restrict__ wl,
                                                    const float* __restrict__ bl,
                                                    float* __restrict__ out) {
    int idx = blockIdx.x * 256 + threadIdx.x;
    if (idx >= 1280) return;
    int b = idx / 10, f = idx % 10;
    const float* feat = ws + OFF_FEAT;
    float s = bl[f];
    for (int o = 0; o < 40; ++o) s += feat[b * 40 + o] * wl[f * 40 + o];
    out[idx] = s;
}

// ---------------------------------------------------------------------------
extern "C" void kernel_launch(void* const* d_in, const int* in_sizes, int n_in,
                              void* d_out, int out_size, void* d_ws, size_t ws_size,
                              hipStream_t stream) {
    (void)in_sizes; (void)n_in; (void)out_size; (void)ws_size;
    const float* x  = (const float*)d_in[0];
    const float* k1 = (const float*)d_in[1];
    const float* k2 = (const float*)d_in[2];
    const float* wl = (const float*)d_in[3];
    const float* bl = (const float*)d_in[4];
    float* out = (float*)d_out;
    float* ws  = (float*)d_ws;

    build_tables_kernel<<<828, 256, 0, stream>>>(ws);   // 211836 elems
    psi1_kernel<<<15, 256, 0, stream>>>(ws, k1);
    xform1_kernel<<<128, 256, 0, stream>>>(ws, x);
    psi2_kernel<<<894, 256, 0, stream>>>(ws, k2);       // 228800 packed
    stage1_kernel<<<128 * 20, 256, 0, stream>>>(
        ws + OFF_WINV1, ws + OFF_WSO3, ws + OFF_EA1, ws + OFF_FF2,
        (const float2*)(ws + OFF_X), (const float2*)(ws + OFF_PSI),
        (float2*)(ws + OFF_X2P));
    stage2_kernel<<<128 * 40, 256, 0, stream>>>(ws);
    final_kernel<<<5, 256, 0, stream>>>(ws, wl, bl, out);
}

// Round 9
// 375.583 us; speedup vs baseline: 4.1631x; 1.2035x over previous
//
#include <hip/hip_runtime.h>
#include <math.h>

// ---------------------------------------------------------------------------
// Problem dims: B_IN=15, B1=10, B2=6, F1=20, F2=40, F_OUT=10
// M1=19, C1=9, M2=11, C2=5, batch=128
// VALID(l,m,n): |m-5|<=l && |n-5|<=l -> 286 of 726; packed base(l)=l(4l^2-1)/3
// HALF set (z2 Hermitian: z2[l,-m,-n]=(-1)^{m+n}conj(z2[l,m,n])): dm>0 or
// (dm==0 && dn>=0) -> 146 elements, stored l-DESCENDING for lane balance.
// ---------------------------------------------------------------------------

constexpr int OFF_WS2   = 0;                      // W_S2_FWD  [30][10][19]
constexpr int OFF_WINV1 = OFF_WS2   + 5700;       // W_INV1    [20][10][19][19]
constexpr int OFF_WSO3  = OFF_WINV1 + 72200;      // W_SO3_FWD [20][6][11][11]
constexpr int OFF_WINV2 = OFF_WSO3  + 14520;      // W_INV2    [12][6][11][11]
constexpr int OFF_WINT  = OFF_WINV2 + 8712;       // W_INT     [12] (+pad)
constexpr int OFF_FE1   = OFF_WINT  + 16;         // FE1  cplx [19][30]
constexpr int OFF_EA1   = OFF_FE1   + 1140;       // E_A1 cplx [19][20]
constexpr int OFF_FF2   = OFF_EA1   + 760;        // FF2  cplx [11][20]
constexpr int OFF_EA2   = OFF_FF2   + 440;        // E_A2 cplx [11][12]
constexpr int OFF_BS2   = OFF_EA2   + 264;        // B_S2 cplx [24][10][19]
constexpr int OFF_BSO3  = OFF_BS2   + 9120;       // B_SO3 cplx[144][6][11][11]
constexpr int OFF_PSI   = OFF_BSO3  + 209088;     // psi  cplx [20][10][19]
constexpr int OFF_X     = OFF_PSI   + 7600;       // X    cplx [128][10][19]
constexpr int OFF_X2P   = OFF_X     + 48640;      // X2 packed [128][20][286] cplx
constexpr int OFF_PSI2P = OFF_X2P   + 1464320;    // psi2 packed [20][40][286] cplx
constexpr int OFF_FEAT  = OFF_PSI2P + 457600;     // feat      [128][40]
constexpr int OFF_VTAB  = OFF_FEAT  + 5120;       // int[286] valid (l,m,n)
constexpr int OFF_VTAB2 = OFF_VTAB  + 286;        // int[146] half-set, l desc

#define DPI 3.14159265358979323846

// ---------------------------------------------------------------------------
__device__ __forceinline__ double dfact(int n) {
    double f = 1.0;
    for (int i = 2; i <= n; ++i) f *= (double)i;
    return f;
}
__device__ __forceinline__ double dpowi(double x, int n) {
    double r = 1.0;
    for (int i = 0; i < n; ++i) r *= x;
    return r;
}
__device__ double wig_d(int l, int mi, int ni, double beta) {
    int m = mi - l, n = ni - l;
    double cb = cos(0.5 * beta), sb = sin(0.5 * beta);
    double pref = sqrt(dfact(l + m) * dfact(l - m) * dfact(l + n) * dfact(l - n));
    int s0 = (n - m) > 0 ? (n - m) : 0;
    int s1 = (l + n) < (l - m) ? (l + n) : (l - m);
    double v = 0.0;
    for (int s = s0; s <= s1; ++s) {
        double term = dpowi(cb, 2 * l + n - m - 2 * s) * dpowi(sb, m - n + 2 * s) /
                      (dfact(l + n - s) * dfact(s) * dfact(m - n + s) * dfact(l - m - s));
        v += ((m - n + s) & 1) ? -term : term;
    }
    return pref * v;
}
__device__ double wig_pad(int l, int m, int n, int c, double beta) {
    if (m < c - l || m > c + l || n < c - l || n > c + l) return 0.0;
    return wig_d(l, m - (c - l), n - (c - l), beta);
}
__device__ double quad_w(int b, int k) {
    double beta = DPI * (2 * k + 1) / (4.0 * b);
    double s = 0.0;
    for (int j = 0; j < b; ++j) s += sin((2 * j + 1) * beta) / (double)(2 * j + 1);
    return 2.0 / b * sin(beta) * s;
}

// element ids total = 211550 + 286 + 146 = 211982
__global__ __launch_bounds__(256) void build_tables_kernel(float* ws) {
    int idx = blockIdx.x * 256 + threadIdx.x;
    if (idx < 5700) {
        int k = idx / 190, r = idx % 190, l = r / 19, m = r % 19;
        double beta = DPI * (2 * k + 1) / 60.0;
        ws[OFF_WS2 + idx] = (float)(quad_w(15, k) * wig_pad(l, m, 9, 9, beta));
        return;
    }
    idx -= 5700;
    if (idx < 72200) {
        int k = idx / 3610, r = idx % 3610, l = r / 361, r2 = r % 361, m = r2 / 19, n = r2 % 19;
        double beta = DPI * (2 * k + 1) / 40.0;
        ws[OFF_WINV1 + idx] = (float)((2 * l + 1) * wig_pad(l, m, n, 9, beta));
        return;
    }
    idx -= 72200;
    if (idx < 14520) {
        int k = idx / 726, r = idx % 726, l = r / 121, m = (r % 121) / 11, n = r % 11;
        double beta = DPI * (2 * k + 1) / 40.0;
        ws[OFF_WSO3 + idx] = (float)(quad_w(10, k) * wig_pad(l, m, n, 5, beta));
        return;
    }
    idx -= 14520;
    if (idx < 8712) {
        int k = idx / 726, r = idx % 726, l = r / 121, m = (r % 121) / 11, n = r % 11;
        double beta = DPI * (2 * k + 1) / 24.0;
        ws[OFF_WINV2 + idx] = (float)((2 * l + 1) * wig_pad(l, m, n, 5, beta));
        return;
    }
    idx -= 8712;
    if (idx < 12) { ws[OFF_WINT + idx] = (float)quad_w(6, idx); return; }
    idx -= 12;
    if (idx < 570) {
        int m = idx / 30, t = idx % 30;
        double ang = -2.0 * DPI * (double)((m - 9) * t) / 30.0;
        ws[OFF_FE1 + 2 * idx] = (float)cos(ang);
        ws[OFF_FE1 + 2 * idx + 1] = (float)sin(ang);
        return;
    }
    idx -= 570;
    if (idx < 380) {
        int m = idx / 20, a = idx % 20;
        double ang = 2.0 * DPI * (double)((m - 9) * a) / 20.0;
        ws[OFF_EA1 + 2 * idx] = (float)cos(ang);
        ws[OFF_EA1 + 2 * idx + 1] = (float)sin(ang);
        return;
    }
    idx -= 380;
    if (idx < 220) {
        int m = idx / 20, a = idx % 20;
        double ang = -2.0 * DPI * (double)((m - 5) * a) / 20.0;
        ws[OFF_FF2 + 2 * idx] = (float)cos(ang);
        ws[OFF_FF2 + 2 * idx + 1] = (float)sin(ang);
        return;
    }
    idx -= 220;
    if (idx < 132) {
        int m = idx / 12, a = idx % 12;
        double ang = 2.0 * DPI * (double)((m - 5) * a) / 12.0;
        ws[OFF_EA2 + 2 * idx] = (float)cos(ang);
        ws[OFF_EA2 + 2 * idx + 1] = (float)sin(ang);
        return;
    }
    idx -= 132;
    if (idx < 4560) {
        int p = idx / 190, r = idx % 190, l = r / 19, m = r % 19;
        int bi = p / 8, ai = p % 8;
        double beta = (bi + 1) * (DPI / 24.0);
        double alpha = 2.0 * DPI * ai / 8.0;
        double re = 0.0, im = 0.0;
        if (m - 9 >= -l && m - 9 <= l) {
            double d = wig_d(l, m - 9 + l, l, beta);
            double ang = -(double)(m - 9) * alpha;
            re = d * cos(ang); im = d * sin(ang);
        }
        ws[OFF_BS2 + 2 * idx] = (float)re;
        ws[OFF_BS2 + 2 * idx + 1] = (float)im;
        return;
    }
    idx -= 4560;
    if (idx < 104544) {
        int p = idx / 726, r = idx % 726, l = r / 121, m = (r % 121) / 11, n = r % 11;
        int bi = p / 48, ai = (p % 48) / 6, gi = p % 6;
        double beta = (bi + 1) * (DPI / 24.0);
        double alpha = 2.0 * DPI * ai / 8.0;
        double gamma = 2.0 * DPI * gi / 6.0;
        double re = 0.0, im = 0.0;
        if (m - 5 >= -l && m - 5 <= l && n - 5 >= -l && n - 5 <= l) {
            double d = wig_d(l, m - 5 + l, n - 5 + l, beta);
            double ang = -((double)(m - 5) * alpha + (double)(n - 5) * gamma);
            re = d * cos(ang); im = d * sin(ang);
        }
        ws[OFF_BSO3 + 2 * idx] = (float)re;
        ws[OFF_BSO3 + 2 * idx + 1] = (float)im;
        return;
    }
    idx -= 104544;
    // VTAB[286]: valid (l,m,n) triplets, l ascending (legacy)
    if (idx < 286) {
        int l = 0, cum = 0;
        while (idx >= cum + (2 * l + 1) * (2 * l + 1)) { cum += (2 * l + 1) * (2 * l + 1); ++l; }
        int rem = idx - cum, w = 2 * l + 1;
        int m = 5 - l + rem / w, n = 5 - l + rem % w;
        ((int*)(ws + OFF_VTAB))[idx] = l | (m << 4) | (n << 8);
        return;
    }
    idx -= 286;
    // VTAB2[146]: half set (dm>0 or dm==0&&dn>=0), l DESCENDING
    if (idx < 146) {
        int l = 5, st = 0;
        while (idx >= st + (2 * l * l + 2 * l + 1)) { st += 2 * l * l + 2 * l + 1; --l; }
        int rem = idx - st;
        int dm, dn;
        if (rem < l + 1) { dm = 0; dn = rem; }
        else { int r2 = rem - (l + 1); dm = 1 + r2 / (2 * l + 1); dn = r2 % (2 * l + 1) - l; }
        ((int*)(ws + OFF_VTAB2))[idx] = l | ((dm + 5) << 4) | ((dn + 5) << 8);
        return;
    }
}

// ---------------------------------------------------------------------------
__global__ __launch_bounds__(256) void psi1_kernel(float* ws, const float* __restrict__ k1) {
    int idx = blockIdx.x * 256 + threadIdx.x;
    if (idx >= 3800) return;
    int o = idx / 190, r = idx % 190;
    const float2* BS2 = (const float2*)(ws + OFF_BS2);
    float2 s = {0.f, 0.f};
    for (int p = 0; p < 24; ++p) {
        float w = k1[o * 24 + p];
        float2 bv = BS2[p * 190 + r];
        s.x += w * bv.x; s.y += w * bv.y;
    }
    ((float2*)(ws + OFF_PSI))[idx] = s;
}

// psi2: compute HALF (146 per (i,o)), write mirror via psi2[l,-m,-n] =
// (-1)^{m+n} conj(psi2[l,m,n]).  116800 dot products (was 228800).
__global__ __launch_bounds__(256) void psi2_kernel(float* ws, const float* __restrict__ k2) {
    int idx = blockIdx.x * 256 + threadIdx.x;
    if (idx >= 116800) return;
    int i = idx / 5840, r = idx % 5840, o = r / 146, h = r % 146;
    int w = ((const int*)(ws + OFF_VTAB2))[h];
    int l = w & 15, dm = ((w >> 4) & 15) - 5, dn = ((w >> 8) & 15) - 5;
    int lmn = l * 121 + (dm + 5) * 11 + (dn + 5);
    const float2* BS = (const float2*)(ws + OFF_BSO3);
    float2 s = {0.f, 0.f};
    for (int p = 0; p < 144; ++p) {
        float wv = k2[(i * 40 + o) * 144 + p];
        float2 bv = BS[p * 726 + lmn];
        s.x += wv * bv.x; s.y += wv * bv.y;
    }
    float2* row = (float2*)(ws + OFF_PSI2P) + (i * 40 + o) * 286;
    int base = l * (4 * l * l - 1) / 3, span = 2 * l + 1;
    row[base + (dm + l) * span + (dn + l)] = s;
    float sign = ((dm + dn + 16) & 1) ? -1.f : 1.f;
    row[base + (-dm + l) * span + (-dn + l)] = make_float2(sign * s.x, -sign * s.y);
}

__global__ __launch_bounds__(256) void xform1_kernel(float* ws, const float* __restrict__ x) {
    const int tid = threadIdx.x, b = blockIdx.x;
    const float2* FE1 = (const float2*)(ws + OFF_FE1);
    const float* WS2 = ws + OFF_WS2;
    float2* Xg = (float2*)(ws + OFF_X) + b * 190;
    __shared__ float xs[900];
    __shared__ float2 xm[570];
    for (int i = tid; i < 900; i += 256) xs[i] = x[b * 900 + i];
    __syncthreads();
    for (int i = tid; i < 570; i += 256) {
        int k = i / 19, m = i % 19;
        float2 s = {0.f, 0.f};
        #pragma unroll
        for (int t = 0; t < 30; ++t) {
            float v = xs[k * 30 + t];
            float2 e = FE1[m * 30 + t];
            s.x += v * e.x; s.y += v * e.y;
        }
        xm[k * 19 + m] = s;
    }
    __syncthreads();
    for (int i = tid; i < 190; i += 256) {
        int l = i / 19, m = i % 19;
        float2 s = {0.f, 0.f};
        for (int k = 0; k < 30; ++k) {
            float w = WS2[k * 190 + l * 19 + m];
            float2 v = xm[k * 19 + m];
            s.x += w * v.x; s.y += w * v.y;
        }
        Xg[i] = s;
    }
}

// ---------------------------------------------------------------------------
// stage1 v6 (unchanged, r8-validated): Hermitian-halved + unroll-1 + (256,3).
// ---------------------------------------------------------------------------
__global__ __launch_bounds__(256, 3) void stage1_kernel(
    const float* __restrict__ WI1, const float* __restrict__ WS3,
    const float* __restrict__ EA1, const float* __restrict__ FF2,
    const float2* __restrict__ Xall, const float2* __restrict__ Pall,
    float2* __restrict__ X2out)
{
    const int tid = threadIdx.x;
    const int wave = tid >> 6, lane = tid & 63;
    const int b = blockIdx.x / 20;
    const int o = blockIdx.x % 20;
    const float2* Xg = Xall + b * 190;
    const float2* Pg = Pall + o * 190;
    float2* X2g = X2out + (b * 20 + o) * 286;
    const float2* EA1c = (const float2*)EA1;
    const float2* FF2c = (const float2*)FF2;

    __shared__ float2 Xs[190], Ps[190], FF2s[220];
    __shared__ float wbuf[4][2048];

    const int g = lane % 20, j = lane / 20;

    float2 eg[19];
    #pragma unroll
    for (int n = 0; n < 19; ++n) eg[n] = EA1c[n * 20 + g];

    for (int i = tid; i < 190; i += 256) { Xs[i] = Xg[i]; Ps[i] = Pg[i]; }
    for (int i = tid; i < 220; i += 256) FF2s[i] = FF2c[i];

    float2 acc[12];
    #pragma unroll
    for (int t = 0; t < 12; ++t) acc[t] = make_float2(0.f, 0.f);
    __syncthreads();

    for (int pass = 0; pass < 2; ++pass) {
        const int nk = pass ? 2 : 3;
        const int kbase = wave + pass * 12;
        float2* fhbuf = (float2*)&wbuf[wave][0];

        for (int i = lane; i < 190 * nk; i += 64) {
            int jj = i / 190, idx = i - jj * 190;
            int mrow = idx / 19, ni = idx - mrow * 19;
            int mi = mrow + 9;
            int an = ni > 9 ? ni - 9 : 9 - ni;
            int lmin = mrow > an ? mrow : an;
            const float* wk = WI1 + (kbase + 4 * jj) * 3610 + mi * 19 + ni;
            float2 s = {0.f, 0.f};
            for (int l = lmin; l < 10; ++l) {
                float2 a = Xs[l * 19 + mi], c = Ps[l * 19 + ni];
                float wv = wk[l * 361];
                s.x += wv * (a.x * c.x + a.y * c.y);
                s.y += wv * (a.y * c.x - a.x * c.y);
            }
            fhbuf[i] = s;
        }
        __builtin_amdgcn_wave_barrier();

        const bool active = (j < nk);
        const float2* fhj = fhbuf + (active ? j * 190 : 0);
        float ybuf[20];
        {
            float2 t = {0.f, 0.f};
            #pragma unroll
            for (int n = 0; n < 19; ++n) {
                float2 f = fhj[n];
                t.x += f.x * eg[n].x - f.y * eg[n].y;
                t.y += f.x * eg[n].y + f.y * eg[n].x;
            }
            #pragma unroll
            for (int a = 0; a < 20; ++a) ybuf[a] = t.x;
        }
        #pragma unroll 1   // keep live ranges small (r7: full unroll -> 220 VGPR)
        for (int mrow = 1; mrow < 10; ++mrow) {
            float2 t = {0.f, 0.f};
            #pragma unroll
            for (int n = 0; n < 19; ++n) {
                float2 f = fhj[mrow * 19 + n];
                t.x += f.x * eg[n].x - f.y * eg[n].y;
                t.y += f.x * eg[n].y + f.y * eg[n].x;
            }
            t.x *= 2.f; t.y *= 2.f;
            #pragma unroll
            for (int a = 0; a < 20; ++a) {
                float2 e = EA1c[(9 + mrow) * 20 + a];
                ybuf[a] += t.x * e.x - t.y * e.y;
            }
        }
        float2 uacc[6];
        #pragma unroll
        for (int d = 0; d < 6; ++d) uacc[d] = make_float2(0.f, 0.f);
        #pragma unroll
        for (int a = 0; a < 20; ++a) {
            float y = ybuf[a] > 0.f ? ybuf[a] : 0.f;
            uacc[0].x += y;
            #pragma unroll
            for (int d = 1; d < 6; ++d) {
                float2 e = FF2c[(5 + d) * 20 + a];
                uacc[d].x += e.x * y; uacc[d].y += e.y * y;
            }
        }
        float2* uubuf = (float2*)&wbuf[wave][0];
        if (active) {
            uubuf[j * 220 + 5 * 20 + g] = make_float2(uacc[0].x, 0.f);
            #pragma unroll
            for (int d = 1; d < 6; ++d) {
                uubuf[j * 220 + (5 + d) * 20 + g] = uacc[d];
                uubuf[j * 220 + (5 - d) * 20 + g] = make_float2(uacc[d].x, -uacc[d].y);
            }
        }
        __builtin_amdgcn_wave_barrier();

        float2* ymnbuf = (float2*)&wbuf[wave][1320];
        for (int i = lane; i < 121 * nk; i += 64) {
            int jj = i / 121, rr = i - jj * 121;
            int mi = rr / 11, ni = rr - mi * 11;
            float2 s = {0.f, 0.f};
            #pragma unroll
            for (int gg = 0; gg < 20; ++gg) {
                float2 u = uubuf[jj * 220 + mi * 20 + gg];
                float2 e = FF2s[ni * 20 + gg];
                s.x += u.x * e.x - u.y * e.y;
                s.y += u.x * e.y + u.y * e.x;
            }
            ymnbuf[i] = s;
        }
        __builtin_amdgcn_wave_barrier();

        for (int jj = 0; jj < nk; ++jj) {
            const float* wsk = WS3 + (kbase + 4 * jj) * 726;
            #pragma unroll
            for (int t = 0; t < 12; ++t) {
                int jdx = lane + 64 * t;
                if (jdx < 726) {
                    float w = wsk[jdx];
                    float2 v = ymnbuf[jj * 121 + jdx % 121];
                    acc[t].x += w * v.x; acc[t].y += w * v.y;
                }
            }
        }
        __builtin_amdgcn_wave_barrier();
    }

    __syncthreads();
    float2* myred = (float2*)&wbuf[wave][0];
    #pragma unroll
    for (int t = 0; t < 12; ++t) {
        int jdx = lane + 64 * t;
        if (jdx < 726) myred[jdx] = acc[t];
    }
    __syncthreads();
    for (int i = tid; i < 726; i += 256) {
        float2 s0 = ((float2*)&wbuf[0][0])[i];
        float2 s1 = ((float2*)&wbuf[1][0])[i];
        float2 s2 = ((float2*)&wbuf[2][0])[i];
        float2 s3 = ((float2*)&wbuf[3][0])[i];
        int l = i / 121, r = i - l * 121, m = r / 11, n = r - m * 11;
        int dm = m - 5, dn = n - 5;
        int adm = dm < 0 ? -dm : dm, adn = dn < 0 ? -dn : dn;
        if (adm <= l && adn <= l) {
            int pidx = l * (4 * l * l - 1) / 3 + (dm + l) * (2 * l + 1) + (dn + l);
            X2g[pidx] = make_float2(s0.x + s1.x + s2.x + s3.x, s0.y + s1.y + s2.y + s3.y);
        }
    }
}

// ---------------------------------------------------------------------------
// stage2 v7: Hermitian-halved Z2. Phase A computes only the 146-element half
// set (l-descending, lane-striped: max wave k-iters ~25 vs 49); phase B
// rebuilds full z2 via sign*conj mirror; phase C: fh2 only m>=5 (792), t2
// halved (864), y2 = t0.x + sum 2Re(E*t_d), all 12 k2 in one pass.
// ---------------------------------------------------------------------------
__global__ __launch_bounds__(256) void stage2_kernel(float* ws) {
    const int tid = threadIdx.x;
    const int wave = tid >> 6, lane = tid & 63;
    const int b = blockIdx.x / 40;
    const int o = blockIdx.x % 40;
    const float2* X2p = (const float2*)(ws + OFF_X2P) + b * 20 * 286;
    const float2* P2p = (const float2*)(ws + OFF_PSI2P);
    const float*  WI2 = ws + OFF_WINV2;
    const float2* EA2 = (const float2*)(ws + OFF_EA2);
    const float*  WIT = ws + OFF_WINT;
    const int*  VTAB2 = (const int*)(ws + OFF_VTAB2);
    float* featg = ws + OFF_FEAT;

    // sm: [0..4576) 4 wave regions of 1144 (xi 572 | pp 572); partials alias
    //     [4576..6028) z2s 726 cplx
    // phase C: fh2 = sm[0..1584) (792 cplx), t2 = sm[1584..3312) (864 cplx)
    __shared__ float sm[6028];
    __shared__ float red[4];
    float* wreg = sm + wave * 1144;

    int xo[3], po[3], klen[3];
    float2 acc[3];
    #pragma unroll
    for (int t = 0; t < 3; ++t) {
        int v = lane + 64 * t;
        acc[t] = make_float2(0.f, 0.f);
        if (v < 146) {
            int w = VTAB2[v];
            int l = w & 15, dm = ((w >> 4) & 15) - 5, dn = ((w >> 8) & 15) - 5;
            int base = l * (4 * l * l - 1) / 3, span = 2 * l + 1;
            xo[t] = base + (dm + l) * span;
            po[t] = base + (dn + l) * span;
            klen[t] = span;
        } else { xo[t] = 0; po[t] = 0; klen[t] = 0; }
    }

    // phase A: wave-synchronous i-loop over packed rows
    for (int ii = wave; ii < 20; ii += 4) {
        const float4* xs = (const float4*)(X2p + ii * 286);
        const float4* ps = (const float4*)(P2p + (ii * 40 + o) * 286);
        float4* xiW4 = (float4*)wreg;
        float4* ppW4 = (float4*)(wreg + 572);
        for (int v = lane; v < 143; v += 64) { xiW4[v] = xs[v]; ppW4[v] = ps[v]; }
        __builtin_amdgcn_wave_barrier();
        const float2* xiW = (const float2*)xiW4;
        const float2* ppW = (const float2*)ppW4;
        #pragma unroll
        for (int t = 0; t < 3; ++t) {
            for (int k = 0; k < klen[t]; ++k) {
                float2 u = xiW[xo[t] + k], v2 = ppW[po[t] + k];
                acc[t].x += u.x * v2.x + u.y * v2.y;
                acc[t].y += u.y * v2.x - u.x * v2.y;
            }
        }
        __builtin_amdgcn_wave_barrier();
    }

    float2* part = (float2*)wreg;
    #pragma unroll
    for (int t = 0; t < 3; ++t) {
        int v = lane + 64 * t;
        if (v < 146) part[v] = acc[t];
    }
    __syncthreads();

    // phase B: rebuild full z2[726]; mirror = (-1)^{dm+dn} conj(half)
    float2* z2s = (float2*)(sm + 4576);
    for (int idx = tid; idx < 726; idx += 256) {
        int l = idx / 121, r = idx - l * 121, m = r / 11, n = r - m * 11;
        int dm = m - 5, dn = n - 5;
        int am = dm < 0 ? -dm : dm, an = dn < 0 ? -dn : dn;
        float2 s = {0.f, 0.f};
        if (am <= l && an <= l) {
            bool inhalf = (dm > 0) || (dm == 0 && dn >= 0);
            int ddm = inhalf ? dm : -dm, ddn = inhalf ? dn : -dn;
            int lp = l + 1;
            int st = 146 - lp * (2 * lp * lp + 1) / 3;   // l-descending start
            int h = st + (ddm == 0 ? ddn : (l + 1) + (ddm - 1) * (2 * l + 1) + (ddn + l));
            #pragma unroll
            for (int w = 0; w < 4; ++w) {
                float2 p = ((float2*)(sm + w * 1144))[h];
                s.x += p.x; s.y += p.y;
            }
            if (!inhalf) {
                float sign = ((am + an) & 1) ? -1.f : 1.f;
                s = make_float2(sign * s.x, -sign * s.y);
            }
        }
        z2s[idx] = s;
    }
    __syncthreads();

    // phase C: fh2 rows m>=5 only, all 12 k2 at once
    float2* fh2 = (float2*)sm;            // [12][6][11]
    float2* t2  = (float2*)(sm + 1584);   // [12][6][12]
    for (int i = tid; i < 792; i += 256) {
        int k2 = i / 66, rr = i - k2 * 66;
        int mrow = rr / 11, n = rr - mrow * 11;
        int dn = n - 5, an = dn < 0 ? -dn : dn;
        int lmin = mrow > an ? mrow : an;
        int mfull = mrow + 5;
        float2 s = {0.f, 0.f};
        for (int ll = lmin; ll < 6; ++ll) {
            float w = WI2[k2 * 726 + ll * 121 + mfull * 11 + n];
            float2 z = z2s[ll * 121 + mfull * 11 + n];
            s.x += w * z.x; s.y += w * z.y;
        }
        fh2[i] = s;
    }
    __syncthreads();
    for (int i = tid; i < 864; i += 256) {
        int k2 = i / 72, rr = i - k2 * 72, mrow = rr / 12, g = rr - mrow * 12;
        float2 s = {0.f, 0.f};
        #pragma unroll
        for (int n = 0; n < 11; ++n) {
            float2 f = fh2[k2 * 66 + mrow * 11 + n], e = EA2[n * 12 + g];
            s.x += f.x * e.x - f.y * e.y;
            s.y += f.x * e.y + f.y * e.x;
        }
        t2[i] = s;
    }
    __syncthreads();
    // y2[a,g] = t2[0].x + sum_{d=1..5} 2Re(E_A2[5+d,a] * t2[d,g]); relu; W_INT
    float partial = 0.f;
    for (int i = tid; i < 1728; i += 256) {
        int k2 = i / 144, rr = i - k2 * 144, a = rr / 12, g = rr - a * 12;
        float s = t2[k2 * 72 + g].x;
        #pragma unroll
        for (int d = 1; d < 6; ++d) {
            float2 e = EA2[(5 + d) * 12 + a];
            float2 t = t2[k2 * 72 + d * 12 + g];
            s += 2.f * (e.x * t.x - e.y * t.y);
        }
        if (s > 0.f) partial += WIT[k2] * s;
    }
    for (int off = 32; off > 0; off >>= 1) partial += __shfl_down(partial, off, 64);
    if ((tid & 63) == 0) red[tid >> 6] = partial;
    __syncthreads();
    if (tid == 0) featg[b * 40 + o] = (red[0] + red[1] + red[2] + red[3]) * (1.0f / 144.0f);
}

// ---------------------------------------------------------------------------
__global__ __launch_bounds__(256) void final_kernel(const float* __restrict__ ws,
                                                    const float* __restrict__ wl,
                                                    const float* __restrict__ bl,
                                                    float* __restrict__ out) {
    int idx = blockIdx.x * 256 + threadIdx.x;
    if (idx >= 1280) return;
    int b = idx / 10, f = idx % 10;
    const float* feat = ws + OFF_FEAT;
    float s = bl[f];
    for (int o = 0; o < 40; ++o) s += feat[b * 40 + o] * wl[f * 40 + o];
    out[idx] = s;
}

// ---------------------------------------------------------------------------
extern "C" void kernel_launch(void* const* d_in, const int* in_sizes, int n_in,
                              void* d_out, int out_size, void* d_ws, size_t ws_size,
                              hipStream_t stream) {
    (void)in_sizes; (void)n_in; (void)out_size; (void)ws_size;
    const float* x  = (const float*)d_in[0];
    const float* k1 = (const float*)d_in[1];
    const float* k2 = (const float*)d_in[2];
    const float* wl = (const float*)d_in[3];
    const float* bl = (const float*)d_in[4];
    float* out = (float*)d_out;
    float* ws  = (float*)d_ws;

    build_tables_kernel<<<829, 256, 0, stream>>>(ws);   // 211982 elems
    psi1_kernel<<<15, 256, 0, stream>>>(ws, k1);
    xform1_kernel<<<128, 256, 0, stream>>>(ws, x);
    psi2_kernel<<<457, 256, 0, stream>>>(ws, k2);       // 116800 half-set
    stage1_kernel<<<128 * 20, 256, 0, stream>>>(
        ws + OFF_WINV1, ws + OFF_WSO3, ws + OFF_EA1, ws + OFF_FF2,
        (const float2*)(ws + OFF_X), (const float2*)(ws + OFF_PSI),
        (float2*)(ws + OFF_X2P));
    stage2_kernel<<<128 * 40, 256, 0, stream>>>(ws);
    final_kernel<<<5, 256, 0, stream>>>(ws, wl, bl, out);
}

// Round 10
// 353.085 us; speedup vs baseline: 4.4284x; 1.0637x over previous
//
#include <hip/hip_runtime.h>
#include <math.h>

// ---------------------------------------------------------------------------
// Problem dims: B_IN=15, B1=10, B2=6, F1=20, F2=40, F_OUT=10
// M1=19, C1=9, M2=11, C2=5, batch=128
// VALID(l,m,n): |m-5|<=l && |n-5|<=l -> 286 of 726; packed base(l)=l(4l^2-1)/3
// HALF set (z2 Hermitian): dm>0 or (dm==0 && dn>=0) -> 146, l-DESCENDING.
// Parity identities used (all exact):
//   E_A1[mi, a+10] = (-1)^(mi-9) E_A1[mi, a]   (20-pt DFT half shift)
//   FF2[5+d, a+10] = (-1)^d FF2[5+d, a]
//   E_A2[5+d, a+6] = (-1)^d E_A2[5+d, a]      (12-pt)
// ---------------------------------------------------------------------------

constexpr int OFF_WS2   = 0;                      // W_S2_FWD  [30][10][19]
constexpr int OFF_WINV1 = OFF_WS2   + 5700;       // W_INV1    [20][10][19][19]
constexpr int OFF_WSO3  = OFF_WINV1 + 72200;      // W_SO3_FWD [20][6][11][11]
constexpr int OFF_WINV2 = OFF_WSO3  + 14520;      // W_INV2    [12][6][11][11]
constexpr int OFF_WINT  = OFF_WINV2 + 8712;       // W_INT     [12] (+pad)
constexpr int OFF_FE1   = OFF_WINT  + 16;         // FE1  cplx [19][30]
constexpr int OFF_EA1   = OFF_FE1   + 1140;       // E_A1 cplx [19][20]
constexpr int OFF_FF2   = OFF_EA1   + 760;        // FF2  cplx [11][20]
constexpr int OFF_EA2   = OFF_FF2   + 440;        // E_A2 cplx [11][12]
constexpr int OFF_BS2   = OFF_EA2   + 264;        // B_S2 cplx [24][10][19]
constexpr int OFF_BSO3  = OFF_BS2   + 9120;       // B_SO3 cplx[144][6][11][11]
constexpr int OFF_PSI   = OFF_BSO3  + 209088;     // psi  cplx [20][10][19]
constexpr int OFF_X     = OFF_PSI   + 7600;       // X    cplx [128][10][19]
constexpr int OFF_X2P   = OFF_X     + 48640;      // X2 packed [128][20][286] cplx
constexpr int OFF_PSI2P = OFF_X2P   + 1464320;    // psi2 packed [20][40][286] cplx
constexpr int OFF_FEAT  = OFF_PSI2P + 457600;     // feat      [128][40]
constexpr int OFF_VTAB  = OFF_FEAT  + 5120;       // int[286] valid (l,m,n)
constexpr int OFF_VTAB2 = OFF_VTAB  + 286;        // int[146] half-set, l desc

#define DPI 3.14159265358979323846

// ---------------------------------------------------------------------------
__device__ __forceinline__ double dfact(int n) {
    double f = 1.0;
    for (int i = 2; i <= n; ++i) f *= (double)i;
    return f;
}
__device__ __forceinline__ double dpowi(double x, int n) {
    double r = 1.0;
    for (int i = 0; i < n; ++i) r *= x;
    return r;
}
__device__ double wig_d(int l, int mi, int ni, double beta) {
    int m = mi - l, n = ni - l;
    double cb = cos(0.5 * beta), sb = sin(0.5 * beta);
    double pref = sqrt(dfact(l + m) * dfact(l - m) * dfact(l + n) * dfact(l - n));
    int s0 = (n - m) > 0 ? (n - m) : 0;
    int s1 = (l + n) < (l - m) ? (l + n) : (l - m);
    double v = 0.0;
    for (int s = s0; s <= s1; ++s) {
        double term = dpowi(cb, 2 * l + n - m - 2 * s) * dpowi(sb, m - n + 2 * s) /
                      (dfact(l + n - s) * dfact(s) * dfact(m - n + s) * dfact(l - m - s));
        v += ((m - n + s) & 1) ? -term : term;
    }
    return pref * v;
}
__device__ double wig_pad(int l, int m, int n, int c, double beta) {
    if (m < c - l || m > c + l || n < c - l || n > c + l) return 0.0;
    return wig_d(l, m - (c - l), n - (c - l), beta);
}
__device__ double quad_w(int b, int k) {
    double beta = DPI * (2 * k + 1) / (4.0 * b);
    double s = 0.0;
    for (int j = 0; j < b; ++j) s += sin((2 * j + 1) * beta) / (double)(2 * j + 1);
    return 2.0 / b * sin(beta) * s;
}

// element ids total = 211982
__global__ __launch_bounds__(256) void build_tables_kernel(float* ws) {
    int idx = blockIdx.x * 256 + threadIdx.x;
    if (idx < 5700) {
        int k = idx / 190, r = idx % 190, l = r / 19, m = r % 19;
        double beta = DPI * (2 * k + 1) / 60.0;
        ws[OFF_WS2 + idx] = (float)(quad_w(15, k) * wig_pad(l, m, 9, 9, beta));
        return;
    }
    idx -= 5700;
    if (idx < 72200) {
        int k = idx / 3610, r = idx % 3610, l = r / 361, r2 = r % 361, m = r2 / 19, n = r2 % 19;
        double beta = DPI * (2 * k + 1) / 40.0;
        ws[OFF_WINV1 + idx] = (float)((2 * l + 1) * wig_pad(l, m, n, 9, beta));
        return;
    }
    idx -= 72200;
    if (idx < 14520) {
        int k = idx / 726, r = idx % 726, l = r / 121, m = (r % 121) / 11, n = r % 11;
        double beta = DPI * (2 * k + 1) / 40.0;
        ws[OFF_WSO3 + idx] = (float)(quad_w(10, k) * wig_pad(l, m, n, 5, beta));
        return;
    }
    idx -= 14520;
    if (idx < 8712) {
        int k = idx / 726, r = idx % 726, l = r / 121, m = (r % 121) / 11, n = r % 11;
        double beta = DPI * (2 * k + 1) / 24.0;
        ws[OFF_WINV2 + idx] = (float)((2 * l + 1) * wig_pad(l, m, n, 5, beta));
        return;
    }
    idx -= 8712;
    if (idx < 12) { ws[OFF_WINT + idx] = (float)quad_w(6, idx); return; }
    idx -= 12;
    if (idx < 570) {
        int m = idx / 30, t = idx % 30;
        double ang = -2.0 * DPI * (double)((m - 9) * t) / 30.0;
        ws[OFF_FE1 + 2 * idx] = (float)cos(ang);
        ws[OFF_FE1 + 2 * idx + 1] = (float)sin(ang);
        return;
    }
    idx -= 570;
    if (idx < 380) {
        int m = idx / 20, a = idx % 20;
        double ang = 2.0 * DPI * (double)((m - 9) * a) / 20.0;
        ws[OFF_EA1 + 2 * idx] = (float)cos(ang);
        ws[OFF_EA1 + 2 * idx + 1] = (float)sin(ang);
        return;
    }
    idx -= 380;
    if (idx < 220) {
        int m = idx / 20, a = idx % 20;
        double ang = -2.0 * DPI * (double)((m - 5) * a) / 20.0;
        ws[OFF_FF2 + 2 * idx] = (float)cos(ang);
        ws[OFF_FF2 + 2 * idx + 1] = (float)sin(ang);
        return;
    }
    idx -= 220;
    if (idx < 132) {
        int m = idx / 12, a = idx % 12;
        double ang = 2.0 * DPI * (double)((m - 5) * a) / 12.0;
        ws[OFF_EA2 + 2 * idx] = (float)cos(ang);
        ws[OFF_EA2 + 2 * idx + 1] = (float)sin(ang);
        return;
    }
    idx -= 132;
    if (idx < 4560) {
        int p = idx / 190, r = idx % 190, l = r / 19, m = r % 19;
        int bi = p / 8, ai = p % 8;
        double beta = (bi + 1) * (DPI / 24.0);
        double alpha = 2.0 * DPI * ai / 8.0;
        double re = 0.0, im = 0.0;
        if (m - 9 >= -l && m - 9 <= l) {
            double d = wig_d(l, m - 9 + l, l, beta);
            double ang = -(double)(m - 9) * alpha;
            re = d * cos(ang); im = d * sin(ang);
        }
        ws[OFF_BS2 + 2 * idx] = (float)re;
        ws[OFF_BS2 + 2 * idx + 1] = (float)im;
        return;
    }
    idx -= 4560;
    if (idx < 104544) {
        int p = idx / 726, r = idx % 726, l = r / 121, m = (r % 121) / 11, n = r % 11;
        int bi = p / 48, ai = (p % 48) / 6, gi = p % 6;
        double beta = (bi + 1) * (DPI / 24.0);
        double alpha = 2.0 * DPI * ai / 8.0;
        double gamma = 2.0 * DPI * gi / 6.0;
        double re = 0.0, im = 0.0;
        if (m - 5 >= -l && m - 5 <= l && n - 5 >= -l && n - 5 <= l) {
            double d = wig_d(l, m - 5 + l, n - 5 + l, beta);
            double ang = -((double)(m - 5) * alpha + (double)(n - 5) * gamma);
            re = d * cos(ang); im = d * sin(ang);
        }
        ws[OFF_BSO3 + 2 * idx] = (float)re;
        ws[OFF_BSO3 + 2 * idx + 1] = (float)im;
        return;
    }
    idx -= 104544;
    if (idx < 286) {
        int l = 0, cum = 0;
        while (idx >= cum + (2 * l + 1) * (2 * l + 1)) { cum += (2 * l + 1) * (2 * l + 1); ++l; }
        int rem = idx - cum, w = 2 * l + 1;
        int m = 5 - l + rem / w, n = 5 - l + rem % w;
        ((int*)(ws + OFF_VTAB))[idx] = l | (m << 4) | (n << 8);
        return;
    }
    idx -= 286;
    if (idx < 146) {
        int l = 5, st = 0;
        while (idx >= st + (2 * l * l + 2 * l + 1)) { st += 2 * l * l + 2 * l + 1; --l; }
        int rem = idx - st;
        int dm, dn;
        if (rem < l + 1) { dm = 0; dn = rem; }
        else { int r2 = rem - (l + 1); dm = 1 + r2 / (2 * l + 1); dn = r2 % (2 * l + 1) - l; }
        ((int*)(ws + OFF_VTAB2))[idx] = l | ((dm + 5) << 4) | ((dn + 5) << 8);
        return;
    }
}

// ---------------------------------------------------------------------------
__global__ __launch_bounds__(256) void psi1_kernel(float* ws, const float* __restrict__ k1) {
    int idx = blockIdx.x * 256 + threadIdx.x;
    if (idx >= 3800) return;
    int o = idx / 190, r = idx % 190;
    const float2* BS2 = (const float2*)(ws + OFF_BS2);
    float2 s = {0.f, 0.f};
    for (int p = 0; p < 24; ++p) {
        float w = k1[o * 24 + p];
        float2 bv = BS2[p * 190 + r];
        s.x += w * bv.x; s.y += w * bv.y;
    }
    ((float2*)(ws + OFF_PSI))[idx] = s;
}

// psi2: half-set (146 per (i,o)) + Hermitian mirror write.
__global__ __launch_bounds__(256) void psi2_kernel(float* ws, const float* __restrict__ k2) {
    int idx = blockIdx.x * 256 + threadIdx.x;
    if (idx >= 116800) return;
    int i = idx / 5840, r = idx % 5840, o = r / 146, h = r % 146;
    int w = ((const int*)(ws + OFF_VTAB2))[h];
    int l = w & 15, dm = ((w >> 4) & 15) - 5, dn = ((w >> 8) & 15) - 5;
    int lmn = l * 121 + (dm + 5) * 11 + (dn + 5);
    const float2* BS = (const float2*)(ws + OFF_BSO3);
    float2 s = {0.f, 0.f};
    for (int p = 0; p < 144; ++p) {
        float wv = k2[(i * 40 + o) * 144 + p];
        float2 bv = BS[p * 726 + lmn];
        s.x += wv * bv.x; s.y += wv * bv.y;
    }
    float2* row = (float2*)(ws + OFF_PSI2P) + (i * 40 + o) * 286;
    int base = l * (4 * l * l - 1) / 3, span = 2 * l + 1;
    row[base + (dm + l) * span + (dn + l)] = s;
    float sign = ((dm + dn + 16) & 1) ? -1.f : 1.f;
    row[base + (-dm + l) * span + (-dn + l)] = make_float2(sign * s.x, -sign * s.y);
}

__global__ __launch_bounds__(256) void xform1_kernel(float* ws, const float* __restrict__ x) {
    const int tid = threadIdx.x, b = blockIdx.x;
    const float2* FE1 = (const float2*)(ws + OFF_FE1);
    const float* WS2 = ws + OFF_WS2;
    float2* Xg = (float2*)(ws + OFF_X) + b * 190;
    __shared__ float xs[900];
    __shared__ float2 xm[570];
    for (int i = tid; i < 900; i += 256) xs[i] = x[b * 900 + i];
    __syncthreads();
    for (int i = tid; i < 570; i += 256) {
        int k = i / 19, m = i % 19;
        float2 s = {0.f, 0.f};
        #pragma unroll
        for (int t = 0; t < 30; ++t) {
            float v = xs[k * 30 + t];
            float2 e = FE1[m * 30 + t];
            s.x += v * e.x; s.y += v * e.y;
        }
        xm[k * 19 + m] = s;
    }
    __syncthreads();
    for (int i = tid; i < 190; i += 256) {
        int l = i / 19, m = i % 19;
        float2 s = {0.f, 0.f};
        for (int k = 0; k < 30; ++k) {
            float w = WS2[k * 190 + l * 19 + m];
            float2 v = xm[k * 19 + m];
            s.x += w * v.x; s.y += w * v.y;
        }
        Xg[i] = s;
    }
}

// ---------------------------------------------------------------------------
// stage1 v7: v6 + mrow-parity halving of the a-loop (ye/yo by mrow parity,
// y[a]=ye+yo, y[a+10]=ye-yo) and a-parity halving of uu (yp/ym fold).
// Purely per-lane; LDS/barrier structure identical to r8/r9-validated v6.
// ---------------------------------------------------------------------------
__global__ __launch_bounds__(256, 3) void stage1_kernel(
    const float* __restrict__ WI1, const float* __restrict__ WS3,
    const float* __restrict__ EA1, const float* __restrict__ FF2,
    const float2* __restrict__ Xall, const float2* __restrict__ Pall,
    float2* __restrict__ X2out)
{
    const int tid = threadIdx.x;
    const int wave = tid >> 6, lane = tid & 63;
    const int b = blockIdx.x / 20;
    const int o = blockIdx.x % 20;
    const float2* Xg = Xall + b * 190;
    const float2* Pg = Pall + o * 190;
    float2* X2g = X2out + (b * 20 + o) * 286;
    const float2* EA1c = (const float2*)EA1;
    const float2* FF2c = (const float2*)FF2;

    __shared__ float2 Xs[190], Ps[190], FF2s[220];
    __shared__ float wbuf[4][2048];

    const int g = lane % 20, j = lane / 20;

    float2 eg[19];
    #pragma unroll
    for (int n = 0; n < 19; ++n) eg[n] = EA1c[n * 20 + g];

    for (int i = tid; i < 190; i += 256) { Xs[i] = Xg[i]; Ps[i] = Pg[i]; }
    for (int i = tid; i < 220; i += 256) FF2s[i] = FF2c[i];

    float2 acc[12];
    #pragma unroll
    for (int t = 0; t < 12; ++t) acc[t] = make_float2(0.f, 0.f);
    __syncthreads();

    for (int pass = 0; pass < 2; ++pass) {
        const int nk = pass ? 2 : 3;
        const int kbase = wave + pass * 12;
        float2* fhbuf = (float2*)&wbuf[wave][0];

        // (a) fh rows mi=9..18 only (Hermitian half)
        for (int i = lane; i < 190 * nk; i += 64) {
            int jj = i / 190, idx = i - jj * 190;
            int mrow = idx / 19, ni = idx - mrow * 19;
            int mi = mrow + 9;
            int an = ni > 9 ? ni - 9 : 9 - ni;
            int lmin = mrow > an ? mrow : an;
            const float* wk = WI1 + (kbase + 4 * jj) * 3610 + mi * 19 + ni;
            float2 s = {0.f, 0.f};
            for (int l = lmin; l < 10; ++l) {
                float2 a = Xs[l * 19 + mi], c = Ps[l * 19 + ni];
                float wv = wk[l * 361];
                s.x += wv * (a.x * c.x + a.y * c.y);
                s.y += wv * (a.y * c.x - a.x * c.y);
            }
            fhbuf[i] = s;
        }
        __builtin_amdgcn_wave_barrier();

        // (b) per-lane column pipeline, mrow-parity halved
        const bool active = (j < nk);
        const float2* fhj = fhbuf + (active ? j * 190 : 0);
        float ye[10], yo[10];
        {   // mrow = 0 (even parity): contributes t.x to all a
            float2 t = {0.f, 0.f};
            #pragma unroll
            for (int n = 0; n < 19; ++n) {
                float2 f = fhj[n];
                t.x += f.x * eg[n].x - f.y * eg[n].y;
                t.y += f.x * eg[n].y + f.y * eg[n].x;
            }
            #pragma unroll
            for (int a = 0; a < 10; ++a) { ye[a] = t.x; yo[a] = 0.f; }
        }
        #pragma unroll 1   // r7 lesson: full unroll -> 220 VGPR occupancy cliff
        for (int mrow = 1; mrow < 10; ++mrow) {
            float2 t = {0.f, 0.f};
            #pragma unroll
            for (int n = 0; n < 19; ++n) {
                float2 f = fhj[mrow * 19 + n];
                t.x += f.x * eg[n].x - f.y * eg[n].y;
                t.y += f.x * eg[n].y + f.y * eg[n].x;
            }
            t.x *= 2.f; t.y *= 2.f;
            if (mrow & 1) {   // wave-uniform branch
                #pragma unroll
                for (int a = 0; a < 10; ++a) {
                    float2 e = EA1c[(9 + mrow) * 20 + a];   // scalar load
                    yo[a] += t.x * e.x - t.y * e.y;
                }
            } else {
                #pragma unroll
                for (int a = 0; a < 10; ++a) {
                    float2 e = EA1c[(9 + mrow) * 20 + a];
                    ye[a] += t.x * e.x - t.y * e.y;
                }
            }
        }
        // y[a]=ye+yo, y[a+10]=ye-yo; relu; fold to yp/ym (in place)
        #pragma unroll
        for (int a = 0; a < 10; ++a) {
            float y0 = ye[a] + yo[a]; y0 = y0 > 0.f ? y0 : 0.f;
            float y1 = ye[a] - yo[a]; y1 = y1 > 0.f ? y1 : 0.f;
            ye[a] = y0 + y1;   // yp
            yo[a] = y0 - y1;   // ym
        }
        // uu[d] = sum_{a<10} (d even ? yp : ym)[a] * FF2[5+d, a]
        float2 uacc[6];
        uacc[0] = make_float2(0.f, 0.f);
        #pragma unroll
        for (int a = 0; a < 10; ++a) uacc[0].x += ye[a];
        #pragma unroll
        for (int d = 1; d < 6; ++d) {
            uacc[d] = make_float2(0.f, 0.f);
            #pragma unroll
            for (int a = 0; a < 10; ++a) {
                float q = (d & 1) ? yo[a] : ye[a];
                float2 e = FF2c[(5 + d) * 20 + a];   // scalar load
                uacc[d].x += e.x * q; uacc[d].y += e.y * q;
            }
        }
        // (c) uu -> LDS with conj mirror
        float2* uubuf = (float2*)&wbuf[wave][0];
        if (active) {
            uubuf[j * 220 + 5 * 20 + g] = make_float2(uacc[0].x, 0.f);
            #pragma unroll
            for (int d = 1; d < 6; ++d) {
                uubuf[j * 220 + (5 + d) * 20 + g] = uacc[d];
                uubuf[j * 220 + (5 - d) * 20 + g] = make_float2(uacc[d].x, -uacc[d].y);
            }
        }
        __builtin_amdgcn_wave_barrier();

        // (d) ymn[jj][mi,ni] = sum_g uu[jj][mi,g]*FF2[ni,g]
        float2* ymnbuf = (float2*)&wbuf[wave][1320];
        for (int i = lane; i < 121 * nk; i += 64) {
            int jj = i / 121, rr = i - jj * 121;
            int mi = rr / 11, ni = rr - mi * 11;
            float2 s = {0.f, 0.f};
            #pragma unroll
            for (int gg = 0; gg < 20; ++gg) {
                float2 u = uubuf[jj * 220 + mi * 20 + gg];
                float2 e = FF2s[ni * 20 + gg];
                s.x += u.x * e.x - u.y * e.y;
                s.y += u.x * e.y + u.y * e.x;
            }
            ymnbuf[i] = s;
        }
        __builtin_amdgcn_wave_barrier();

        // (e) acc[j] += W_SO3_FWD[k,j] * ymn[jj][j%121]
        for (int jj = 0; jj < nk; ++jj) {
            const float* wsk = WS3 + (kbase + 4 * jj) * 726;
            #pragma unroll
            for (int t = 0; t < 12; ++t) {
                int jdx = lane + 64 * t;
                if (jdx < 726) {
                    float w = wsk[jdx];
                    float2 v = ymnbuf[jj * 121 + jdx % 121];
                    acc[t].x += w * v.x; acc[t].y += w * v.y;
                }
            }
        }
        __builtin_amdgcn_wave_barrier();
    }

    __syncthreads();
    float2* myred = (float2*)&wbuf[wave][0];
    #pragma unroll
    for (int t = 0; t < 12; ++t) {
        int jdx = lane + 64 * t;
        if (jdx < 726) myred[jdx] = acc[t];
    }
    __syncthreads();
    for (int i = tid; i < 726; i += 256) {
        float2 s0 = ((float2*)&wbuf[0][0])[i];
        float2 s1 = ((float2*)&wbuf[1][0])[i];
        float2 s2 = ((float2*)&wbuf[2][0])[i];
        float2 s3 = ((float2*)&wbuf[3][0])[i];
        int l = i / 121, r = i - l * 121, m = r / 11, n = r - m * 11;
        int dm = m - 5, dn = n - 5;
        int adm = dm < 0 ? -dm : dm, adn = dn < 0 ? -dn : dn;
        if (adm <= l && adn <= l) {
            int pidx = l * (4 * l * l - 1) / 3 + (dm + l) * (2 * l + 1) + (dn + l);
            X2g[pidx] = make_float2(s0.x + s1.x + s2.x + s3.x, s0.y + s1.y + s2.y + s3.y);
        }
    }
}

// ---------------------------------------------------------------------------
// stage2 v8: v7 + a-parity halving of the y2 loop (1728 -> 864 items,
// E_A2[5+d,a+6] = (-1)^d E_A2[5+d,a]).
// ---------------------------------------------------------------------------
__global__ __launch_bounds__(256) void stage2_kernel(float* ws) {
    const int tid = threadIdx.x;
    const int wave = tid >> 6, lane = tid & 63;
    const int b = blockIdx.x / 40;
    const int o = blockIdx.x % 40;
    const float2* X2p = (const float2*)(ws + OFF_X2P) + b * 20 * 286;
    const float2* P2p = (const float2*)(ws + OFF_PSI2P);
    const float*  WI2 = ws + OFF_WINV2;
    const float2* EA2 = (const float2*)(ws + OFF_EA2);
    const float*  WIT = ws + OFF_WINT;
    const int*  VTAB2 = (const int*)(ws + OFF_VTAB2);
    float* featg = ws + OFF_FEAT;

    __shared__ float sm[6028];
    __shared__ float red[4];
    float* wreg = sm + wave * 1144;

    int xo[3], po[3], klen[3];
    float2 acc[3];
    #pragma unroll
    for (int t = 0; t < 3; ++t) {
        int v = lane + 64 * t;
        acc[t] = make_float2(0.f, 0.f);
        if (v < 146) {
            int w = VTAB2[v];
            int l = w & 15, dm = ((w >> 4) & 15) - 5, dn = ((w >> 8) & 15) - 5;
            int base = l * (4 * l * l - 1) / 3, span = 2 * l + 1;
            xo[t] = base + (dm + l) * span;
            po[t] = base + (dn + l) * span;
            klen[t] = span;
        } else { xo[t] = 0; po[t] = 0; klen[t] = 0; }
    }

    for (int ii = wave; ii < 20; ii += 4) {
        const float4* xs = (const float4*)(X2p + ii * 286);
        const float4* ps = (const float4*)(P2p + (ii * 40 + o) * 286);
        float4* xiW4 = (float4*)wreg;
        float4* ppW4 = (float4*)(wreg + 572);
        for (int v = lane; v < 143; v += 64) { xiW4[v] = xs[v]; ppW4[v] = ps[v]; }
        __builtin_amdgcn_wave_barrier();
        const float2* xiW = (const float2*)xiW4;
        const float2* ppW = (const float2*)ppW4;
        #pragma unroll
        for (int t = 0; t < 3; ++t) {
            for (int k = 0; k < klen[t]; ++k) {
                float2 u = xiW[xo[t] + k], v2 = ppW[po[t] + k];
                acc[t].x += u.x * v2.x + u.y * v2.y;
                acc[t].y += u.y * v2.x - u.x * v2.y;
            }
        }
        __builtin_amdgcn_wave_barrier();
    }

    float2* part = (float2*)wreg;
    #pragma unroll
    for (int t = 0; t < 3; ++t) {
        int v = lane + 64 * t;
        if (v < 146) part[v] = acc[t];
    }
    __syncthreads();

    // phase B: rebuild full z2[726]; mirror = (-1)^{dm+dn} conj(half)
    float2* z2s = (float2*)(sm + 4576);
    for (int idx = tid; idx < 726; idx += 256) {
        int l = idx / 121, r = idx - l * 121, m = r / 11, n = r - m * 11;
        int dm = m - 5, dn = n - 5;
        int am = dm < 0 ? -dm : dm, an = dn < 0 ? -dn : dn;
        float2 s = {0.f, 0.f};
        if (am <= l && an <= l) {
            bool inhalf = (dm > 0) || (dm == 0 && dn >= 0);
            int ddm = inhalf ? dm : -dm, ddn = inhalf ? dn : -dn;
            int lp = l + 1;
            int st = 146 - lp * (2 * lp * lp + 1) / 3;
            int h = st + (ddm == 0 ? ddn : (l + 1) + (ddm - 1) * (2 * l + 1) + (ddn + l));
            #pragma unroll
            for (int w = 0; w < 4; ++w) {
                float2 p = ((float2*)(sm + w * 1144))[h];
                s.x += p.x; s.y += p.y;
            }
            if (!inhalf) {
                float sign = ((am + an) & 1) ? -1.f : 1.f;
                s = make_float2(sign * s.x, -sign * s.y);
            }
        }
        z2s[idx] = s;
    }
    __syncthreads();

    // phase C: fh2 rows m>=5, all 12 k2; t2 halved; y2 a-parity halved
    float2* fh2 = (float2*)sm;            // [12][6][11]
    float2* t2  = (float2*)(sm + 1584);   // [12][6][12]
    for (int i = tid; i < 792; i += 256) {
        int k2 = i / 66, rr = i - k2 * 66;
        int mrow = rr / 11, n = rr - mrow * 11;
        int dn = n - 5, an = dn < 0 ? -dn : dn;
        int lmin = mrow > an ? mrow : an;
        int mfull = mrow + 5;
        float2 s = {0.f, 0.f};
        for (int ll = lmin; ll < 6; ++ll) {
            float w = WI2[k2 * 726 + ll * 121 + mfull * 11 + n];
            float2 z = z2s[ll * 121 + mfull * 11 + n];
            s.x += w * z.x; s.y += w * z.y;
        }
        fh2[i] = s;
    }
    __syncthreads();
    for (int i = tid; i < 864; i += 256) {
        int k2 = i / 72, rr = i - k2 * 72, mrow = rr / 12, g = rr - mrow * 12;
        float2 s = {0.f, 0.f};
        #pragma unroll
        for (int n = 0; n < 11; ++n) {
            float2 f = fh2[k2 * 66 + mrow * 11 + n], e = EA2[n * 12 + g];
            s.x += f.x * e.x - f.y * e.y;
            s.y += f.x * e.y + f.y * e.x;
        }
        t2[i] = s;
    }
    __syncthreads();
    // y2[a,g] and y2[a+6,g] from even/odd-d partials (a in 0..5)
    float partial = 0.f;
    for (int i = tid; i < 864; i += 256) {
        int k2 = i / 72, rr = i - k2 * 72, a = rr / 12, g = rr - a * 12;
        float base = t2[k2 * 72 + g].x;
        float se = 0.f, so = 0.f;
        #pragma unroll
        for (int d = 1; d < 6; ++d) {
            float2 e = EA2[(5 + d) * 12 + a];
            float2 t = t2[k2 * 72 + d * 12 + g];
            float c = 2.f * (e.x * t.x - e.y * t.y);
            if (d & 1) so += c; else se += c;
        }
        float y0 = base + se + so, y1 = base + se - so;
        float w = WIT[k2];
        if (y0 > 0.f) partial += w * y0;
        if (y1 > 0.f) partial += w * y1;
    }
    for (int off = 32; off > 0; off >>= 1) partial += __shfl_down(partial, off, 64);
    if ((tid & 63) == 0) red[tid >> 6] = partial;
    __syncthreads();
    if (tid == 0) featg[b * 40 + o] = (red[0] + red[1] + red[2] + red[3]) * (1.0f / 144.0f);
}

// ---------------------------------------------------------------------------
__global__ __launch_bounds__(256) void final_kernel(const float* __restrict__ ws,
                                                    const float* __restrict__ wl,
                                                    const float* __restrict__ bl,
                                                    float* __restrict__ out) {
    int idx = blockIdx.x * 256 + threadIdx.x;
    if (idx >= 1280) return;
    int b = idx / 10, f = idx % 10;
    const float* feat = ws + OFF_FEAT;
    float s = bl[f];
    for (int o = 0; o < 40; ++o) s += feat[b * 40 + o] * wl[f * 40 + o];
    out[idx] = s;
}

// ---------------------------------------------------------------------------
extern "C" void kernel_launch(void* const* d_in, const int* in_sizes, int n_in,
                              void* d_out, int out_size, void* d_ws, size_t ws_size,
                              hipStream_t stream) {
    (void)in_sizes; (void)n_in; (void)out_size; (void)ws_size;
    const float* x  = (const float*)d_in[0];
    const float* k1 = (const float*)d_in[1];
    const float* k2 = (const float*)d_in[2];
    const float* wl = (const float*)d_in[3];
    const float* bl = (const float*)d_in[4];
    float* out = (float*)d_out;
    float* ws  = (float*)d_ws;

    build_tables_kernel<<<829, 256, 0, stream>>>(ws);
    psi1_kernel<<<15, 256, 0, stream>>>(ws, k1);
    xform1_kernel<<<128, 256, 0, stream>>>(ws, x);
    psi2_kernel<<<457, 256, 0, stream>>>(ws, k2);
    stage1_kernel<<<128 * 20, 256, 0, stream>>>(
        ws + OFF_WINV1, ws + OFF_WSO3, ws + OFF_EA1, ws + OFF_FF2,
        (const float2*)(ws + OFF_X), (const float2*)(ws + OFF_PSI),
        (float2*)(ws + OFF_X2P));
    stage2_kernel<<<128 * 40, 256, 0, stream>>>(ws);
    final_kernel<<<5, 256, 0, stream>>>(ws, wl, bl, out);
}